// Round 10
// baseline (264.335 us; speedup 1.0000x reference)
//
#include <hip/hip_runtime.h>
#include <hip/hip_bf16.h>

constexpr int N_NODES = 50000;
constexpr int N_EDGES = 800000;
constexpr int F_IN = 128;
constexpr int H1 = 64;
constexpr int HEADS = 4;
constexpr int D_H = 32;
constexpr int HOUT = HEADS * D_H;       // 128
constexpr int N_REL = 4;
constexpr int N_GRAPHS = 64;
constexpr int MBIG = H1 * (1 + N_REL);  // 320
constexpr int NBLK = (N_NODES + 255) / 256;  // 196
constexpr int N_PAD = 50048;            // rows padded to 16*3128

typedef __attribute__((ext_vector_type(8))) short bf16x8;
typedef __attribute__((ext_vector_type(4))) float f32x4;

// ---- monotonic float<->uint for atomicMax on floats ----
__device__ __forceinline__ unsigned f2mono(float f) {
  unsigned u = __float_as_uint(f);
  return (u & 0x80000000u) ? ~u : (u | 0x80000000u);
}
__device__ __forceinline__ float mono2f(unsigned m) {
  unsigned u = (m & 0x80000000u) ? (m & 0x7FFFFFFFu) : ~m;
  return __uint_as_float(u);
}
constexpr unsigned MONO_NEG_INF = 0x007FFFFFu;

// ---- bf16 helpers ----
__device__ __forceinline__ unsigned short f2bf(float f) {
  unsigned u = __float_as_uint(f);
  unsigned r = (u + 0x7FFFu + ((u >> 16) & 1u)) >> 16;  // RNE
  return (unsigned short)r;
}
__device__ __forceinline__ float bf2f(unsigned short h) {
  return __uint_as_float((unsigned)h << 16);
}
__device__ __forceinline__ float bflo(unsigned u) { return __uint_as_float(u << 16); }
__device__ __forceinline__ float bfhi(unsigned u) { return __uint_as_float(u & 0xFFFF0000u); }

// ---- split x (f32) -> xhi/xlo bf16, once ----
__global__ __launch_bounds__(256) void xcvt(const float* __restrict__ x,
                                            unsigned short* __restrict__ xhi,
                                            unsigned short* __restrict__ xlo) {
  int i = blockIdx.x * 256 + threadIdx.x;      // float4 slot
  if (i >= N_NODES * (F_IN / 4)) return;
  float4 v = reinterpret_cast<const float4*>(x)[i];
  ushort4 hi, lo;
  hi.x = f2bf(v.x); lo.x = f2bf(v.x - bf2f(hi.x));
  hi.y = f2bf(v.y); lo.y = f2bf(v.y - bf2f(hi.y));
  hi.z = f2bf(v.z); lo.z = f2bf(v.z - bf2f(hi.z));
  hi.w = f2bf(v.w); lo.w = f2bf(v.w - bf2f(hi.w));
  reinterpret_cast<ushort4*>(xhi)[i] = hi;
  reinterpret_cast<ushort4*>(xlo)[i] = lo;
}

// ---- build transposed bf16 hi/lo weights ----
__global__ __launch_bounds__(256) void build_wT(const float* __restrict__ W_root,
                                                const float* __restrict__ W_rel,
                                                const float* __restrict__ W_gat,
                                                unsigned short* __restrict__ WbT_hi,
                                                unsigned short* __restrict__ WbT_lo,
                                                unsigned short* __restrict__ WgT_hi,
                                                unsigned short* __restrict__ WgT_lo) {
  int i = blockIdx.x * 256 + threadIdx.x;
  if (i < MBIG * F_IN) {               // WbigT[c][k]
    int c = i / F_IN, k = i % F_IN;
    float w = (c < H1) ? W_root[k * H1 + c]
                       : W_rel[((size_t)(((c - H1) >> 6) * F_IN + k)) * H1 + ((c - H1) & 63)];
    unsigned short hi = f2bf(w);
    WbT_hi[i] = hi;
    WbT_lo[i] = f2bf(w - bf2f(hi));
  } else {
    int j = i - MBIG * F_IN;
    if (j < HOUT * H1) {               // WgatT[c][k]
      int c = j / H1, k = j % H1;
      float w = W_gat[k * HOUT + c];
      unsigned short hi = f2bf(w);
      WgT_hi[j] = hi;
      WgT_lo[j] = f2bf(w - bf2f(hi));
    }
  }
}

// ---- split-bf16 MFMA GEMM, register-direct, occupancy-filling:
//      block = 4 waves sharing the SAME 16 rows (A re-reads hit L1);
//      wave wv owns col-slice [wv*MW, (wv+1)*MW). A pre-split bf16 hi/lo.
//      No LDS, no barriers. Grid = N_PAD/16 = 3128 blocks = 12512 waves. ----
template <int K, int MW>
__global__ __launch_bounds__(256) void gemm_bf(const unsigned short* __restrict__ Ahi_,
                                               const unsigned short* __restrict__ Alo_,
                                               const unsigned short* __restrict__ BT_hi,
                                               const unsigned short* __restrict__ BT_lo,
                                               unsigned short* __restrict__ Cbf,
                                               int N, int M) {
  constexpr int NKS = K / 32;
  const int tid = threadIdx.x;
  const int wv = tid >> 6, lane = tid & 63;
  const int lrow = lane & 15, lkc = lane >> 4;
  const int row0 = blockIdx.x * 16;
  int ar = row0 + lrow;
  int ars = (ar < N) ? ar : 0;                 // clamp OOB rows (stores guarded)
  const unsigned short* aph = Ahi_ + (size_t)ars * K + lkc * 8;
  const unsigned short* apl = Alo_ + (size_t)ars * K + lkc * 8;
  bf16x8 ah[NKS], al[NKS];
#pragma unroll
  for (int ksi = 0; ksi < NKS; ++ksi) {
    ah[ksi] = *reinterpret_cast<const bf16x8*>(aph + ksi * 32);
    al[ksi] = *reinterpret_cast<const bf16x8*>(apl + ksi * 32);
  }
#pragma unroll
  for (int cf = 0; cf < MW / 16; ++cf) {
    int cb = wv * MW + cf * 16;
    const unsigned short* bph = BT_hi + (size_t)(cb + lrow) * K + lkc * 8;
    const unsigned short* bpl = BT_lo + (size_t)(cb + lrow) * K + lkc * 8;
    f32x4 acc = {};
#pragma unroll
    for (int ksi = 0; ksi < NKS; ++ksi) {
      bf16x8 bh = *reinterpret_cast<const bf16x8*>(bph + ksi * 32);
      bf16x8 bl = *reinterpret_cast<const bf16x8*>(bpl + ksi * 32);
      acc = __builtin_amdgcn_mfma_f32_16x16x32_bf16(ah[ksi], bh, acc, 0, 0, 0);
      acc = __builtin_amdgcn_mfma_f32_16x16x32_bf16(ah[ksi], bl, acc, 0, 0, 0);
      acc = __builtin_amdgcn_mfma_f32_16x16x32_bf16(al[ksi], bh, acc, 0, 0, 0);
    }
    // C/D: col = lane&15, row = (lane>>4)*4 + i
#pragma unroll
    for (int i = 0; i < 4; ++i) {
      int row = row0 + lkc * 4 + i;
      if (row < N) Cbf[(size_t)row * M + cb + lrow] = f2bf(acc[i]);
    }
  }
}

// ---- CSR build: histogram of dst + per-edge rank (coalesced store) ----
__global__ __launch_bounds__(256) void k_hist(const int* __restrict__ dst,
                                              int* __restrict__ deg,
                                              int* __restrict__ rank) {
  int e = blockIdx.x * 256 + threadIdx.x;
  if (e < N_EDGES) rank[e] = atomicAdd(&deg[dst[e]], 1);
}

// ---- scan stage 1: per-block sums ----
__global__ __launch_bounds__(256) void k_s1(const int* __restrict__ deg,
                                            int* __restrict__ bsum) {
  __shared__ int ss[256];
  int t = threadIdx.x;
  int i = blockIdx.x * 256 + t;
  ss[t] = (i < N_NODES) ? deg[i] : 0;
  __syncthreads();
  for (int d = 128; d > 0; d >>= 1) {
    if (t < d) ss[t] += ss[t + d];
    __syncthreads();
  }
  if (t == 0) bsum[blockIdx.x] = ss[0];
}

// ---- scan stage 2: exclusive scan of block sums ----
__global__ __launch_bounds__(256) void k_s2(const int* __restrict__ bsum,
                                            int* __restrict__ bbase,
                                            int* __restrict__ off) {
  __shared__ int ss[256];
  int t = threadIdx.x;
  int v = (t < NBLK) ? bsum[t] : 0;
  ss[t] = v;
  __syncthreads();
  for (int d = 1; d < 256; d <<= 1) {
    int u = (t >= d) ? ss[t - d] : 0;
    __syncthreads();
    ss[t] += u;
    __syncthreads();
  }
  if (t < NBLK) bbase[t] = ss[t] - v;
  if (t == NBLK - 1) off[N_NODES] = ss[t];
}

// ---- scan stage 3: block-local scan + base ----
__global__ __launch_bounds__(256) void k_s3(const int* __restrict__ deg,
                                            const int* __restrict__ bbase,
                                            int* __restrict__ off) {
  __shared__ int ss[256];
  int t = threadIdx.x;
  int i = blockIdx.x * 256 + t;
  int v = (i < N_NODES) ? deg[i] : 0;
  ss[t] = v;
  __syncthreads();
  for (int d = 1; d < 256; d <<= 1) {
    int u = (t >= d) ? ss[t - d] : 0;
    __syncthreads();
    ss[t] += u;
    __syncthreads();
  }
  if (i < N_NODES) off[i] = bbase[blockIdx.x] + ss[t] - v;
}

// ---- CSR fill: atomic-free — pos = off[dst] + rank; scatter store ----
__global__ __launch_bounds__(256) void k_fill(const int* __restrict__ src,
                                              const int* __restrict__ dst,
                                              const int* __restrict__ etype,
                                              const int* __restrict__ off,
                                              const int* __restrict__ rank,
                                              int* __restrict__ eprep) {
  int e = blockIdx.x * 256 + threadIdx.x;
  if (e >= N_EDGES) return;
  int pos = off[dst[e]] + rank[e];
  eprep[pos] = src[e] | (etype[e] << 16);
}

// ---- RGCN: gather from bf16 xt; wave/node; emits h as bf16 hi/lo ----
__global__ __launch_bounds__(256) void rgcn_gather(const unsigned short* __restrict__ xtbf,
                                                   const int* __restrict__ off,
                                                   const int* __restrict__ eprep,
                                                   const float* __restrict__ b_rgcn,
                                                   unsigned short* __restrict__ hhi,
                                                   unsigned short* __restrict__ hlo) {
  int wid = (blockIdx.x * 256 + threadIdx.x) >> 6;
  int lane = threadIdx.x & 63;
  int half = lane >> 5;
  int cp = lane & 31;
  int start = off[wid], end = off[wid + 1];
  float a0x=0.f,a0y=0.f,a1x=0.f,a1y=0.f,a2x=0.f,a2y=0.f,a3x=0.f,a3y=0.f;
  int c0=0,c1=0,c2=0,c3=0;
  int niter = (end - start + 1) >> 1;
  for (int t = 0; t < niter; t += 2) {
    int idx0 = start + 2 * t + half;
    int idx1 = idx0 + 2;
    int p0 = (idx0 < end) ? eprep[idx0] : 0x70000;
    int p1 = (idx1 < end) ? eprep[idx1] : 0x70000;
    int s0 = p0 & 0xFFFF, r0 = p0 >> 16;
    int s1 = p1 & 0xFFFF, r1 = p1 >> 16;
    unsigned u0 = *reinterpret_cast<const unsigned*>(
        &xtbf[(size_t)s0 * MBIG + H1 + (r0 << 6) + cp * 2]);
    unsigned u1 = *reinterpret_cast<const unsigned*>(
        &xtbf[(size_t)s1 * MBIG + H1 + (r1 << 6) + cp * 2]);
    float v0x = bflo(u0), v0y = bfhi(u0);
    float v1x = bflo(u1), v1y = bfhi(u1);
    a0x += (r0==0)?v0x:0.f; a0y += (r0==0)?v0y:0.f; c0 += (r0==0);
    a1x += (r0==1)?v0x:0.f; a1y += (r0==1)?v0y:0.f; c1 += (r0==1);
    a2x += (r0==2)?v0x:0.f; a2y += (r0==2)?v0y:0.f; c2 += (r0==2);
    a3x += (r0==3)?v0x:0.f; a3y += (r0==3)?v0y:0.f; c3 += (r0==3);
    a0x += (r1==0)?v1x:0.f; a0y += (r1==0)?v1y:0.f; c0 += (r1==0);
    a1x += (r1==1)?v1x:0.f; a1y += (r1==1)?v1y:0.f; c1 += (r1==1);
    a2x += (r1==2)?v1x:0.f; a2y += (r1==2)?v1y:0.f; c2 += (r1==2);
    a3x += (r1==3)?v1x:0.f; a3y += (r1==3)?v1y:0.f; c3 += (r1==3);
  }
  a0x += __shfl_xor(a0x, 32); a0y += __shfl_xor(a0y, 32);
  a1x += __shfl_xor(a1x, 32); a1y += __shfl_xor(a1y, 32);
  a2x += __shfl_xor(a2x, 32); a2y += __shfl_xor(a2y, 32);
  a3x += __shfl_xor(a3x, 32); a3y += __shfl_xor(a3y, 32);
  c0 += __shfl_xor(c0, 32); c1 += __shfl_xor(c1, 32);
  c2 += __shfl_xor(c2, 32); c3 += __shfl_xor(c3, 32);
  if (half == 0) {
    unsigned ur = *reinterpret_cast<const unsigned*>(&xtbf[(size_t)wid * MBIG + cp * 2]);
    float2 bb = *reinterpret_cast<const float2*>(&b_rgcn[cp * 2]);
    float i0 = 1.0f / (float)max(c0, 1);
    float i1 = 1.0f / (float)max(c1, 1);
    float i2 = 1.0f / (float)max(c2, 1);
    float i3 = 1.0f / (float)max(c3, 1);
    float vx = bflo(ur) + bb.x + a0x * i0 + a1x * i1 + a2x * i2 + a3x * i3;
    float vy = bfhi(ur) + bb.y + a0y * i0 + a1y * i1 + a2y * i2 + a3y * i3;
    vx = fmaxf(vx, 0.f);
    vy = fmaxf(vy, 0.f);
    unsigned short hx = f2bf(vx), hy = f2bf(vy);
    ushort2 hv = {hx, hy};
    ushort2 lv = {f2bf(vx - bf2f(hx)), f2bf(vy - bf2f(hy))};
    *reinterpret_cast<ushort2*>(&hhi[(size_t)wid * H1 + cp * 2]) = hv;
    *reinterpret_cast<ushort2*>(&hlo[(size_t)wid * H1 + cp * 2]) = lv;
  }
}

// ---- attention coefficients from bf16 g, LDS-staged ----
__global__ __launch_bounds__(256) void gat_att(const unsigned short* __restrict__ gbf,
                                               const float* __restrict__ att_src,
                                               const float* __restrict__ att_dst,
                                               float* __restrict__ a_s,
                                               float* __restrict__ a_d) {
  __shared__ float gs[64][129];
  __shared__ float asrc[HOUT], adst[HOUT];
  int t = threadIdx.x;
  if (t < HOUT) { asrc[t] = att_src[t]; adst[t] = att_dst[t]; }
  int nb = blockIdx.x * 64;
#pragma unroll
  for (int it = 0; it < 8; ++it) {
    int idx = it * 256 + t;
    int r = idx >> 5, c4 = (idx & 31) * 4;
    int gn = nb + r;
    uint2 v = make_uint2(0u, 0u);
    if (gn < N_NODES)
      v = *reinterpret_cast<const uint2*>(&gbf[(size_t)gn * HOUT + c4]);
    gs[r][c4 + 0] = bflo(v.x); gs[r][c4 + 1] = bfhi(v.x);
    gs[r][c4 + 2] = bflo(v.y); gs[r][c4 + 3] = bfhi(v.y);
  }
  __syncthreads();
  int n = t & 63, hh = t >> 6;
  float s = 0.f, d = 0.f;
#pragma unroll
  for (int k = 0; k < D_H; ++k) {
    float gv = gs[n][hh * D_H + k];
    s += gv * asrc[hh * D_H + k];
    d += gv * adst[hh * D_H + k];
  }
  if (nb + n < N_NODES) {
    a_s[(size_t)(nb + n) * 4 + hh] = s;
    a_d[(size_t)(nb + n) * 4 + hh] = d;
  }
}

// ---- init mono buffer ----
__global__ __launch_bounds__(256) void init_mono(unsigned* __restrict__ p, int count) {
  int i = blockIdx.x * 256 + threadIdx.x;
  if (i < count) p[i] = MONO_NEG_INF;
}

// ---- GAT + head fused ----
constexpr int GAT_BLOCKS = 2048;
constexpr int GAT_WAVES = GAT_BLOCKS * 4;   // 8192
__global__ __launch_bounds__(256) void gat_fused(const unsigned short* __restrict__ gbf,
                                                 const float* __restrict__ a_s,
                                                 const float* __restrict__ a_d,
                                                 const int* __restrict__ off,
                                                 const int* __restrict__ eprep,
                                                 const float* __restrict__ b_gat,
                                                 const float* __restrict__ W1,
                                                 const float* __restrict__ b1,
                                                 const int* __restrict__ batch,
                                                 unsigned* __restrict__ p_mono) {
  __shared__ float w1s[HOUT * 16];        // W1[k][j]
  __shared__ float ob[4][HOUT];           // per-wave o row
  __shared__ unsigned sp[N_GRAPHS * 16];
  const int t = threadIdx.x;
  for (int i = t; i < HOUT * 16; i += 256) w1s[i] = W1[i];
  for (int i = t; i < N_GRAPHS * 16; i += 256) sp[i] = MONO_NEG_INF;
  __syncthreads();
  const int wv = t >> 6, lane = t & 63;
  const int hh = lane >> 4;
  const int jj = lane & 15, grp = lane >> 4;
  const int w = blockIdx.x * 4 + wv;
  const int q = N_NODES / GAT_WAVES;
  const int r = N_NODES % GAT_WAVES;
  const int nbeg = w * q + ((w < r) ? w : r);
  const int ncnt = q + ((w < r) ? 1 : 0);
  for (int wid = nbeg; wid < nbeg + ncnt; ++wid) {
    int start = off[wid], end = off[wid + 1];
    float4 ad4 = *reinterpret_cast<const float4*>(a_d + (size_t)wid * 4);
    float adh = (hh == 0) ? ad4.x : (hh == 1) ? ad4.y : (hh == 2) ? ad4.z : ad4.w;
    float ox = 0.f, oy = 0.f, den = 0.f;
    int i = start;
    for (; i + 4 <= end; i += 4) {
      int p0 = eprep[i], p1 = eprep[i + 1], p2 = eprep[i + 2], p3 = eprep[i + 3];
      int s0 = p0 & 0xFFFF, s1 = p1 & 0xFFFF, s2 = p2 & 0xFFFF, s3 = p3 & 0xFFFF;
      float as0 = a_s[(size_t)s0 * 4 + hh];
      float as1 = a_s[(size_t)s1 * 4 + hh];
      float as2 = a_s[(size_t)s2 * 4 + hh];
      float as3 = a_s[(size_t)s3 * 4 + hh];
      unsigned u0 = *reinterpret_cast<const unsigned*>(&gbf[(size_t)s0 * HOUT + lane * 2]);
      unsigned u1 = *reinterpret_cast<const unsigned*>(&gbf[(size_t)s1 * HOUT + lane * 2]);
      unsigned u2 = *reinterpret_cast<const unsigned*>(&gbf[(size_t)s2 * HOUT + lane * 2]);
      unsigned u3 = *reinterpret_cast<const unsigned*>(&gbf[(size_t)s3 * HOUT + lane * 2]);
      float e0 = as0 + adh; e0 = (e0 > 0.f) ? e0 : 0.2f * e0;
      float e1 = as1 + adh; e1 = (e1 > 0.f) ? e1 : 0.2f * e1;
      float e2 = as2 + adh; e2 = (e2 > 0.f) ? e2 : 0.2f * e2;
      float e3 = as3 + adh; e3 = (e3 > 0.f) ? e3 : 0.2f * e3;
      float x0 = __expf(e0), x1 = __expf(e1), x2 = __expf(e2), x3 = __expf(e3);
      den += x0 + x1 + x2 + x3;
      ox += x0 * bflo(u0) + x1 * bflo(u1) + x2 * bflo(u2) + x3 * bflo(u3);
      oy += x0 * bfhi(u0) + x1 * bfhi(u1) + x2 * bfhi(u2) + x3 * bfhi(u3);
    }
    for (; i < end; ++i) {
      int p = eprep[i];
      int s = p & 0xFFFF;
      float as = a_s[(size_t)s * 4 + hh];
      unsigned u = *reinterpret_cast<const unsigned*>(&gbf[(size_t)s * HOUT + lane * 2]);
      float e = as + adh; e = (e > 0.f) ? e : 0.2f * e;
      float ex = __expf(e);
      den += ex;
      ox += ex * bflo(u);
      oy += ex * bfhi(u);
    }
    float dinv = (den > 0.f) ? (1.0f / den) : 0.f;
    float2 bg = *reinterpret_cast<const float2*>(b_gat + lane * 2);
    float vx = ox * dinv + bg.x; vx = (vx > 0.f) ? vx : 0.01f * vx;
    float vy = oy * dinv + bg.y; vy = (vy > 0.f) ? vy : 0.01f * vy;
    *reinterpret_cast<float2*>(&ob[wv][lane * 2]) = make_float2(vx, vy);
    float acc = 0.f;
#pragma unroll 8
    for (int i2 = 0; i2 < 32; ++i2) {
      int c = grp + 4 * i2;
      acc += ob[wv][c] * w1s[c * 16 + jj];
    }
    acc += __shfl_xor(acc, 16);
    acc += __shfl_xor(acc, 32);
    float z = acc + b1[jj];
    z = (z > 0.f) ? z : 0.01f * z;
    int b = batch[wid];
    if (lane < 16) atomicMax(&sp[b * 16 + jj], f2mono(z));
  }
  __syncthreads();
  for (int i = t; i < N_GRAPHS * 16; i += 256) {
    unsigned v = sp[i];
    if (v != MONO_NEG_INF) atomicMax(p_mono + i, v);
  }
}

// ---- y = p @ W2 + b2 ----
__global__ void final_y(const unsigned* __restrict__ p_mono,
                        const float* __restrict__ W2,
                        const float* __restrict__ b2,
                        float* __restrict__ y) {
  int gr = threadIdx.x;
  if (gr >= N_GRAPHS) return;
  float acc = b2[0];
#pragma unroll
  for (int k = 0; k < 16; ++k) acc += mono2f(p_mono[gr * 16 + k]) * W2[k];
  y[gr] = acc;
}

extern "C" void kernel_launch(void* const* d_in, const int* in_sizes, int n_in,
                              void* d_out, int out_size, void* d_ws, size_t ws_size,
                              hipStream_t stream) {
  const float* x       = (const float*)d_in[0];
  const int*   eidx    = (const int*)d_in[1];
  const int*   etype   = (const int*)d_in[2];
  const int*   batch   = (const int*)d_in[3];
  const float* W_rel   = (const float*)d_in[4];
  const float* W_root  = (const float*)d_in[5];
  const float* b_rgcn  = (const float*)d_in[6];
  const float* W_gat   = (const float*)d_in[7];
  const float* att_src = (const float*)d_in[8];
  const float* att_dst = (const float*)d_in[9];
  const float* b_gat   = (const float*)d_in[10];
  const float* W1      = (const float*)d_in[11];
  const float* b1      = (const float*)d_in[12];
  const float* W2      = (const float*)d_in[13];
  const float* b2      = (const float*)d_in[14];
  float* y = (float*)d_out;

  const int* src = eidx;
  const int* dst = eidx + N_EDGES;

  float* ws = (float*)d_ws;
  // ---- workspace layout (float offsets) ----
  const size_t OFF_XTBF= 0;           //  8,007,680 f: xt bf16 [N_PAD,320]
  const size_t OFF_GBF = 0;           //  g bf16 [N_PAD,128] (reuses xtbf)
  const size_t OFF_XHI = 8007680;     //  3,203,072 f: x hi bf16 [N_PAD,128]
  const size_t OFF_XLO = 11210752;    //  3,203,072 f: x lo
  const size_t OFF_HHI = 14413824;    //  1,601,536 f: h hi bf16 [N_PAD,64]
  const size_t OFF_HLO = 16015360;    //  1,601,536 f: h lo
  const size_t OFF_AS  = 17616896;    //    200,000  a_src
  const size_t OFF_AD  = 17816896;    //    200,000  a_dst
  const size_t OFF_PM  = 18016896;    //        256  pool max (1024 u32)
  const size_t OFF_DEG = 18017152;    //     50,000  deg (int)
  const size_t OFF_OFFS= 18067152;    //     50,001  off (int)
  const size_t OFF_RANK= 18117156;    //    800,000  rank (int)
  const size_t OFF_EP  = 18917156;    //    800,000  eprep (int)
  const size_t OFF_BS  = 19717156;    //        196
  const size_t OFF_BB  = 19717352;    //        196
  const size_t OFF_WBH = 19717552;    //     20,480  WbigT_hi (16B aligned)
  const size_t OFF_WBL = 19738032;    //     20,480  WbigT_lo
  const size_t OFF_WGH = 19758512;    //      4,096  WgatT_hi
  const size_t OFF_WGL = 19762608;    //      4,096  WgatT_lo
  const size_t TOTAL_F = 19766704;
  if (ws_size < TOTAL_F * sizeof(float)) return;

  unsigned short* xtbf = (unsigned short*)(ws + OFF_XTBF);
  unsigned short* gbf  = (unsigned short*)(ws + OFF_GBF);
  unsigned short* xhi  = (unsigned short*)(ws + OFF_XHI);
  unsigned short* xlo  = (unsigned short*)(ws + OFF_XLO);
  unsigned short* hhi  = (unsigned short*)(ws + OFF_HHI);
  unsigned short* hlo  = (unsigned short*)(ws + OFF_HLO);
  float* a_s   = ws + OFF_AS;
  float* a_d   = ws + OFF_AD;
  unsigned* pm = (unsigned*)(ws + OFF_PM);
  int* deg     = (int*)(ws + OFF_DEG);
  int* offs    = (int*)(ws + OFF_OFFS);
  int* rank    = (int*)(ws + OFF_RANK);
  int* eprep   = (int*)(ws + OFF_EP);
  int* bsum    = (int*)(ws + OFF_BS);
  int* bbase   = (int*)(ws + OFF_BB);
  unsigned short* wbt_hi = (unsigned short*)(ws + OFF_WBH);
  unsigned short* wbt_lo = (unsigned short*)(ws + OFF_WBL);
  unsigned short* wgt_hi = (unsigned short*)(ws + OFF_WGH);
  unsigned short* wgt_lo = (unsigned short*)(ws + OFF_WGL);

  // CSR build (atomic-free fill)
  hipMemsetAsync(deg, 0, N_NODES * sizeof(int), stream);
  k_hist<<<(N_EDGES + 255) / 256, 256, 0, stream>>>(dst, deg, rank);
  k_s1<<<NBLK, 256, 0, stream>>>(deg, bsum);
  k_s2<<<1, 256, 0, stream>>>(bsum, bbase, offs);
  k_s3<<<NBLK, 256, 0, stream>>>(deg, bbase, offs);
  k_fill<<<(N_EDGES + 255) / 256, 256, 0, stream>>>(src, dst, etype, offs, rank, eprep);

  // weights + x split to bf16 hi/lo
  build_wT<<<(MBIG * F_IN + HOUT * H1 + 255) / 256, 256, 0, stream>>>(
      W_root, W_rel, W_gat, wbt_hi, wbt_lo, wgt_hi, wgt_lo);
  xcvt<<<(N_NODES * (F_IN / 4) + 255) / 256, 256, 0, stream>>>(x, xhi, xlo);

  // xt(bf16) = x @ [W_root | W_rel]  (register-direct, full-occupancy)
  gemm_bf<128, 80><<<N_PAD / 16, 256, 0, stream>>>(xhi, xlo, wbt_hi, wbt_lo,
                                                   xtbf, N_NODES, MBIG);

  // RGCN gather -> h (bf16 hi/lo, emitted directly)
  rgcn_gather<<<N_NODES / 4, 256, 0, stream>>>(xtbf, offs, eprep, b_rgcn, hhi, hlo);

  // g(bf16) = h @ W_gat
  gemm_bf<64, 32><<<N_PAD / 16, 256, 0, stream>>>(hhi, hlo, wgt_hi, wgt_lo,
                                                  gbf, N_NODES, HOUT);

  // attention coefficients
  gat_att<<<(N_NODES + 63) / 64, 256, 0, stream>>>(gbf, att_src, att_dst, a_s, a_d);

  // fused GAT aggregation + head + per-graph max pool
  init_mono<<<(N_GRAPHS * 16 + 255) / 256, 256, 0, stream>>>(pm, N_GRAPHS * 16);
  gat_fused<<<GAT_BLOCKS, 256, 0, stream>>>(gbf, a_s, a_d, offs, eprep, b_gat,
                                            W1, b1, batch, pm);

  // y = p @ W2 + b2
  final_y<<<1, 64, 0, stream>>>(pm, W2, b2, y);
}

// Round 11
// 263.387 us; speedup vs baseline: 1.0036x; 1.0036x over previous
//
#include <hip/hip_runtime.h>
#include <hip/hip_bf16.h>

constexpr int N_NODES = 50000;
constexpr int N_EDGES = 800000;
constexpr int F_IN = 128;
constexpr int H1 = 64;
constexpr int HEADS = 4;
constexpr int D_H = 32;
constexpr int HOUT = HEADS * D_H;       // 128
constexpr int N_REL = 4;
constexpr int N_GRAPHS = 64;
constexpr int MBIG = H1 * (1 + N_REL);  // 320
constexpr int NBLK = (N_NODES + 255) / 256;  // 196
constexpr int N_PAD = 50048;            // rows padded to 64*782

typedef __attribute__((ext_vector_type(8))) short bf16x8;
typedef __attribute__((ext_vector_type(4))) float f32x4;

// ---- monotonic float<->uint for atomicMax on floats ----
__device__ __forceinline__ unsigned f2mono(float f) {
  unsigned u = __float_as_uint(f);
  return (u & 0x80000000u) ? ~u : (u | 0x80000000u);
}
__device__ __forceinline__ float mono2f(unsigned m) {
  unsigned u = (m & 0x80000000u) ? (m & 0x7FFFFFFFu) : ~m;
  return __uint_as_float(u);
}
constexpr unsigned MONO_NEG_INF = 0x007FFFFFu;

// ---- bf16 helpers ----
__device__ __forceinline__ unsigned short f2bf(float f) {
  unsigned u = __float_as_uint(f);
  unsigned r = (u + 0x7FFFu + ((u >> 16) & 1u)) >> 16;  // RNE
  return (unsigned short)r;
}
__device__ __forceinline__ float bf2f(unsigned short h) {
  return __uint_as_float((unsigned)h << 16);
}
__device__ __forceinline__ float bflo(unsigned u) { return __uint_as_float(u << 16); }
__device__ __forceinline__ float bfhi(unsigned u) { return __uint_as_float(u & 0xFFFF0000u); }

// ---- split x (f32) -> xhi/xlo bf16, once ----
__global__ __launch_bounds__(256) void xcvt(const float* __restrict__ x,
                                            unsigned short* __restrict__ xhi,
                                            unsigned short* __restrict__ xlo) {
  int i = blockIdx.x * 256 + threadIdx.x;      // float4 slot
  if (i >= N_NODES * (F_IN / 4)) return;
  float4 v = reinterpret_cast<const float4*>(x)[i];
  ushort4 hi, lo;
  hi.x = f2bf(v.x); lo.x = f2bf(v.x - bf2f(hi.x));
  hi.y = f2bf(v.y); lo.y = f2bf(v.y - bf2f(hi.y));
  hi.z = f2bf(v.z); lo.z = f2bf(v.z - bf2f(hi.z));
  hi.w = f2bf(v.w); lo.w = f2bf(v.w - bf2f(hi.w));
  reinterpret_cast<ushort4*>(xhi)[i] = hi;
  reinterpret_cast<ushort4*>(xlo)[i] = lo;
}

// ---- build transposed bf16 hi/lo weights ----
__global__ __launch_bounds__(256) void build_wT(const float* __restrict__ W_root,
                                                const float* __restrict__ W_rel,
                                                const float* __restrict__ W_gat,
                                                unsigned short* __restrict__ WbT_hi,
                                                unsigned short* __restrict__ WbT_lo,
                                                unsigned short* __restrict__ WgT_hi,
                                                unsigned short* __restrict__ WgT_lo) {
  int i = blockIdx.x * 256 + threadIdx.x;
  if (i < MBIG * F_IN) {               // WbigT[c][k]
    int c = i / F_IN, k = i % F_IN;
    float w = (c < H1) ? W_root[k * H1 + c]
                       : W_rel[((size_t)(((c - H1) >> 6) * F_IN + k)) * H1 + ((c - H1) & 63)];
    unsigned short hi = f2bf(w);
    WbT_hi[i] = hi;
    WbT_lo[i] = f2bf(w - bf2f(hi));
  } else {
    int j = i - MBIG * F_IN;
    if (j < HOUT * H1) {               // WgatT[c][k]
      int c = j / H1, k = j % H1;
      float w = W_gat[k * HOUT + c];
      unsigned short hi = f2bf(w);
      WgT_hi[j] = hi;
      WgT_lo[j] = f2bf(w - bf2f(hi));
    }
  }
}

// ---- split-bf16 MFMA GEMM: block = 4 waves x (16 rows each) = 64 rows,
//      64-col tile via blockIdx.y. Wave owns 16x64 = 4 INDEPENDENT acc
//      fragments (ILP), A hi/lo in registers (pre-split), B fragments
//      from global — identical across the 4 waves (L1 broadcast).
//      No LDS, no barriers. ----
template <int K>
__global__ __launch_bounds__(256) void gemm_bf(const unsigned short* __restrict__ Ahi_,
                                               const unsigned short* __restrict__ Alo_,
                                               const unsigned short* __restrict__ BT_hi,
                                               const unsigned short* __restrict__ BT_lo,
                                               unsigned short* __restrict__ Cbf,
                                               int N, int M) {
  constexpr int NKS = K / 32;
  const int tid = threadIdx.x;
  const int wv = tid >> 6, lane = tid & 63;
  const int lrow = lane & 15, lkc = lane >> 4;
  const int row0 = blockIdx.x * 64 + wv * 16;
  const int colBase = blockIdx.y * 64;
  int ar = row0 + lrow;
  int ars = (ar < N) ? ar : 0;                 // clamp OOB rows (stores guarded)
  const unsigned short* aph = Ahi_ + (size_t)ars * K + lkc * 8;
  const unsigned short* apl = Alo_ + (size_t)ars * K + lkc * 8;
  bf16x8 ah[NKS], al[NKS];
#pragma unroll
  for (int ksi = 0; ksi < NKS; ++ksi) {
    ah[ksi] = *reinterpret_cast<const bf16x8*>(aph + ksi * 32);
    al[ksi] = *reinterpret_cast<const bf16x8*>(apl + ksi * 32);
  }
  f32x4 acc[4] = {};
#pragma unroll
  for (int ksi = 0; ksi < NKS; ++ksi) {
    bf16x8 bh[4], bl[4];
#pragma unroll
    for (int fc = 0; fc < 4; ++fc) {
      const unsigned short* bph = BT_hi + (size_t)(colBase + fc * 16 + lrow) * K + ksi * 32 + lkc * 8;
      const unsigned short* bpl = BT_lo + (size_t)(colBase + fc * 16 + lrow) * K + ksi * 32 + lkc * 8;
      bh[fc] = *reinterpret_cast<const bf16x8*>(bph);
      bl[fc] = *reinterpret_cast<const bf16x8*>(bpl);
    }
#pragma unroll
    for (int fc = 0; fc < 4; ++fc) {
      acc[fc] = __builtin_amdgcn_mfma_f32_16x16x32_bf16(ah[ksi], bh[fc], acc[fc], 0, 0, 0);
      acc[fc] = __builtin_amdgcn_mfma_f32_16x16x32_bf16(ah[ksi], bl[fc], acc[fc], 0, 0, 0);
      acc[fc] = __builtin_amdgcn_mfma_f32_16x16x32_bf16(al[ksi], bh[fc], acc[fc], 0, 0, 0);
    }
  }
  // C/D: col = lane&15, row = (lane>>4)*4 + i
#pragma unroll
  for (int fc = 0; fc < 4; ++fc) {
#pragma unroll
    for (int i = 0; i < 4; ++i) {
      int row = row0 + lkc * 4 + i;
      if (row < N) Cbf[(size_t)row * M + colBase + fc * 16 + lrow] = f2bf(acc[fc][i]);
    }
  }
}

// ---- CSR build: histogram of dst + per-edge rank (coalesced store) ----
__global__ __launch_bounds__(256) void k_hist(const int* __restrict__ dst,
                                              int* __restrict__ deg,
                                              int* __restrict__ rank) {
  int e = blockIdx.x * 256 + threadIdx.x;
  if (e < N_EDGES) rank[e] = atomicAdd(&deg[dst[e]], 1);
}

// ---- scan stage 1: per-block sums ----
__global__ __launch_bounds__(256) void k_s1(const int* __restrict__ deg,
                                            int* __restrict__ bsum) {
  __shared__ int ss[256];
  int t = threadIdx.x;
  int i = blockIdx.x * 256 + t;
  ss[t] = (i < N_NODES) ? deg[i] : 0;
  __syncthreads();
  for (int d = 128; d > 0; d >>= 1) {
    if (t < d) ss[t] += ss[t + d];
    __syncthreads();
  }
  if (t == 0) bsum[blockIdx.x] = ss[0];
}

// ---- scan stage 2: exclusive scan of block sums ----
__global__ __launch_bounds__(256) void k_s2(const int* __restrict__ bsum,
                                            int* __restrict__ bbase,
                                            int* __restrict__ off) {
  __shared__ int ss[256];
  int t = threadIdx.x;
  int v = (t < NBLK) ? bsum[t] : 0;
  ss[t] = v;
  __syncthreads();
  for (int d = 1; d < 256; d <<= 1) {
    int u = (t >= d) ? ss[t - d] : 0;
    __syncthreads();
    ss[t] += u;
    __syncthreads();
  }
  if (t < NBLK) bbase[t] = ss[t] - v;
  if (t == NBLK - 1) off[N_NODES] = ss[t];
}

// ---- scan stage 3: block-local scan + base ----
__global__ __launch_bounds__(256) void k_s3(const int* __restrict__ deg,
                                            const int* __restrict__ bbase,
                                            int* __restrict__ off) {
  __shared__ int ss[256];
  int t = threadIdx.x;
  int i = blockIdx.x * 256 + t;
  int v = (i < N_NODES) ? deg[i] : 0;
  ss[t] = v;
  __syncthreads();
  for (int d = 1; d < 256; d <<= 1) {
    int u = (t >= d) ? ss[t - d] : 0;
    __syncthreads();
    ss[t] += u;
    __syncthreads();
  }
  if (i < N_NODES) off[i] = bbase[blockIdx.x] + ss[t] - v;
}

// ---- CSR fill: atomic-free — pos = off[dst] + rank; scatter store ----
__global__ __launch_bounds__(256) void k_fill(const int* __restrict__ src,
                                              const int* __restrict__ dst,
                                              const int* __restrict__ etype,
                                              const int* __restrict__ off,
                                              const int* __restrict__ rank,
                                              int* __restrict__ eprep) {
  int e = blockIdx.x * 256 + threadIdx.x;
  if (e >= N_EDGES) return;
  int pos = off[dst[e]] + rank[e];
  eprep[pos] = src[e] | (etype[e] << 16);
}

// ---- RGCN: gather from bf16 xt; wave/node; emits h as bf16 hi/lo ----
__global__ __launch_bounds__(256) void rgcn_gather(const unsigned short* __restrict__ xtbf,
                                                   const int* __restrict__ off,
                                                   const int* __restrict__ eprep,
                                                   const float* __restrict__ b_rgcn,
                                                   unsigned short* __restrict__ hhi,
                                                   unsigned short* __restrict__ hlo) {
  int wid = (blockIdx.x * 256 + threadIdx.x) >> 6;
  int lane = threadIdx.x & 63;
  int half = lane >> 5;
  int cp = lane & 31;
  int start = off[wid], end = off[wid + 1];
  float a0x=0.f,a0y=0.f,a1x=0.f,a1y=0.f,a2x=0.f,a2y=0.f,a3x=0.f,a3y=0.f;
  int c0=0,c1=0,c2=0,c3=0;
  int niter = (end - start + 1) >> 1;
  for (int t = 0; t < niter; t += 2) {
    int idx0 = start + 2 * t + half;
    int idx1 = idx0 + 2;
    int p0 = (idx0 < end) ? eprep[idx0] : 0x70000;
    int p1 = (idx1 < end) ? eprep[idx1] : 0x70000;
    int s0 = p0 & 0xFFFF, r0 = p0 >> 16;
    int s1 = p1 & 0xFFFF, r1 = p1 >> 16;
    unsigned u0 = *reinterpret_cast<const unsigned*>(
        &xtbf[(size_t)s0 * MBIG + H1 + (r0 << 6) + cp * 2]);
    unsigned u1 = *reinterpret_cast<const unsigned*>(
        &xtbf[(size_t)s1 * MBIG + H1 + (r1 << 6) + cp * 2]);
    float v0x = bflo(u0), v0y = bfhi(u0);
    float v1x = bflo(u1), v1y = bfhi(u1);
    a0x += (r0==0)?v0x:0.f; a0y += (r0==0)?v0y:0.f; c0 += (r0==0);
    a1x += (r0==1)?v0x:0.f; a1y += (r0==1)?v0y:0.f; c1 += (r0==1);
    a2x += (r0==2)?v0x:0.f; a2y += (r0==2)?v0y:0.f; c2 += (r0==2);
    a3x += (r0==3)?v0x:0.f; a3y += (r0==3)?v0y:0.f; c3 += (r0==3);
    a0x += (r1==0)?v1x:0.f; a0y += (r1==0)?v1y:0.f; c0 += (r1==0);
    a1x += (r1==1)?v1x:0.f; a1y += (r1==1)?v1y:0.f; c1 += (r1==1);
    a2x += (r1==2)?v1x:0.f; a2y += (r1==2)?v1y:0.f; c2 += (r1==2);
    a3x += (r1==3)?v1x:0.f; a3y += (r1==3)?v1y:0.f; c3 += (r1==3);
  }
  a0x += __shfl_xor(a0x, 32); a0y += __shfl_xor(a0y, 32);
  a1x += __shfl_xor(a1x, 32); a1y += __shfl_xor(a1y, 32);
  a2x += __shfl_xor(a2x, 32); a2y += __shfl_xor(a2y, 32);
  a3x += __shfl_xor(a3x, 32); a3y += __shfl_xor(a3y, 32);
  c0 += __shfl_xor(c0, 32); c1 += __shfl_xor(c1, 32);
  c2 += __shfl_xor(c2, 32); c3 += __shfl_xor(c3, 32);
  if (half == 0) {
    unsigned ur = *reinterpret_cast<const unsigned*>(&xtbf[(size_t)wid * MBIG + cp * 2]);
    float2 bb = *reinterpret_cast<const float2*>(&b_rgcn[cp * 2]);
    float i0 = 1.0f / (float)max(c0, 1);
    float i1 = 1.0f / (float)max(c1, 1);
    float i2 = 1.0f / (float)max(c2, 1);
    float i3 = 1.0f / (float)max(c3, 1);
    float vx = bflo(ur) + bb.x + a0x * i0 + a1x * i1 + a2x * i2 + a3x * i3;
    float vy = bfhi(ur) + bb.y + a0y * i0 + a1y * i1 + a2y * i2 + a3y * i3;
    vx = fmaxf(vx, 0.f);
    vy = fmaxf(vy, 0.f);
    unsigned short hx = f2bf(vx), hy = f2bf(vy);
    ushort2 hv = {hx, hy};
    ushort2 lv = {f2bf(vx - bf2f(hx)), f2bf(vy - bf2f(hy))};
    *reinterpret_cast<ushort2*>(&hhi[(size_t)wid * H1 + cp * 2]) = hv;
    *reinterpret_cast<ushort2*>(&hlo[(size_t)wid * H1 + cp * 2]) = lv;
  }
}

// ---- attention coefficients from bf16 g, LDS-staged ----
__global__ __launch_bounds__(256) void gat_att(const unsigned short* __restrict__ gbf,
                                               const float* __restrict__ att_src,
                                               const float* __restrict__ att_dst,
                                               float* __restrict__ a_s,
                                               float* __restrict__ a_d) {
  __shared__ float gs[64][129];
  __shared__ float asrc[HOUT], adst[HOUT];
  int t = threadIdx.x;
  if (t < HOUT) { asrc[t] = att_src[t]; adst[t] = att_dst[t]; }
  int nb = blockIdx.x * 64;
#pragma unroll
  for (int it = 0; it < 8; ++it) {
    int idx = it * 256 + t;
    int r = idx >> 5, c4 = (idx & 31) * 4;
    int gn = nb + r;
    uint2 v = make_uint2(0u, 0u);
    if (gn < N_NODES)
      v = *reinterpret_cast<const uint2*>(&gbf[(size_t)gn * HOUT + c4]);
    gs[r][c4 + 0] = bflo(v.x); gs[r][c4 + 1] = bfhi(v.x);
    gs[r][c4 + 2] = bflo(v.y); gs[r][c4 + 3] = bfhi(v.y);
  }
  __syncthreads();
  int n = t & 63, hh = t >> 6;
  float s = 0.f, d = 0.f;
#pragma unroll
  for (int k = 0; k < D_H; ++k) {
    float gv = gs[n][hh * D_H + k];
    s += gv * asrc[hh * D_H + k];
    d += gv * adst[hh * D_H + k];
  }
  if (nb + n < N_NODES) {
    a_s[(size_t)(nb + n) * 4 + hh] = s;
    a_d[(size_t)(nb + n) * 4 + hh] = d;
  }
}

// ---- init mono buffer ----
__global__ __launch_bounds__(256) void init_mono(unsigned* __restrict__ p, int count) {
  int i = blockIdx.x * 256 + threadIdx.x;
  if (i < count) p[i] = MONO_NEG_INF;
}

// ---- GAT + head fused ----
constexpr int GAT_BLOCKS = 2048;
constexpr int GAT_WAVES = GAT_BLOCKS * 4;   // 8192
__global__ __launch_bounds__(256) void gat_fused(const unsigned short* __restrict__ gbf,
                                                 const float* __restrict__ a_s,
                                                 const float* __restrict__ a_d,
                                                 const int* __restrict__ off,
                                                 const int* __restrict__ eprep,
                                                 const float* __restrict__ b_gat,
                                                 const float* __restrict__ W1,
                                                 const float* __restrict__ b1,
                                                 const int* __restrict__ batch,
                                                 unsigned* __restrict__ p_mono) {
  __shared__ float w1s[HOUT * 16];        // W1[k][j]
  __shared__ float ob[4][HOUT];           // per-wave o row
  __shared__ unsigned sp[N_GRAPHS * 16];
  const int t = threadIdx.x;
  for (int i = t; i < HOUT * 16; i += 256) w1s[i] = W1[i];
  for (int i = t; i < N_GRAPHS * 16; i += 256) sp[i] = MONO_NEG_INF;
  __syncthreads();
  const int wv = t >> 6, lane = t & 63;
  const int hh = lane >> 4;
  const int jj = lane & 15, grp = lane >> 4;
  const int w = blockIdx.x * 4 + wv;
  const int q = N_NODES / GAT_WAVES;
  const int r = N_NODES % GAT_WAVES;
  const int nbeg = w * q + ((w < r) ? w : r);
  const int ncnt = q + ((w < r) ? 1 : 0);
  for (int wid = nbeg; wid < nbeg + ncnt; ++wid) {
    int start = off[wid], end = off[wid + 1];
    float4 ad4 = *reinterpret_cast<const float4*>(a_d + (size_t)wid * 4);
    float adh = (hh == 0) ? ad4.x : (hh == 1) ? ad4.y : (hh == 2) ? ad4.z : ad4.w;
    float ox = 0.f, oy = 0.f, den = 0.f;
    int i = start;
    for (; i + 4 <= end; i += 4) {
      int p0 = eprep[i], p1 = eprep[i + 1], p2 = eprep[i + 2], p3 = eprep[i + 3];
      int s0 = p0 & 0xFFFF, s1 = p1 & 0xFFFF, s2 = p2 & 0xFFFF, s3 = p3 & 0xFFFF;
      float as0 = a_s[(size_t)s0 * 4 + hh];
      float as1 = a_s[(size_t)s1 * 4 + hh];
      float as2 = a_s[(size_t)s2 * 4 + hh];
      float as3 = a_s[(size_t)s3 * 4 + hh];
      unsigned u0 = *reinterpret_cast<const unsigned*>(&gbf[(size_t)s0 * HOUT + lane * 2]);
      unsigned u1 = *reinterpret_cast<const unsigned*>(&gbf[(size_t)s1 * HOUT + lane * 2]);
      unsigned u2 = *reinterpret_cast<const unsigned*>(&gbf[(size_t)s2 * HOUT + lane * 2]);
      unsigned u3 = *reinterpret_cast<const unsigned*>(&gbf[(size_t)s3 * HOUT + lane * 2]);
      float e0 = as0 + adh; e0 = (e0 > 0.f) ? e0 : 0.2f * e0;
      float e1 = as1 + adh; e1 = (e1 > 0.f) ? e1 : 0.2f * e1;
      float e2 = as2 + adh; e2 = (e2 > 0.f) ? e2 : 0.2f * e2;
      float e3 = as3 + adh; e3 = (e3 > 0.f) ? e3 : 0.2f * e3;
      float x0 = __expf(e0), x1 = __expf(e1), x2 = __expf(e2), x3 = __expf(e3);
      den += x0 + x1 + x2 + x3;
      ox += x0 * bflo(u0) + x1 * bflo(u1) + x2 * bflo(u2) + x3 * bflo(u3);
      oy += x0 * bfhi(u0) + x1 * bfhi(u1) + x2 * bfhi(u2) + x3 * bfhi(u3);
    }
    for (; i < end; ++i) {
      int p = eprep[i];
      int s = p & 0xFFFF;
      float as = a_s[(size_t)s * 4 + hh];
      unsigned u = *reinterpret_cast<const unsigned*>(&gbf[(size_t)s * HOUT + lane * 2]);
      float e = as + adh; e = (e > 0.f) ? e : 0.2f * e;
      float ex = __expf(e);
      den += ex;
      ox += ex * bflo(u);
      oy += ex * bfhi(u);
    }
    float dinv = (den > 0.f) ? (1.0f / den) : 0.f;
    float2 bg = *reinterpret_cast<const float2*>(b_gat + lane * 2);
    float vx = ox * dinv + bg.x; vx = (vx > 0.f) ? vx : 0.01f * vx;
    float vy = oy * dinv + bg.y; vy = (vy > 0.f) ? vy : 0.01f * vy;
    *reinterpret_cast<float2*>(&ob[wv][lane * 2]) = make_float2(vx, vy);
    float acc = 0.f;
#pragma unroll 8
    for (int i2 = 0; i2 < 32; ++i2) {
      int c = grp + 4 * i2;
      acc += ob[wv][c] * w1s[c * 16 + jj];
    }
    acc += __shfl_xor(acc, 16);
    acc += __shfl_xor(acc, 32);
    float z = acc + b1[jj];
    z = (z > 0.f) ? z : 0.01f * z;
    int b = batch[wid];
    if (lane < 16) atomicMax(&sp[b * 16 + jj], f2mono(z));
  }
  __syncthreads();
  for (int i = t; i < N_GRAPHS * 16; i += 256) {
    unsigned v = sp[i];
    if (v != MONO_NEG_INF) atomicMax(p_mono + i, v);
  }
}

// ---- y = p @ W2 + b2 ----
__global__ void final_y(const unsigned* __restrict__ p_mono,
                        const float* __restrict__ W2,
                        const float* __restrict__ b2,
                        float* __restrict__ y) {
  int gr = threadIdx.x;
  if (gr >= N_GRAPHS) return;
  float acc = b2[0];
#pragma unroll
  for (int k = 0; k < 16; ++k) acc += mono2f(p_mono[gr * 16 + k]) * W2[k];
  y[gr] = acc;
}

extern "C" void kernel_launch(void* const* d_in, const int* in_sizes, int n_in,
                              void* d_out, int out_size, void* d_ws, size_t ws_size,
                              hipStream_t stream) {
  const float* x       = (const float*)d_in[0];
  const int*   eidx    = (const int*)d_in[1];
  const int*   etype   = (const int*)d_in[2];
  const int*   batch   = (const int*)d_in[3];
  const float* W_rel   = (const float*)d_in[4];
  const float* W_root  = (const float*)d_in[5];
  const float* b_rgcn  = (const float*)d_in[6];
  const float* W_gat   = (const float*)d_in[7];
  const float* att_src = (const float*)d_in[8];
  const float* att_dst = (const float*)d_in[9];
  const float* b_gat   = (const float*)d_in[10];
  const float* W1      = (const float*)d_in[11];
  const float* b1      = (const float*)d_in[12];
  const float* W2      = (const float*)d_in[13];
  const float* b2      = (const float*)d_in[14];
  float* y = (float*)d_out;

  const int* src = eidx;
  const int* dst = eidx + N_EDGES;

  float* ws = (float*)d_ws;
  // ---- workspace layout (float offsets) ----
  const size_t OFF_XTBF= 0;           //  8,007,680 f: xt bf16 [N_PAD,320]
  const size_t OFF_GBF = 0;           //  g bf16 [N_PAD,128] (reuses xtbf)
  const size_t OFF_XHI = 8007680;     //  3,203,072 f: x hi bf16 [N_PAD,128]
  const size_t OFF_XLO = 11210752;    //  3,203,072 f: x lo
  const size_t OFF_HHI = 14413824;    //  1,601,536 f: h hi bf16 [N_PAD,64]
  const size_t OFF_HLO = 16015360;    //  1,601,536 f: h lo
  const size_t OFF_AS  = 17616896;    //    200,000  a_src
  const size_t OFF_AD  = 17816896;    //    200,000  a_dst
  const size_t OFF_PM  = 18016896;    //        256  pool max (1024 u32)
  const size_t OFF_DEG = 18017152;    //     50,000  deg (int)
  const size_t OFF_OFFS= 18067152;    //     50,001  off (int)
  const size_t OFF_RANK= 18117156;    //    800,000  rank (int)
  const size_t OFF_EP  = 18917156;    //    800,000  eprep (int)
  const size_t OFF_BS  = 19717156;    //        196
  const size_t OFF_BB  = 19717352;    //        196
  const size_t OFF_WBH = 19717552;    //     20,480  WbigT_hi (16B aligned)
  const size_t OFF_WBL = 19738032;    //     20,480  WbigT_lo
  const size_t OFF_WGH = 19758512;    //      4,096  WgatT_hi
  const size_t OFF_WGL = 19762608;    //      4,096  WgatT_lo
  const size_t TOTAL_F = 19766704;
  if (ws_size < TOTAL_F * sizeof(float)) return;

  unsigned short* xtbf = (unsigned short*)(ws + OFF_XTBF);
  unsigned short* gbf  = (unsigned short*)(ws + OFF_GBF);
  unsigned short* xhi  = (unsigned short*)(ws + OFF_XHI);
  unsigned short* xlo  = (unsigned short*)(ws + OFF_XLO);
  unsigned short* hhi  = (unsigned short*)(ws + OFF_HHI);
  unsigned short* hlo  = (unsigned short*)(ws + OFF_HLO);
  float* a_s   = ws + OFF_AS;
  float* a_d   = ws + OFF_AD;
  unsigned* pm = (unsigned*)(ws + OFF_PM);
  int* deg     = (int*)(ws + OFF_DEG);
  int* offs    = (int*)(ws + OFF_OFFS);
  int* rank    = (int*)(ws + OFF_RANK);
  int* eprep   = (int*)(ws + OFF_EP);
  int* bsum    = (int*)(ws + OFF_BS);
  int* bbase   = (int*)(ws + OFF_BB);
  unsigned short* wbt_hi = (unsigned short*)(ws + OFF_WBH);
  unsigned short* wbt_lo = (unsigned short*)(ws + OFF_WBL);
  unsigned short* wgt_hi = (unsigned short*)(ws + OFF_WGH);
  unsigned short* wgt_lo = (unsigned short*)(ws + OFF_WGL);

  // CSR build (atomic-free fill)
  hipMemsetAsync(deg, 0, N_NODES * sizeof(int), stream);
  k_hist<<<(N_EDGES + 255) / 256, 256, 0, stream>>>(dst, deg, rank);
  k_s1<<<NBLK, 256, 0, stream>>>(deg, bsum);
  k_s2<<<1, 256, 0, stream>>>(bsum, bbase, offs);
  k_s3<<<NBLK, 256, 0, stream>>>(deg, bbase, offs);
  k_fill<<<(N_EDGES + 255) / 256, 256, 0, stream>>>(src, dst, etype, offs, rank, eprep);

  // weights + x split to bf16 hi/lo
  build_wT<<<(MBIG * F_IN + HOUT * H1 + 255) / 256, 256, 0, stream>>>(
      W_root, W_rel, W_gat, wbt_hi, wbt_lo, wgt_hi, wgt_lo);
  xcvt<<<(N_NODES * (F_IN / 4) + 255) / 256, 256, 0, stream>>>(x, xhi, xlo);

  // xt(bf16) = x @ [W_root | W_rel]  (64x64 tiles, 4 indep acc/wave)
  {
    dim3 grid(N_PAD / 64, MBIG / 64);
    gemm_bf<128><<<grid, 256, 0, stream>>>(xhi, xlo, wbt_hi, wbt_lo,
                                           xtbf, N_NODES, MBIG);
  }

  // RGCN gather -> h (bf16 hi/lo, emitted directly)
  rgcn_gather<<<N_NODES / 4, 256, 0, stream>>>(xtbf, offs, eprep, b_rgcn, hhi, hlo);

  // g(bf16) = h @ W_gat
  {
    dim3 grid(N_PAD / 64, HOUT / 64);
    gemm_bf<64><<<grid, 256, 0, stream>>>(hhi, hlo, wgt_hi, wgt_lo,
                                          gbf, N_NODES, HOUT);
  }

  // attention coefficients
  gat_att<<<(N_NODES + 63) / 64, 256, 0, stream>>>(gbf, att_src, att_dst, a_s, a_d);

  // fused GAT aggregation + head + per-graph max pool
  init_mono<<<(N_GRAPHS * 16 + 255) / 256, 256, 0, stream>>>(pm, N_GRAPHS * 16);
  gat_fused<<<GAT_BLOCKS, 256, 0, stream>>>(gbf, a_s, a_d, offs, eprep, b_gat,
                                            W1, b1, batch, pm);

  // y = p @ W2 + b2
  final_y<<<1, 64, 0, stream>>>(pm, W2, b2, y);
}

// Round 13
// 223.448 us; speedup vs baseline: 1.1830x; 1.1787x over previous
//
#include <hip/hip_runtime.h>
#include <hip/hip_bf16.h>

constexpr int N_NODES = 50000;
constexpr int N_EDGES = 800000;
constexpr int F_IN = 128;
constexpr int H1 = 64;
constexpr int HEADS = 4;
constexpr int D_H = 32;
constexpr int HOUT = HEADS * D_H;       // 128
constexpr int N_REL = 4;
constexpr int N_GRAPHS = 64;
constexpr int MBIG = H1 * (1 + N_REL);  // 320
constexpr int NBLK = (N_NODES + 255) / 256;  // 196
constexpr int N_PAD = 50048;            // 64 * 782

typedef __attribute__((ext_vector_type(8))) short bf16x8;
typedef __attribute__((ext_vector_type(4))) float f32x4;

// ---- monotonic float<->uint for atomicMax on floats ----
__device__ __forceinline__ unsigned f2mono(float f) {
  unsigned u = __float_as_uint(f);
  return (u & 0x80000000u) ? ~u : (u | 0x80000000u);
}
__device__ __forceinline__ float mono2f(unsigned m) {
  unsigned u = (m & 0x80000000u) ? (m & 0x7FFFFFFFu) : ~m;
  return __uint_as_float(u);
}
constexpr unsigned MONO_NEG_INF = 0x007FFFFFu;

// ---- bf16 helpers ----
__device__ __forceinline__ unsigned short f2bf(float f) {
  unsigned u = __float_as_uint(f);
  unsigned r = (u + 0x7FFFu + ((u >> 16) & 1u)) >> 16;  // RNE
  return (unsigned short)r;
}
__device__ __forceinline__ float bf2f(unsigned short h) {
  return __uint_as_float((unsigned)h << 16);
}
__device__ __forceinline__ float bflo(unsigned u) { return __uint_as_float(u << 16); }
__device__ __forceinline__ float bfhi(unsigned u) { return __uint_as_float(u & 0xFFFF0000u); }

// ================= fused prep: xcvt | hist | build_wT | init_mono =========
constexpr int XCVT_BLOCKS = (N_NODES * (F_IN / 4) + 255) / 256;  // 6250
constexpr int HIST_BLOCKS = (N_EDGES + 255) / 256;               // 3125
constexpr int WT_BLOCKS = (MBIG * F_IN + HOUT * H1 + 255) / 256; // 192

__global__ __launch_bounds__(256) void pre_fused(
    const float* __restrict__ x,
    const float* __restrict__ W_root, const float* __restrict__ W_rel,
    const float* __restrict__ W_gat,
    const int* __restrict__ dst,
    unsigned short* __restrict__ xhi, unsigned short* __restrict__ xlo,
    unsigned short* __restrict__ WbT_hi, unsigned short* __restrict__ WbT_lo,
    unsigned short* __restrict__ WgT_hi, unsigned short* __restrict__ WgT_lo,
    int* __restrict__ deg, int* __restrict__ rank,
    unsigned* __restrict__ pm) {
  int b = blockIdx.x;
  if (b < XCVT_BLOCKS) {
    int i = b * 256 + threadIdx.x;
    if (i < N_NODES * (F_IN / 4)) {
      float4 v = reinterpret_cast<const float4*>(x)[i];
      ushort4 hi, lo;
      hi.x = f2bf(v.x); lo.x = f2bf(v.x - bf2f(hi.x));
      hi.y = f2bf(v.y); lo.y = f2bf(v.y - bf2f(hi.y));
      hi.z = f2bf(v.z); lo.z = f2bf(v.z - bf2f(hi.z));
      hi.w = f2bf(v.w); lo.w = f2bf(v.w - bf2f(hi.w));
      reinterpret_cast<ushort4*>(xhi)[i] = hi;
      reinterpret_cast<ushort4*>(xlo)[i] = lo;
    }
  } else if (b < XCVT_BLOCKS + HIST_BLOCKS) {
    int e = (b - XCVT_BLOCKS) * 256 + threadIdx.x;
    if (e < N_EDGES) rank[e] = atomicAdd(&deg[dst[e]], 1);
  } else if (b < XCVT_BLOCKS + HIST_BLOCKS + WT_BLOCKS) {
    int i = (b - XCVT_BLOCKS - HIST_BLOCKS) * 256 + threadIdx.x;
    if (i < MBIG * F_IN) {
      int c = i / F_IN, k = i % F_IN;
      float w = (c < H1) ? W_root[k * H1 + c]
                         : W_rel[((size_t)(((c - H1) >> 6) * F_IN + k)) * H1 + ((c - H1) & 63)];
      unsigned short hi = f2bf(w);
      WbT_hi[i] = hi;
      WbT_lo[i] = f2bf(w - bf2f(hi));
    } else {
      int j = i - MBIG * F_IN;
      if (j < HOUT * H1) {
        int c = j / H1, k = j % H1;
        float w = W_gat[k * HOUT + c];
        unsigned short hi = f2bf(w);
        WgT_hi[j] = hi;
        WgT_lo[j] = f2bf(w - bf2f(hi));
      }
    }
  } else {
    for (int i = threadIdx.x; i < N_GRAPHS * 16; i += 256) pm[i] = MONO_NEG_INF;
  }
}

// ================= LDS-staged split-bf16 MFMA GEMM (R8 structure) =========
// Block = 64 rows x 64 cols, 4 waves (2x2), 2x2 frags/wave. A hi/lo staged
// in LDS by pure copy (pre-split inputs), XOR-swizzled k to kill 8-way
// bank conflicts. B fragments straight from global (L2-hot, small).
template <int K>
__device__ __forceinline__ void gemm_body(int bx, int by,
    const unsigned short* __restrict__ Ahi_,
    const unsigned short* __restrict__ Alo_,
    const unsigned short* __restrict__ BT_hi,
    const unsigned short* __restrict__ BT_lo,
    unsigned short* __restrict__ Cbf, int N, int M) {
  __shared__ unsigned short Ah[64 * K];
  __shared__ unsigned short Al[64 * K];
  const int tid = threadIdx.x;
  const int rowBase = bx * 64;
  const int colBase = by * 64;
  constexpr int KQ8 = K / 8;                 // uint4 (8 ushorts) per row
  for (int s = tid; s < 64 * KQ8; s += 256) {
    int r = s / KQ8, c8 = (s % KQ8) * 8;
    size_t gi = (size_t)(rowBase + r) * K + c8;
    int sw = c8 ^ ((r & 7) << 3);            // XOR swizzle (bits 3-5)
    *reinterpret_cast<uint4*>(&Ah[r * K + sw]) =
        *reinterpret_cast<const uint4*>(&Ahi_[gi]);
    *reinterpret_cast<uint4*>(&Al[r * K + sw]) =
        *reinterpret_cast<const uint4*>(&Alo_[gi]);
  }
  __syncthreads();
  const int wv = tid >> 6, lane = tid & 63;
  const int wr = (wv >> 1) * 32, wc = (wv & 1) * 32;
  const int lrow = lane & 15, lkc = lane >> 4;
  f32x4 acc[2][2] = {};
#pragma unroll
  for (int ks = 0; ks < K; ks += 32) {
    bf16x8 ah[2], al[2], bh[2], bl[2];
#pragma unroll
    for (int fr = 0; fr < 2; ++fr) {
      int r = wr + fr * 16 + lrow;
      int sw = (ks + lkc * 8) ^ ((r & 7) << 3);
      ah[fr] = *reinterpret_cast<const bf16x8*>(&Ah[r * K + sw]);
      al[fr] = *reinterpret_cast<const bf16x8*>(&Al[r * K + sw]);
    }
#pragma unroll
    for (int fc = 0; fc < 2; ++fc) {
      int c = colBase + wc + fc * 16 + lrow;
      bh[fc] = *reinterpret_cast<const bf16x8*>(&BT_hi[(size_t)c * K + ks + lkc * 8]);
      bl[fc] = *reinterpret_cast<const bf16x8*>(&BT_lo[(size_t)c * K + ks + lkc * 8]);
    }
#pragma unroll
    for (int fr = 0; fr < 2; ++fr)
#pragma unroll
      for (int fc = 0; fc < 2; ++fc) {
        acc[fr][fc] = __builtin_amdgcn_mfma_f32_16x16x32_bf16(ah[fr], bh[fc], acc[fr][fc], 0, 0, 0);
        acc[fr][fc] = __builtin_amdgcn_mfma_f32_16x16x32_bf16(ah[fr], bl[fc], acc[fr][fc], 0, 0, 0);
        acc[fr][fc] = __builtin_amdgcn_mfma_f32_16x16x32_bf16(al[fr], bh[fc], acc[fr][fc], 0, 0, 0);
      }
  }
#pragma unroll
  for (int fr = 0; fr < 2; ++fr) {
#pragma unroll
    for (int i = 0; i < 4; ++i) {
      int row = rowBase + wr + fr * 16 + lkc * 4 + i;
      if (row < N) {
#pragma unroll
        for (int fc = 0; fc < 2; ++fc) {
          int col = colBase + wc + fc * 16 + lrow;
          Cbf[(size_t)row * M + col] = f2bf(acc[fr][fc][i]);
        }
      }
    }
  }
}

// ---- gemm1 (K=128, xt) fused with CSR fill ----
constexpr int G1_BX = N_PAD / 64;          // 782
constexpr int G1_BLOCKS = G1_BX * (MBIG / 64);  // 3910
__global__ __launch_bounds__(256) void gemm1_fill(
    const unsigned short* __restrict__ xhi, const unsigned short* __restrict__ xlo,
    const unsigned short* __restrict__ wbt_hi, const unsigned short* __restrict__ wbt_lo,
    unsigned short* __restrict__ xtbf,
    const int* __restrict__ src, const int* __restrict__ dst,
    const int* __restrict__ etype, const int* __restrict__ off,
    const int* __restrict__ rank, int* __restrict__ eprep) {
  if (blockIdx.x < G1_BLOCKS) {
    gemm_body<128>(blockIdx.x % G1_BX, blockIdx.x / G1_BX,
                   xhi, xlo, wbt_hi, wbt_lo, xtbf, N_NODES, MBIG);
  } else {
    int e = (blockIdx.x - G1_BLOCKS) * 256 + threadIdx.x;
    if (e < N_EDGES) {
      int pos = off[dst[e]] + rank[e];
      eprep[pos] = src[e] | (etype[e] << 16);
    }
  }
}

// ---- gemm2 (K=64, g) ----
__global__ __launch_bounds__(256) void gemm2_k(
    const unsigned short* __restrict__ hhi, const unsigned short* __restrict__ hlo,
    const unsigned short* __restrict__ wgt_hi, const unsigned short* __restrict__ wgt_lo,
    unsigned short* __restrict__ gbf) {
  gemm_body<64>(blockIdx.x % G1_BX, blockIdx.x / G1_BX,
                hhi, hlo, wgt_hi, wgt_lo, gbf, N_NODES, HOUT);
}

// ---- scan stage 1: per-block sums ----
__global__ __launch_bounds__(256) void k_s1(const int* __restrict__ deg,
                                            int* __restrict__ bsum) {
  __shared__ int ss[256];
  int t = threadIdx.x;
  int i = blockIdx.x * 256 + t;
  ss[t] = (i < N_NODES) ? deg[i] : 0;
  __syncthreads();
  for (int d = 128; d > 0; d >>= 1) {
    if (t < d) ss[t] += ss[t + d];
    __syncthreads();
  }
  if (t == 0) bsum[blockIdx.x] = ss[0];
}

// ---- scan stage 2: exclusive scan of block sums ----
__global__ __launch_bounds__(256) void k_s2(const int* __restrict__ bsum,
                                            int* __restrict__ bbase,
                                            int* __restrict__ off) {
  __shared__ int ss[256];
  int t = threadIdx.x;
  int v = (t < NBLK) ? bsum[t] : 0;
  ss[t] = v;
  __syncthreads();
  for (int d = 1; d < 256; d <<= 1) {
    int u = (t >= d) ? ss[t - d] : 0;
    __syncthreads();
    ss[t] += u;
    __syncthreads();
  }
  if (t < NBLK) bbase[t] = ss[t] - v;
  if (t == NBLK - 1) off[N_NODES] = ss[t];
}

// ---- scan stage 3: block-local scan + base ----
__global__ __launch_bounds__(256) void k_s3(const int* __restrict__ deg,
                                            const int* __restrict__ bbase,
                                            int* __restrict__ off) {
  __shared__ int ss[256];
  int t = threadIdx.x;
  int i = blockIdx.x * 256 + t;
  int v = (i < N_NODES) ? deg[i] : 0;
  ss[t] = v;
  __syncthreads();
  for (int d = 1; d < 256; d <<= 1) {
    int u = (t >= d) ? ss[t - d] : 0;
    __syncthreads();
    ss[t] += u;
    __syncthreads();
  }
  if (i < N_NODES) off[i] = bbase[blockIdx.x] + ss[t] - v;
}

// ---- RGCN: gather from bf16 xt; wave/node; emits h as bf16 hi/lo ----
__global__ __launch_bounds__(256) void rgcn_gather(const unsigned short* __restrict__ xtbf,
                                                   const int* __restrict__ off,
                                                   const int* __restrict__ eprep,
                                                   const float* __restrict__ b_rgcn,
                                                   unsigned short* __restrict__ hhi,
                                                   unsigned short* __restrict__ hlo) {
  int wid = (blockIdx.x * 256 + threadIdx.x) >> 6;
  int lane = threadIdx.x & 63;
  int half = lane >> 5;
  int cp = lane & 31;
  int start = off[wid], end = off[wid + 1];
  float a0x=0.f,a0y=0.f,a1x=0.f,a1y=0.f,a2x=0.f,a2y=0.f,a3x=0.f,a3y=0.f;
  int c0=0,c1=0,c2=0,c3=0;
  int niter = (end - start + 1) >> 1;
  for (int t = 0; t < niter; t += 2) {
    int idx0 = start + 2 * t + half;
    int idx1 = idx0 + 2;
    int p0 = (idx0 < end) ? eprep[idx0] : 0x70000;
    int p1 = (idx1 < end) ? eprep[idx1] : 0x70000;
    int s0 = p0 & 0xFFFF, r0 = p0 >> 16;
    int s1 = p1 & 0xFFFF, r1 = p1 >> 16;
    unsigned u0 = *reinterpret_cast<const unsigned*>(
        &xtbf[(size_t)s0 * MBIG + H1 + (r0 << 6) + cp * 2]);
    unsigned u1 = *reinterpret_cast<const unsigned*>(
        &xtbf[(size_t)s1 * MBIG + H1 + (r1 << 6) + cp * 2]);
    float v0x = bflo(u0), v0y = bfhi(u0);
    float v1x = bflo(u1), v1y = bfhi(u1);
    a0x += (r0==0)?v0x:0.f; a0y += (r0==0)?v0y:0.f; c0 += (r0==0);
    a1x += (r0==1)?v0x:0.f; a1y += (r0==1)?v0y:0.f; c1 += (r0==1);
    a2x += (r0==2)?v0x:0.f; a2y += (r0==2)?v0y:0.f; c2 += (r0==2);
    a3x += (r0==3)?v0x:0.f; a3y += (r0==3)?v0y:0.f; c3 += (r0==3);
    a0x += (r1==0)?v1x:0.f; a0y += (r1==0)?v1y:0.f; c0 += (r1==0);
    a1x += (r1==1)?v1x:0.f; a1y += (r1==1)?v1y:0.f; c1 += (r1==1);
    a2x += (r1==2)?v1x:0.f; a2y += (r1==2)?v1y:0.f; c2 += (r1==2);
    a3x += (r1==3)?v1x:0.f; a3y += (r1==3)?v1y:0.f; c3 += (r1==3);
  }
  a0x += __shfl_xor(a0x, 32); a0y += __shfl_xor(a0y, 32);
  a1x += __shfl_xor(a1x, 32); a1y += __shfl_xor(a1y, 32);
  a2x += __shfl_xor(a2x, 32); a2y += __shfl_xor(a2y, 32);
  a3x += __shfl_xor(a3x, 32); a3y += __shfl_xor(a3y, 32);
  c0 += __shfl_xor(c0, 32); c1 += __shfl_xor(c1, 32);
  c2 += __shfl_xor(c2, 32); c3 += __shfl_xor(c3, 32);
  if (half == 0) {
    unsigned ur = *reinterpret_cast<const unsigned*>(&xtbf[(size_t)wid * MBIG + cp * 2]);
    float2 bb = *reinterpret_cast<const float2*>(&b_rgcn[cp * 2]);
    float i0 = 1.0f / (float)max(c0, 1);
    float i1 = 1.0f / (float)max(c1, 1);
    float i2 = 1.0f / (float)max(c2, 1);
    float i3 = 1.0f / (float)max(c3, 1);
    float vx = bflo(ur) + bb.x + a0x * i0 + a1x * i1 + a2x * i2 + a3x * i3;
    float vy = bfhi(ur) + bb.y + a0y * i0 + a1y * i1 + a2y * i2 + a3y * i3;
    vx = fmaxf(vx, 0.f);
    vy = fmaxf(vy, 0.f);
    unsigned short hx = f2bf(vx), hy = f2bf(vy);
    ushort2 hv = {hx, hy};
    ushort2 lv = {f2bf(vx - bf2f(hx)), f2bf(vy - bf2f(hy))};
    *reinterpret_cast<ushort2*>(&hhi[(size_t)wid * H1 + cp * 2]) = hv;
    *reinterpret_cast<ushort2*>(&hlo[(size_t)wid * H1 + cp * 2]) = lv;
  }
}

// ---- attention coefficients from bf16 g, LDS-staged ----
__global__ __launch_bounds__(256) void gat_att(const unsigned short* __restrict__ gbf,
                                               const float* __restrict__ att_src,
                                               const float* __restrict__ att_dst,
                                               float* __restrict__ a_s,
                                               float* __restrict__ a_d) {
  __shared__ float gs[64][129];
  __shared__ float asrc[HOUT], adst[HOUT];
  int t = threadIdx.x;
  if (t < HOUT) { asrc[t] = att_src[t]; adst[t] = att_dst[t]; }
  int nb = blockIdx.x * 64;
#pragma unroll
  for (int it = 0; it < 8; ++it) {
    int idx = it * 256 + t;
    int r = idx >> 5, c4 = (idx & 31) * 4;
    int gn = nb + r;
    uint2 v = make_uint2(0u, 0u);
    if (gn < N_NODES)
      v = *reinterpret_cast<const uint2*>(&gbf[(size_t)gn * HOUT + c4]);
    gs[r][c4 + 0] = bflo(v.x); gs[r][c4 + 1] = bfhi(v.x);
    gs[r][c4 + 2] = bflo(v.y); gs[r][c4 + 3] = bfhi(v.y);
  }
  __syncthreads();
  int n = t & 63, hh = t >> 6;
  float s = 0.f, d = 0.f;
#pragma unroll
  for (int k = 0; k < D_H; ++k) {
    float gv = gs[n][hh * D_H + k];
    s += gv * asrc[hh * D_H + k];
    d += gv * adst[hh * D_H + k];
  }
  if (nb + n < N_NODES) {
    a_s[(size_t)(nb + n) * 4 + hh] = s;
    a_d[(size_t)(nb + n) * 4 + hh] = d;
  }
}

// ---- GAT + head fused ----
constexpr int GAT_BLOCKS = 2048;
constexpr int GAT_WAVES = GAT_BLOCKS * 4;   // 8192
__global__ __launch_bounds__(256) void gat_fused(const unsigned short* __restrict__ gbf,
                                                 const float* __restrict__ a_s,
                                                 const float* __restrict__ a_d,
                                                 const int* __restrict__ off,
                                                 const int* __restrict__ eprep,
                                                 const float* __restrict__ b_gat,
                                                 const float* __restrict__ W1,
                                                 const float* __restrict__ b1,
                                                 const int* __restrict__ batch,
                                                 unsigned* __restrict__ p_mono) {
  __shared__ float w1s[HOUT * 16];        // W1[k][j]
  __shared__ float ob[4][HOUT];           // per-wave o row
  __shared__ unsigned sp[N_GRAPHS * 16];
  const int t = threadIdx.x;
  for (int i = t; i < HOUT * 16; i += 256) w1s[i] = W1[i];
  for (int i = t; i < N_GRAPHS * 16; i += 256) sp[i] = MONO_NEG_INF;
  __syncthreads();
  const int wv = t >> 6, lane = t & 63;
  const int hh = lane >> 4;
  const int jj = lane & 15, grp = lane >> 4;
  const int w = blockIdx.x * 4 + wv;
  const int q = N_NODES / GAT_WAVES;
  const int r = N_NODES % GAT_WAVES;
  const int nbeg = w * q + ((w < r) ? w : r);
  const int ncnt = q + ((w < r) ? 1 : 0);
  for (int wid = nbeg; wid < nbeg + ncnt; ++wid) {
    int start = off[wid], end = off[wid + 1];
    float4 ad4 = *reinterpret_cast<const float4*>(a_d + (size_t)wid * 4);
    float adh = (hh == 0) ? ad4.x : (hh == 1) ? ad4.y : (hh == 2) ? ad4.z : ad4.w;
    float ox = 0.f, oy = 0.f, den = 0.f;
    int i = start;
    for (; i + 4 <= end; i += 4) {
      int p0 = eprep[i], p1 = eprep[i + 1], p2 = eprep[i + 2], p3 = eprep[i + 3];
      int s0 = p0 & 0xFFFF, s1 = p1 & 0xFFFF, s2 = p2 & 0xFFFF, s3 = p3 & 0xFFFF;
      float as0 = a_s[(size_t)s0 * 4 + hh];
      float as1 = a_s[(size_t)s1 * 4 + hh];
      float as2 = a_s[(size_t)s2 * 4 + hh];
      float as3 = a_s[(size_t)s3 * 4 + hh];
      unsigned u0 = *reinterpret_cast<const unsigned*>(&gbf[(size_t)s0 * HOUT + lane * 2]);
      unsigned u1 = *reinterpret_cast<const unsigned*>(&gbf[(size_t)s1 * HOUT + lane * 2]);
      unsigned u2 = *reinterpret_cast<const unsigned*>(&gbf[(size_t)s2 * HOUT + lane * 2]);
      unsigned u3 = *reinterpret_cast<const unsigned*>(&gbf[(size_t)s3 * HOUT + lane * 2]);
      float e0 = as0 + adh; e0 = (e0 > 0.f) ? e0 : 0.2f * e0;
      float e1 = as1 + adh; e1 = (e1 > 0.f) ? e1 : 0.2f * e1;
      float e2 = as2 + adh; e2 = (e2 > 0.f) ? e2 : 0.2f * e2;
      float e3 = as3 + adh; e3 = (e3 > 0.f) ? e3 : 0.2f * e3;
      float x0 = __expf(e0), x1 = __expf(e1), x2 = __expf(e2), x3 = __expf(e3);
      den += x0 + x1 + x2 + x3;
      ox += x0 * bflo(u0) + x1 * bflo(u1) + x2 * bflo(u2) + x3 * bflo(u3);
      oy += x0 * bfhi(u0) + x1 * bfhi(u1) + x2 * bfhi(u2) + x3 * bfhi(u3);
    }
    for (; i < end; ++i) {
      int p = eprep[i];
      int s = p & 0xFFFF;
      float as = a_s[(size_t)s * 4 + hh];
      unsigned u = *reinterpret_cast<const unsigned*>(&gbf[(size_t)s * HOUT + lane * 2]);
      float e = as + adh; e = (e > 0.f) ? e : 0.2f * e;
      float ex = __expf(e);
      den += ex;
      ox += ex * bflo(u);
      oy += ex * bfhi(u);
    }
    float dinv = (den > 0.f) ? (1.0f / den) : 0.f;
    float2 bg = *reinterpret_cast<const float2*>(b_gat + lane * 2);
    float vx = ox * dinv + bg.x; vx = (vx > 0.f) ? vx : 0.01f * vx;
    float vy = oy * dinv + bg.y; vy = (vy > 0.f) ? vy : 0.01f * vy;
    *reinterpret_cast<float2*>(&ob[wv][lane * 2]) = make_float2(vx, vy);
    float acc = 0.f;
#pragma unroll 8
    for (int i2 = 0; i2 < 32; ++i2) {
      int c = grp + 4 * i2;
      acc += ob[wv][c] * w1s[c * 16 + jj];
    }
    acc += __shfl_xor(acc, 16);
    acc += __shfl_xor(acc, 32);
    float z = acc + b1[jj];
    z = (z > 0.f) ? z : 0.01f * z;
    int b = batch[wid];
    if (lane < 16) atomicMax(&sp[b * 16 + jj], f2mono(z));
  }
  __syncthreads();
  for (int i = t; i < N_GRAPHS * 16; i += 256) {
    unsigned v = sp[i];
    if (v != MONO_NEG_INF) atomicMax(p_mono + i, v);
  }
}

// ---- y = p @ W2 + b2 ----
__global__ void final_y(const unsigned* __restrict__ p_mono,
                        const float* __restrict__ W2,
                        const float* __restrict__ b2,
                        float* __restrict__ y) {
  int gr = threadIdx.x;
  if (gr >= N_GRAPHS) return;
  float acc = b2[0];
#pragma unroll
  for (int k = 0; k < 16; ++k) acc += mono2f(p_mono[gr * 16 + k]) * W2[k];
  y[gr] = acc;
}

extern "C" void kernel_launch(void* const* d_in, const int* in_sizes, int n_in,
                              void* d_out, int out_size, void* d_ws, size_t ws_size,
                              hipStream_t stream) {
  const float* x       = (const float*)d_in[0];
  const int*   eidx    = (const int*)d_in[1];
  const int*   etype   = (const int*)d_in[2];
  const int*   batch   = (const int*)d_in[3];
  const float* W_rel   = (const float*)d_in[4];
  const float* W_root  = (const float*)d_in[5];
  const float* b_rgcn  = (const float*)d_in[6];
  const float* W_gat   = (const float*)d_in[7];
  const float* att_src = (const float*)d_in[8];
  const float* att_dst = (const float*)d_in[9];
  const float* b_gat   = (const float*)d_in[10];
  const float* W1      = (const float*)d_in[11];
  const float* b1      = (const float*)d_in[12];
  const float* W2      = (const float*)d_in[13];
  const float* b2      = (const float*)d_in[14];
  float* y = (float*)d_out;

  const int* src = eidx;
  const int* dst = eidx + N_EDGES;

  float* ws = (float*)d_ws;
  // ---- workspace layout (float offsets) ----
  const size_t OFF_XTBF= 0;           //  8,007,680 f: xt bf16 [N_PAD,320]
  const size_t OFF_GBF = 0;           //  g bf16 [N_PAD,128] (reuses xtbf)
  const size_t OFF_XHI = 8007680;     //  3,203,072 f: x hi bf16 [N_PAD,128]
  const size_t OFF_XLO = 11210752;    //  3,203,072 f: x lo
  const size_t OFF_HHI = 14413824;    //  1,601,536 f: h hi bf16 [N_PAD,64]
  const size_t OFF_HLO = 16015360;    //  1,601,536 f: h lo
  const size_t OFF_AS  = 17616896;    //    200,000  a_src
  const size_t OFF_AD  = 17816896;    //    200,000  a_dst
  const size_t OFF_PM  = 18016896;    //      1,024 f = 1024 u32 pool max (FIXED SIZE)
  const size_t OFF_DEG = 18017920;    //     50,000  deg (int)
  const size_t OFF_OFFS= 18067920;    //     50,001  off (int)
  const size_t OFF_RANK= 18117924;    //    800,000  rank (int)
  const size_t OFF_EP  = 18917924;    //    800,000  eprep (int)
  const size_t OFF_BS  = 19717924;    //        196
  const size_t OFF_BB  = 19718120;    //        196
  const size_t OFF_WBH = 19718320;    //     20,480  WbigT_hi (float off %4 -> 16B aligned)
  const size_t OFF_WBL = 19738800;    //     20,480  WbigT_lo
  const size_t OFF_WGH = 19759280;    //      4,096  WgatT_hi
  const size_t OFF_WGL = 19763376;    //      4,096  WgatT_lo
  const size_t TOTAL_F = 19767472;
  if (ws_size < TOTAL_F * sizeof(float)) return;

  unsigned short* xtbf = (unsigned short*)(ws + OFF_XTBF);
  unsigned short* gbf  = (unsigned short*)(ws + OFF_GBF);
  unsigned short* xhi  = (unsigned short*)(ws + OFF_XHI);
  unsigned short* xlo  = (unsigned short*)(ws + OFF_XLO);
  unsigned short* hhi  = (unsigned short*)(ws + OFF_HHI);
  unsigned short* hlo  = (unsigned short*)(ws + OFF_HLO);
  float* a_s   = ws + OFF_AS;
  float* a_d   = ws + OFF_AD;
  unsigned* pm = (unsigned*)(ws + OFF_PM);
  int* deg     = (int*)(ws + OFF_DEG);
  int* offs    = (int*)(ws + OFF_OFFS);
  int* rank    = (int*)(ws + OFF_RANK);
  int* eprep   = (int*)(ws + OFF_EP);
  int* bsum    = (int*)(ws + OFF_BS);
  int* bbase   = (int*)(ws + OFF_BB);
  unsigned short* wbt_hi = (unsigned short*)(ws + OFF_WBH);
  unsigned short* wbt_lo = (unsigned short*)(ws + OFF_WBL);
  unsigned short* wgt_hi = (unsigned short*)(ws + OFF_WGH);
  unsigned short* wgt_lo = (unsigned short*)(ws + OFF_WGL);

  // 1. deg = 0 (before fused hist)
  hipMemsetAsync(deg, 0, N_NODES * sizeof(int), stream);

  // 2. fused independent prep: xcvt | hist(+rank) | build_wT | init_mono
  pre_fused<<<XCVT_BLOCKS + HIST_BLOCKS + WT_BLOCKS + 1, 256, 0, stream>>>(
      x, W_root, W_rel, W_gat, dst, xhi, xlo,
      wbt_hi, wbt_lo, wgt_hi, wgt_lo, deg, rank, pm);

  // 3. scan (off from deg)
  k_s1<<<NBLK, 256, 0, stream>>>(deg, bsum);
  k_s2<<<1, 256, 0, stream>>>(bsum, bbase, offs);
  k_s3<<<NBLK, 256, 0, stream>>>(deg, bbase, offs);

  // 4. gemm1 (xt = x @ Wbig) fused with CSR fill
  gemm1_fill<<<G1_BLOCKS + HIST_BLOCKS, 256, 0, stream>>>(
      xhi, xlo, wbt_hi, wbt_lo, xtbf, src, dst, etype, offs, rank, eprep);

  // 5. RGCN gather -> h (bf16 hi/lo)
  rgcn_gather<<<N_NODES / 4, 256, 0, stream>>>(xtbf, offs, eprep, b_rgcn, hhi, hlo);

  // 6. g = h @ W_gat
  gemm2_k<<<G1_BX * (HOUT / 64), 256, 0, stream>>>(hhi, hlo, wgt_hi, wgt_lo, gbf);

  // 7. attention coefficients
  gat_att<<<(N_NODES + 63) / 64, 256, 0, stream>>>(gbf, att_src, att_dst, a_s, a_d);

  // 8. fused GAT aggregation + head + per-graph max pool
  gat_fused<<<GAT_BLOCKS, 256, 0, stream>>>(gbf, a_s, a_d, offs, eprep, b_gat,
                                            W1, b1, batch, pm);

  // 9. y = p @ W2 + b2
  final_y<<<1, 64, 0, stream>>>(pm, W2, b2, y);
}

// Round 14
// 220.290 us; speedup vs baseline: 1.1999x; 1.0143x over previous
//
#include <hip/hip_runtime.h>
#include <hip/hip_bf16.h>

constexpr int N_NODES = 50000;
constexpr int N_EDGES = 800000;
constexpr int F_IN = 128;
constexpr int H1 = 64;
constexpr int HEADS = 4;
constexpr int D_H = 32;
constexpr int HOUT = HEADS * D_H;       // 128
constexpr int N_REL = 4;
constexpr int N_GRAPHS = 64;
constexpr int MBIG = H1 * (1 + N_REL);  // 320
constexpr int NBLK = (N_NODES + 255) / 256;  // 196
constexpr int N_PAD = 50048;            // 64 * 782

typedef __attribute__((ext_vector_type(8))) short bf16x8;
typedef __attribute__((ext_vector_type(4))) float f32x4;

// ---- monotonic float<->uint for atomicMax on floats ----
__device__ __forceinline__ unsigned f2mono(float f) {
  unsigned u = __float_as_uint(f);
  return (u & 0x80000000u) ? ~u : (u | 0x80000000u);
}
__device__ __forceinline__ float mono2f(unsigned m) {
  unsigned u = (m & 0x80000000u) ? (m & 0x7FFFFFFFu) : ~m;
  return __uint_as_float(u);
}
constexpr unsigned MONO_NEG_INF = 0x007FFFFFu;

// ---- bf16 helpers ----
__device__ __forceinline__ unsigned short f2bf(float f) {
  unsigned u = __float_as_uint(f);
  unsigned r = (u + 0x7FFFu + ((u >> 16) & 1u)) >> 16;  // RNE
  return (unsigned short)r;
}
__device__ __forceinline__ float bf2f(unsigned short h) {
  return __uint_as_float((unsigned)h << 16);
}
__device__ __forceinline__ float bflo(unsigned u) { return __uint_as_float(u << 16); }
__device__ __forceinline__ float bfhi(unsigned u) { return __uint_as_float(u & 0xFFFF0000u); }

// ======= fused prep: xcvt | hist | build_wT | init_mono | watt =======
constexpr int XCVT_BLOCKS = (N_NODES * (F_IN / 4) + 255) / 256;  // 6250
constexpr int HIST_BLOCKS = (N_EDGES + 255) / 256;               // 3125
constexpr int WT_BLOCKS = (MBIG * F_IN + HOUT * H1 + 255) / 256; // 192

__global__ __launch_bounds__(256) void pre_fused(
    const float* __restrict__ x,
    const float* __restrict__ W_root, const float* __restrict__ W_rel,
    const float* __restrict__ W_gat,
    const float* __restrict__ att_src, const float* __restrict__ att_dst,
    const int* __restrict__ dst,
    unsigned short* __restrict__ xhi, unsigned short* __restrict__ xlo,
    unsigned short* __restrict__ WbT_hi, unsigned short* __restrict__ WbT_lo,
    unsigned short* __restrict__ WgT_hi, unsigned short* __restrict__ WgT_lo,
    int* __restrict__ deg, int* __restrict__ rank,
    unsigned* __restrict__ pm,
    float* __restrict__ was, float* __restrict__ wad) {
  int b = blockIdx.x;
  if (b < XCVT_BLOCKS) {
    int i = b * 256 + threadIdx.x;
    if (i < N_NODES * (F_IN / 4)) {
      float4 v = reinterpret_cast<const float4*>(x)[i];
      ushort4 hi, lo;
      hi.x = f2bf(v.x); lo.x = f2bf(v.x - bf2f(hi.x));
      hi.y = f2bf(v.y); lo.y = f2bf(v.y - bf2f(hi.y));
      hi.z = f2bf(v.z); lo.z = f2bf(v.z - bf2f(hi.z));
      hi.w = f2bf(v.w); lo.w = f2bf(v.w - bf2f(hi.w));
      reinterpret_cast<ushort4*>(xhi)[i] = hi;
      reinterpret_cast<ushort4*>(xlo)[i] = lo;
    }
  } else if (b < XCVT_BLOCKS + HIST_BLOCKS) {
    int e = (b - XCVT_BLOCKS) * 256 + threadIdx.x;
    if (e < N_EDGES) rank[e] = atomicAdd(&deg[dst[e]], 1);
  } else if (b < XCVT_BLOCKS + HIST_BLOCKS + WT_BLOCKS) {
    int i = (b - XCVT_BLOCKS - HIST_BLOCKS) * 256 + threadIdx.x;
    if (i < MBIG * F_IN) {
      int c = i / F_IN, k = i % F_IN;
      float w = (c < H1) ? W_root[k * H1 + c]
                         : W_rel[((size_t)(((c - H1) >> 6) * F_IN + k)) * H1 + ((c - H1) & 63)];
      unsigned short hi = f2bf(w);
      WbT_hi[i] = hi;
      WbT_lo[i] = f2bf(w - bf2f(hi));
    } else {
      int j = i - MBIG * F_IN;
      if (j < HOUT * H1) {
        int c = j / H1, k = j % H1;
        float w = W_gat[k * HOUT + c];
        unsigned short hi = f2bf(w);
        WgT_hi[j] = hi;
        WgT_lo[j] = f2bf(w - bf2f(hi));
      }
    }
  } else if (b == XCVT_BLOCKS + HIST_BLOCKS + WT_BLOCKS) {
    for (int i = threadIdx.x; i < N_GRAPHS * 16; i += 256) pm[i] = MONO_NEG_INF;
  } else {
    // watt: was/wad[k*4+hh] = sum_d W_gat[k][hh*32+d] * att[hh][d]
    int t = threadIdx.x;          // t = k*4 + hh, 256 threads exactly
    int k = t >> 2, hh = t & 3;
    float s = 0.f, d2 = 0.f;
#pragma unroll 8
    for (int dd = 0; dd < D_H; ++dd) {
      float wg = W_gat[k * HOUT + hh * D_H + dd];
      s += wg * att_src[hh * D_H + dd];
      d2 += wg * att_dst[hh * D_H + dd];
    }
    was[t] = s;
    wad[t] = d2;
  }
}

// ================= LDS-staged split-bf16 MFMA GEMM =========
template <int K>
__device__ __forceinline__ void gemm_body(int bx, int by,
    const unsigned short* __restrict__ Ahi_,
    const unsigned short* __restrict__ Alo_,
    const unsigned short* __restrict__ BT_hi,
    const unsigned short* __restrict__ BT_lo,
    unsigned short* __restrict__ Cbf, int N, int M) {
  __shared__ unsigned short Ah[64 * K];
  __shared__ unsigned short Al[64 * K];
  const int tid = threadIdx.x;
  const int rowBase = bx * 64;
  const int colBase = by * 64;
  constexpr int KQ8 = K / 8;                 // uint4 (8 ushorts) per row
  for (int s = tid; s < 64 * KQ8; s += 256) {
    int r = s / KQ8, c8 = (s % KQ8) * 8;
    size_t gi = (size_t)(rowBase + r) * K + c8;
    int sw = c8 ^ ((r & 7) << 3);            // XOR swizzle (bits 3-5)
    *reinterpret_cast<uint4*>(&Ah[r * K + sw]) =
        *reinterpret_cast<const uint4*>(&Ahi_[gi]);
    *reinterpret_cast<uint4*>(&Al[r * K + sw]) =
        *reinterpret_cast<const uint4*>(&Alo_[gi]);
  }
  __syncthreads();
  const int wv = tid >> 6, lane = tid & 63;
  const int wr = (wv >> 1) * 32, wc = (wv & 1) * 32;
  const int lrow = lane & 15, lkc = lane >> 4;
  f32x4 acc[2][2] = {};
#pragma unroll
  for (int ks = 0; ks < K; ks += 32) {
    bf16x8 ah[2], al[2], bh[2], bl[2];
#pragma unroll
    for (int fr = 0; fr < 2; ++fr) {
      int r = wr + fr * 16 + lrow;
      int sw = (ks + lkc * 8) ^ ((r & 7) << 3);
      ah[fr] = *reinterpret_cast<const bf16x8*>(&Ah[r * K + sw]);
      al[fr] = *reinterpret_cast<const bf16x8*>(&Al[r * K + sw]);
    }
#pragma unroll
    for (int fc = 0; fc < 2; ++fc) {
      int c = colBase + wc + fc * 16 + lrow;
      bh[fc] = *reinterpret_cast<const bf16x8*>(&BT_hi[(size_t)c * K + ks + lkc * 8]);
      bl[fc] = *reinterpret_cast<const bf16x8*>(&BT_lo[(size_t)c * K + ks + lkc * 8]);
    }
#pragma unroll
    for (int fr = 0; fr < 2; ++fr)
#pragma unroll
      for (int fc = 0; fc < 2; ++fc) {
        acc[fr][fc] = __builtin_amdgcn_mfma_f32_16x16x32_bf16(ah[fr], bh[fc], acc[fr][fc], 0, 0, 0);
        acc[fr][fc] = __builtin_amdgcn_mfma_f32_16x16x32_bf16(ah[fr], bl[fc], acc[fr][fc], 0, 0, 0);
        acc[fr][fc] = __builtin_amdgcn_mfma_f32_16x16x32_bf16(al[fr], bh[fc], acc[fr][fc], 0, 0, 0);
      }
  }
#pragma unroll
  for (int fr = 0; fr < 2; ++fr) {
#pragma unroll
    for (int i = 0; i < 4; ++i) {
      int row = rowBase + wr + fr * 16 + lkc * 4 + i;
      if (row < N) {
#pragma unroll
        for (int fc = 0; fc < 2; ++fc) {
          int col = colBase + wc + fc * 16 + lrow;
          Cbf[(size_t)row * M + col] = f2bf(acc[fr][fc][i]);
        }
      }
    }
  }
}

// ---- gemm1 (K=128, xt) fused with CSR fill ----
constexpr int G1_BX = N_PAD / 64;          // 782
constexpr int G1_BLOCKS = G1_BX * (MBIG / 64);  // 3910
__global__ __launch_bounds__(256) void gemm1_fill(
    const unsigned short* __restrict__ xhi, const unsigned short* __restrict__ xlo,
    const unsigned short* __restrict__ wbt_hi, const unsigned short* __restrict__ wbt_lo,
    unsigned short* __restrict__ xtbf,
    const int* __restrict__ src, const int* __restrict__ dst,
    const int* __restrict__ etype, const int* __restrict__ off,
    const int* __restrict__ rank, int* __restrict__ eprep) {
  if (blockIdx.x < G1_BLOCKS) {
    gemm_body<128>(blockIdx.x % G1_BX, blockIdx.x / G1_BX,
                   xhi, xlo, wbt_hi, wbt_lo, xtbf, N_NODES, MBIG);
  } else {
    int e = (blockIdx.x - G1_BLOCKS) * 256 + threadIdx.x;
    if (e < N_EDGES) {
      int pos = off[dst[e]] + rank[e];
      eprep[pos] = src[e] | (etype[e] << 16);
    }
  }
}

// ---- gemm2 (K=64, g) ----
__global__ __launch_bounds__(256) void gemm2_k(
    const unsigned short* __restrict__ hhi, const unsigned short* __restrict__ hlo,
    const unsigned short* __restrict__ wgt_hi, const unsigned short* __restrict__ wgt_lo,
    unsigned short* __restrict__ gbf) {
  gemm_body<64>(blockIdx.x % G1_BX, blockIdx.x / G1_BX,
                hhi, hlo, wgt_hi, wgt_lo, gbf, N_NODES, HOUT);
}

// ---- scan stage 1: per-block sums ----
__global__ __launch_bounds__(256) void k_s1(const int* __restrict__ deg,
                                            int* __restrict__ bsum) {
  __shared__ int ss[256];
  int t = threadIdx.x;
  int i = blockIdx.x * 256 + t;
  ss[t] = (i < N_NODES) ? deg[i] : 0;
  __syncthreads();
  for (int d = 128; d > 0; d >>= 1) {
    if (t < d) ss[t] += ss[t + d];
    __syncthreads();
  }
  if (t == 0) bsum[blockIdx.x] = ss[0];
}

// ---- scan stage 2: exclusive scan of block sums ----
__global__ __launch_bounds__(256) void k_s2(const int* __restrict__ bsum,
                                            int* __restrict__ bbase,
                                            int* __restrict__ off) {
  __shared__ int ss[256];
  int t = threadIdx.x;
  int v = (t < NBLK) ? bsum[t] : 0;
  ss[t] = v;
  __syncthreads();
  for (int d = 1; d < 256; d <<= 1) {
    int u = (t >= d) ? ss[t - d] : 0;
    __syncthreads();
    ss[t] += u;
    __syncthreads();
  }
  if (t < NBLK) bbase[t] = ss[t] - v;
  if (t == NBLK - 1) off[N_NODES] = ss[t];
}

// ---- scan stage 3: block-local scan + base ----
__global__ __launch_bounds__(256) void k_s3(const int* __restrict__ deg,
                                            const int* __restrict__ bbase,
                                            int* __restrict__ off) {
  __shared__ int ss[256];
  int t = threadIdx.x;
  int i = blockIdx.x * 256 + t;
  int v = (i < N_NODES) ? deg[i] : 0;
  ss[t] = v;
  __syncthreads();
  for (int d = 1; d < 256; d <<= 1) {
    int u = (t >= d) ? ss[t - d] : 0;
    __syncthreads();
    ss[t] += u;
    __syncthreads();
  }
  if (i < N_NODES) off[i] = bbase[blockIdx.x] + ss[t] - v;
}

// ---- RGCN: gather from bf16 xt; wave/node; emits h (bf16 hi/lo) AND
//      attention coefficients a_s/a_d = h @ (W_gat @ att) (fused) ----
__global__ __launch_bounds__(256) void rgcn_gather(const unsigned short* __restrict__ xtbf,
                                                   const int* __restrict__ off,
                                                   const int* __restrict__ eprep,
                                                   const float* __restrict__ b_rgcn,
                                                   const float* __restrict__ was,
                                                   const float* __restrict__ wad,
                                                   unsigned short* __restrict__ hhi,
                                                   unsigned short* __restrict__ hlo,
                                                   float* __restrict__ a_s,
                                                   float* __restrict__ a_d) {
  int wid = (blockIdx.x * 256 + threadIdx.x) >> 6;
  int lane = threadIdx.x & 63;
  int half = lane >> 5;
  int cp = lane & 31;
  int start = off[wid], end = off[wid + 1];
  float a0x=0.f,a0y=0.f,a1x=0.f,a1y=0.f,a2x=0.f,a2y=0.f,a3x=0.f,a3y=0.f;
  int c0=0,c1=0,c2=0,c3=0;
  int niter = (end - start + 1) >> 1;
  for (int t = 0; t < niter; t += 2) {
    int idx0 = start + 2 * t + half;
    int idx1 = idx0 + 2;
    int p0 = (idx0 < end) ? eprep[idx0] : 0x70000;
    int p1 = (idx1 < end) ? eprep[idx1] : 0x70000;
    int s0 = p0 & 0xFFFF, r0 = p0 >> 16;
    int s1 = p1 & 0xFFFF, r1 = p1 >> 16;
    unsigned u0 = *reinterpret_cast<const unsigned*>(
        &xtbf[(size_t)s0 * MBIG + H1 + (r0 << 6) + cp * 2]);
    unsigned u1 = *reinterpret_cast<const unsigned*>(
        &xtbf[(size_t)s1 * MBIG + H1 + (r1 << 6) + cp * 2]);
    float v0x = bflo(u0), v0y = bfhi(u0);
    float v1x = bflo(u1), v1y = bfhi(u1);
    a0x += (r0==0)?v0x:0.f; a0y += (r0==0)?v0y:0.f; c0 += (r0==0);
    a1x += (r0==1)?v0x:0.f; a1y += (r0==1)?v0y:0.f; c1 += (r0==1);
    a2x += (r0==2)?v0x:0.f; a2y += (r0==2)?v0y:0.f; c2 += (r0==2);
    a3x += (r0==3)?v0x:0.f; a3y += (r0==3)?v0y:0.f; c3 += (r0==3);
    a0x += (r1==0)?v1x:0.f; a0y += (r1==0)?v1y:0.f; c0 += (r1==0);
    a1x += (r1==1)?v1x:0.f; a1y += (r1==1)?v1y:0.f; c1 += (r1==1);
    a2x += (r1==2)?v1x:0.f; a2y += (r1==2)?v1y:0.f; c2 += (r1==2);
    a3x += (r1==3)?v1x:0.f; a3y += (r1==3)?v1y:0.f; c3 += (r1==3);
  }
  a0x += __shfl_xor(a0x, 32); a0y += __shfl_xor(a0y, 32);
  a1x += __shfl_xor(a1x, 32); a1y += __shfl_xor(a1y, 32);
  a2x += __shfl_xor(a2x, 32); a2y += __shfl_xor(a2y, 32);
  a3x += __shfl_xor(a3x, 32); a3y += __shfl_xor(a3y, 32);
  c0 += __shfl_xor(c0, 32); c1 += __shfl_xor(c1, 32);
  c2 += __shfl_xor(c2, 32); c3 += __shfl_xor(c3, 32);
  if (half == 0) {
    unsigned ur = *reinterpret_cast<const unsigned*>(&xtbf[(size_t)wid * MBIG + cp * 2]);
    float2 bb = *reinterpret_cast<const float2*>(&b_rgcn[cp * 2]);
    float i0 = 1.0f / (float)max(c0, 1);
    float i1 = 1.0f / (float)max(c1, 1);
    float i2 = 1.0f / (float)max(c2, 1);
    float i3 = 1.0f / (float)max(c3, 1);
    float vx = bflo(ur) + bb.x + a0x * i0 + a1x * i1 + a2x * i2 + a3x * i3;
    float vy = bfhi(ur) + bb.y + a0y * i0 + a1y * i1 + a2y * i2 + a3y * i3;
    vx = fmaxf(vx, 0.f);
    vy = fmaxf(vy, 0.f);
    unsigned short hx = f2bf(vx), hy = f2bf(vy);
    ushort2 hv = {hx, hy};
    ushort2 lv = {f2bf(vx - bf2f(hx)), f2bf(vy - bf2f(hy))};
    *reinterpret_cast<ushort2*>(&hhi[(size_t)wid * H1 + cp * 2]) = hv;
    *reinterpret_cast<ushort2*>(&hlo[(size_t)wid * H1 + cp * 2]) = lv;
    // ---- fused attention coefficients: a = h @ was / h @ wad ----
    float4 wsA = *reinterpret_cast<const float4*>(&was[cp * 8]);      // k=2cp
    float4 wsB = *reinterpret_cast<const float4*>(&was[cp * 8 + 4]);  // k=2cp+1
    float4 wdA = *reinterpret_cast<const float4*>(&wad[cp * 8]);
    float4 wdB = *reinterpret_cast<const float4*>(&wad[cp * 8 + 4]);
    float ps0 = vx * wsA.x + vy * wsB.x;
    float ps1 = vx * wsA.y + vy * wsB.y;
    float ps2 = vx * wsA.z + vy * wsB.z;
    float ps3 = vx * wsA.w + vy * wsB.w;
    float pd0 = vx * wdA.x + vy * wdB.x;
    float pd1 = vx * wdA.y + vy * wdB.y;
    float pd2 = vx * wdA.z + vy * wdB.z;
    float pd3 = vx * wdA.w + vy * wdB.w;
#pragma unroll
    for (int d = 1; d < 32; d <<= 1) {
      ps0 += __shfl_xor(ps0, d); ps1 += __shfl_xor(ps1, d);
      ps2 += __shfl_xor(ps2, d); ps3 += __shfl_xor(ps3, d);
      pd0 += __shfl_xor(pd0, d); pd1 += __shfl_xor(pd1, d);
      pd2 += __shfl_xor(pd2, d); pd3 += __shfl_xor(pd3, d);
    }
    if (cp == 0) {
      *reinterpret_cast<float4*>(&a_s[(size_t)wid * 4]) = make_float4(ps0, ps1, ps2, ps3);
      *reinterpret_cast<float4*>(&a_d[(size_t)wid * 4]) = make_float4(pd0, pd1, pd2, pd3);
    }
  }
}

// ---- GAT + head fused ----
constexpr int GAT_BLOCKS = 2048;
constexpr int GAT_WAVES = GAT_BLOCKS * 4;   // 8192
__global__ __launch_bounds__(256) void gat_fused(const unsigned short* __restrict__ gbf,
                                                 const float* __restrict__ a_s,
                                                 const float* __restrict__ a_d,
                                                 const int* __restrict__ off,
                                                 const int* __restrict__ eprep,
                                                 const float* __restrict__ b_gat,
                                                 const float* __restrict__ W1,
                                                 const float* __restrict__ b1,
                                                 const int* __restrict__ batch,
                                                 unsigned* __restrict__ p_mono) {
  __shared__ float w1s[HOUT * 16];        // W1[k][j]
  __shared__ float ob[4][HOUT];           // per-wave o row
  __shared__ unsigned sp[N_GRAPHS * 16];
  const int t = threadIdx.x;
  for (int i = t; i < HOUT * 16; i += 256) w1s[i] = W1[i];
  for (int i = t; i < N_GRAPHS * 16; i += 256) sp[i] = MONO_NEG_INF;
  __syncthreads();
  const int wv = t >> 6, lane = t & 63;
  const int hh = lane >> 4;
  const int jj = lane & 15, grp = lane >> 4;
  const int w = blockIdx.x * 4 + wv;
  const int q = N_NODES / GAT_WAVES;
  const int r = N_NODES % GAT_WAVES;
  const int nbeg = w * q + ((w < r) ? w : r);
  const int ncnt = q + ((w < r) ? 1 : 0);
  for (int wid = nbeg; wid < nbeg + ncnt; ++wid) {
    int start = off[wid], end = off[wid + 1];
    float4 ad4 = *reinterpret_cast<const float4*>(a_d + (size_t)wid * 4);
    float adh = (hh == 0) ? ad4.x : (hh == 1) ? ad4.y : (hh == 2) ? ad4.z : ad4.w;
    float ox = 0.f, oy = 0.f, den = 0.f;
    int i = start;
    for (; i + 4 <= end; i += 4) {
      int p0 = eprep[i], p1 = eprep[i + 1], p2 = eprep[i + 2], p3 = eprep[i + 3];
      int s0 = p0 & 0xFFFF, s1 = p1 & 0xFFFF, s2 = p2 & 0xFFFF, s3 = p3 & 0xFFFF;
      float as0 = a_s[(size_t)s0 * 4 + hh];
      float as1 = a_s[(size_t)s1 * 4 + hh];
      float as2 = a_s[(size_t)s2 * 4 + hh];
      float as3 = a_s[(size_t)s3 * 4 + hh];
      unsigned u0 = *reinterpret_cast<const unsigned*>(&gbf[(size_t)s0 * HOUT + lane * 2]);
      unsigned u1 = *reinterpret_cast<const unsigned*>(&gbf[(size_t)s1 * HOUT + lane * 2]);
      unsigned u2 = *reinterpret_cast<const unsigned*>(&gbf[(size_t)s2 * HOUT + lane * 2]);
      unsigned u3 = *reinterpret_cast<const unsigned*>(&gbf[(size_t)s3 * HOUT + lane * 2]);
      float e0 = as0 + adh; e0 = (e0 > 0.f) ? e0 : 0.2f * e0;
      float e1 = as1 + adh; e1 = (e1 > 0.f) ? e1 : 0.2f * e1;
      float e2 = as2 + adh; e2 = (e2 > 0.f) ? e2 : 0.2f * e2;
      float e3 = as3 + adh; e3 = (e3 > 0.f) ? e3 : 0.2f * e3;
      float x0 = __expf(e0), x1 = __expf(e1), x2 = __expf(e2), x3 = __expf(e3);
      den += x0 + x1 + x2 + x3;
      ox += x0 * bflo(u0) + x1 * bflo(u1) + x2 * bflo(u2) + x3 * bflo(u3);
      oy += x0 * bfhi(u0) + x1 * bfhi(u1) + x2 * bfhi(u2) + x3 * bfhi(u3);
    }
    for (; i < end; ++i) {
      int p = eprep[i];
      int s = p & 0xFFFF;
      float as = a_s[(size_t)s * 4 + hh];
      unsigned u = *reinterpret_cast<const unsigned*>(&gbf[(size_t)s * HOUT + lane * 2]);
      float e = as + adh; e = (e > 0.f) ? e : 0.2f * e;
      float ex = __expf(e);
      den += ex;
      ox += ex * bflo(u);
      oy += ex * bfhi(u);
    }
    float dinv = (den > 0.f) ? (1.0f / den) : 0.f;
    float2 bg = *reinterpret_cast<const float2*>(b_gat + lane * 2);
    float vx = ox * dinv + bg.x; vx = (vx > 0.f) ? vx : 0.01f * vx;
    float vy = oy * dinv + bg.y; vy = (vy > 0.f) ? vy : 0.01f * vy;
    *reinterpret_cast<float2*>(&ob[wv][lane * 2]) = make_float2(vx, vy);
    float acc = 0.f;
#pragma unroll 8
    for (int i2 = 0; i2 < 32; ++i2) {
      int c = grp + 4 * i2;
      acc += ob[wv][c] * w1s[c * 16 + jj];
    }
    acc += __shfl_xor(acc, 16);
    acc += __shfl_xor(acc, 32);
    float z = acc + b1[jj];
    z = (z > 0.f) ? z : 0.01f * z;
    int b = batch[wid];
    if (lane < 16) atomicMax(&sp[b * 16 + jj], f2mono(z));
  }
  __syncthreads();
  for (int i = t; i < N_GRAPHS * 16; i += 256) {
    unsigned v = sp[i];
    if (v != MONO_NEG_INF) atomicMax(p_mono + i, v);
  }
}

// ---- y = p @ W2 + b2 ----
__global__ void final_y(const unsigned* __restrict__ p_mono,
                        const float* __restrict__ W2,
                        const float* __restrict__ b2,
                        float* __restrict__ y) {
  int gr = threadIdx.x;
  if (gr >= N_GRAPHS) return;
  float acc = b2[0];
#pragma unroll
  for (int k = 0; k < 16; ++k) acc += mono2f(p_mono[gr * 16 + k]) * W2[k];
  y[gr] = acc;
}

extern "C" void kernel_launch(void* const* d_in, const int* in_sizes, int n_in,
                              void* d_out, int out_size, void* d_ws, size_t ws_size,
                              hipStream_t stream) {
  const float* x       = (const float*)d_in[0];
  const int*   eidx    = (const int*)d_in[1];
  const int*   etype   = (const int*)d_in[2];
  const int*   batch   = (const int*)d_in[3];
  const float* W_rel   = (const float*)d_in[4];
  const float* W_root  = (const float*)d_in[5];
  const float* b_rgcn  = (const float*)d_in[6];
  const float* W_gat   = (const float*)d_in[7];
  const float* att_src = (const float*)d_in[8];
  const float* att_dst = (const float*)d_in[9];
  const float* b_gat   = (const float*)d_in[10];
  const float* W1      = (const float*)d_in[11];
  const float* b1      = (const float*)d_in[12];
  const float* W2      = (const float*)d_in[13];
  const float* b2      = (const float*)d_in[14];
  float* y = (float*)d_out;

  const int* src = eidx;
  const int* dst = eidx + N_EDGES;

  float* ws = (float*)d_ws;
  // ---- workspace layout (float offsets) ----
  const size_t OFF_XTBF= 0;           //  8,007,680 f: xt bf16 [N_PAD,320]
  const size_t OFF_GBF = 0;           //  g bf16 [N_PAD,128] (reuses xtbf)
  const size_t OFF_XHI = 8007680;     //  3,203,072 f: x hi bf16 [N_PAD,128]
  const size_t OFF_XLO = 11210752;    //  3,203,072 f: x lo
  const size_t OFF_HHI = 14413824;    //  1,601,536 f: h hi bf16 [N_PAD,64]
  const size_t OFF_HLO = 16015360;    //  1,601,536 f: h lo
  const size_t OFF_AS  = 17616896;    //    200,000  a_src
  const size_t OFF_AD  = 17816896;    //    200,000  a_dst
  const size_t OFF_PM  = 18016896;    //      1,024 f = 1024 u32 pool max
  const size_t OFF_DEG = 18017920;    //     50,000  deg (int)
  const size_t OFF_OFFS= 18067920;    //     50,001  off (int)
  const size_t OFF_RANK= 18117924;    //    800,000  rank (int)
  const size_t OFF_EP  = 18917924;    //    800,000  eprep (int)
  const size_t OFF_BS  = 19717924;    //        196
  const size_t OFF_BB  = 19718120;    //        196
  const size_t OFF_WAS = 19718320;    //        256  was (f32, 16B aligned)
  const size_t OFF_WAD = 19718576;    //        256  wad
  const size_t OFF_WBH = 19718832;    //     20,480  WbigT_hi (16B aligned)
  const size_t OFF_WBL = 19739312;    //     20,480  WbigT_lo
  const size_t OFF_WGH = 19759792;    //      4,096  WgatT_hi
  const size_t OFF_WGL = 19763888;    //      4,096  WgatT_lo
  const size_t TOTAL_F = 19767984;
  if (ws_size < TOTAL_F * sizeof(float)) return;

  unsigned short* xtbf = (unsigned short*)(ws + OFF_XTBF);
  unsigned short* gbf  = (unsigned short*)(ws + OFF_GBF);
  unsigned short* xhi  = (unsigned short*)(ws + OFF_XHI);
  unsigned short* xlo  = (unsigned short*)(ws + OFF_XLO);
  unsigned short* hhi  = (unsigned short*)(ws + OFF_HHI);
  unsigned short* hlo  = (unsigned short*)(ws + OFF_HLO);
  float* a_s   = ws + OFF_AS;
  float* a_d   = ws + OFF_AD;
  unsigned* pm = (unsigned*)(ws + OFF_PM);
  int* deg     = (int*)(ws + OFF_DEG);
  int* offs    = (int*)(ws + OFF_OFFS);
  int* rank    = (int*)(ws + OFF_RANK);
  int* eprep   = (int*)(ws + OFF_EP);
  int* bsum    = (int*)(ws + OFF_BS);
  int* bbase   = (int*)(ws + OFF_BB);
  float* was   = ws + OFF_WAS;
  float* wad   = ws + OFF_WAD;
  unsigned short* wbt_hi = (unsigned short*)(ws + OFF_WBH);
  unsigned short* wbt_lo = (unsigned short*)(ws + OFF_WBL);
  unsigned short* wgt_hi = (unsigned short*)(ws + OFF_WGH);
  unsigned short* wgt_lo = (unsigned short*)(ws + OFF_WGL);

  // 1. deg = 0 (before fused hist)
  hipMemsetAsync(deg, 0, N_NODES * sizeof(int), stream);

  // 2. fused prep: xcvt | hist(+rank) | build_wT | init_mono | watt
  pre_fused<<<XCVT_BLOCKS + HIST_BLOCKS + WT_BLOCKS + 2, 256, 0, stream>>>(
      x, W_root, W_rel, W_gat, att_src, att_dst, dst, xhi, xlo,
      wbt_hi, wbt_lo, wgt_hi, wgt_lo, deg, rank, pm, was, wad);

  // 3. scan (off from deg)
  k_s1<<<NBLK, 256, 0, stream>>>(deg, bsum);
  k_s2<<<1, 256, 0, stream>>>(bsum, bbase, offs);
  k_s3<<<NBLK, 256, 0, stream>>>(deg, bbase, offs);

  // 4. gemm1 (xt = x @ Wbig) fused with CSR fill
  gemm1_fill<<<G1_BLOCKS + HIST_BLOCKS, 256, 0, stream>>>(
      xhi, xlo, wbt_hi, wbt_lo, xtbf, src, dst, etype, offs, rank, eprep);

  // 5. RGCN gather -> h (bf16 hi/lo) + fused a_s/a_d
  rgcn_gather<<<N_NODES / 4, 256, 0, stream>>>(xtbf, offs, eprep, b_rgcn,
                                               was, wad, hhi, hlo, a_s, a_d);

  // 6. g = h @ W_gat
  gemm2_k<<<G1_BX * (HOUT / 64), 256, 0, stream>>>(hhi, hlo, wgt_hi, wgt_lo, gbf);

  // 7. fused GAT aggregation + head + per-graph max pool
  gat_fused<<<GAT_BLOCKS, 256, 0, stream>>>(gbf, a_s, a_d, offs, eprep, b_gat,
                                            W1, b1, batch, pm);

  // 8. y = p @ W2 + b2
  final_y<<<1, 64, 0, stream>>>(pm, W2, b2, y);
}

// Round 15
// 214.084 us; speedup vs baseline: 1.2347x; 1.0290x over previous
//
#include <hip/hip_runtime.h>
#include <hip/hip_bf16.h>

constexpr int N_NODES = 50000;
constexpr int N_EDGES = 800000;
constexpr int F_IN = 128;
constexpr int H1 = 64;
constexpr int HEADS = 4;
constexpr int D_H = 32;
constexpr int HOUT = HEADS * D_H;       // 128
constexpr int N_REL = 4;
constexpr int N_GRAPHS = 64;
constexpr int MBIG = H1 * (1 + N_REL);  // 320
constexpr int NBLK = (N_NODES + 255) / 256;  // 196
constexpr int N_PAD = 50048;            // 64 * 782

typedef __attribute__((ext_vector_type(8))) short bf16x8;
typedef __attribute__((ext_vector_type(4))) float f32x4;

// ---- monotonic float<->uint for atomicMax on floats ----
__device__ __forceinline__ unsigned f2mono(float f) {
  unsigned u = __float_as_uint(f);
  return (u & 0x80000000u) ? ~u : (u | 0x80000000u);
}
__device__ __forceinline__ float mono2f(unsigned m) {
  unsigned u = (m & 0x80000000u) ? (m & 0x7FFFFFFFu) : ~m;
  return __uint_as_float(u);
}
constexpr unsigned MONO_NEG_INF = 0x007FFFFFu;

// ---- bf16 helpers ----
__device__ __forceinline__ unsigned short f2bf(float f) {
  unsigned u = __float_as_uint(f);
  unsigned r = (u + 0x7FFFu + ((u >> 16) & 1u)) >> 16;  // RNE
  return (unsigned short)r;
}
__device__ __forceinline__ float bf2f(unsigned short h) {
  return __uint_as_float((unsigned)h << 16);
}
__device__ __forceinline__ float bflo(unsigned u) { return __uint_as_float(u << 16); }
__device__ __forceinline__ float bfhi(unsigned u) { return __uint_as_float(u & 0xFFFF0000u); }

// ======= fused prep: hist | build_wT | init_mono | watt =======
constexpr int HIST_BLOCKS = (N_EDGES + 255) / 256;               // 3125
constexpr int WT_BLOCKS = (MBIG * F_IN + HOUT * H1 + 255) / 256; // 192

__global__ __launch_bounds__(256) void pre_fused(
    const float* __restrict__ W_root, const float* __restrict__ W_rel,
    const float* __restrict__ W_gat,
    const float* __restrict__ att_src, const float* __restrict__ att_dst,
    const int* __restrict__ dst,
    unsigned short* __restrict__ WbT_hi, unsigned short* __restrict__ WbT_lo,
    unsigned short* __restrict__ WgT_hi, unsigned short* __restrict__ WgT_lo,
    int* __restrict__ deg, int* __restrict__ rank,
    unsigned* __restrict__ pm,
    float* __restrict__ was, float* __restrict__ wad) {
  int b = blockIdx.x;
  if (b < HIST_BLOCKS) {
    int e = b * 256 + threadIdx.x;
    if (e < N_EDGES) rank[e] = atomicAdd(&deg[dst[e]], 1);
  } else if (b < HIST_BLOCKS + WT_BLOCKS) {
    int i = (b - HIST_BLOCKS) * 256 + threadIdx.x;
    if (i < MBIG * F_IN) {
      int c = i / F_IN, k = i % F_IN;
      float w = (c < H1) ? W_root[k * H1 + c]
                         : W_rel[((size_t)(((c - H1) >> 6) * F_IN + k)) * H1 + ((c - H1) & 63)];
      unsigned short hi = f2bf(w);
      WbT_hi[i] = hi;
      WbT_lo[i] = f2bf(w - bf2f(hi));
    } else {
      int j = i - MBIG * F_IN;
      if (j < HOUT * H1) {
        int c = j / H1, k = j % H1;
        float w = W_gat[k * HOUT + c];
        unsigned short hi = f2bf(w);
        WgT_hi[j] = hi;
        WgT_lo[j] = f2bf(w - bf2f(hi));
      }
    }
  } else if (b == HIST_BLOCKS + WT_BLOCKS) {
    for (int i = threadIdx.x; i < N_GRAPHS * 16; i += 256) pm[i] = MONO_NEG_INF;
  } else {
    // watt: was/wad[k*4+hh] = sum_d W_gat[k][hh*32+d] * att[hh][d]
    int t = threadIdx.x;          // t = k*4 + hh, 256 threads exactly
    int k = t >> 2, hh = t & 3;
    float s = 0.f, d2 = 0.f;
#pragma unroll 8
    for (int dd = 0; dd < D_H; ++dd) {
      float wg = W_gat[k * HOUT + hh * D_H + dd];
      s += wg * att_src[hh * D_H + dd];
      d2 += wg * att_dst[hh * D_H + dd];
    }
    was[t] = s;
    wad[t] = d2;
  }
}

// ================= LDS-staged split-bf16 MFMA GEMM =========
// Block = 64 rows x 64 cols, 4 waves (2x2), 2x2 frags/wave. XOR-swizzled
// LDS (bits 3-5). SPLIT=false: A is f32, converted to hi/lo during staging
// (conversion hides under latency). SPLIT=true: A pre-split hi/lo, pure copy.
template <int K, bool SPLIT>
__device__ __forceinline__ void gemm_body(int bx, int by,
    const void* __restrict__ A0,      // SPLIT ? Ahi : f32 A
    const void* __restrict__ A1,      // SPLIT ? Alo : unused
    const unsigned short* __restrict__ BT_hi,
    const unsigned short* __restrict__ BT_lo,
    unsigned short* __restrict__ Cbf, int N, int M) {
  __shared__ unsigned short Ah[64 * K];
  __shared__ unsigned short Al[64 * K];
  const int tid = threadIdx.x;
  const int rowBase = bx * 64;
  const int colBase = by * 64;
  if (SPLIT) {
    const unsigned short* Ahi_ = (const unsigned short*)A0;
    const unsigned short* Alo_ = (const unsigned short*)A1;
    constexpr int KQ8 = K / 8;               // uint4 (8 ushorts) per row
    for (int s = tid; s < 64 * KQ8; s += 256) {
      int r = s / KQ8, c8 = (s % KQ8) * 8;
      size_t gi = (size_t)(rowBase + r) * K + c8;
      int sw = c8 ^ ((r & 7) << 3);
      *reinterpret_cast<uint4*>(&Ah[r * K + sw]) =
          *reinterpret_cast<const uint4*>(&Ahi_[gi]);
      *reinterpret_cast<uint4*>(&Al[r * K + sw]) =
          *reinterpret_cast<const uint4*>(&Alo_[gi]);
    }
  } else {
    const float* Af = (const float*)A0;
    constexpr int KQ4 = K / 4;               // float4 per row
    for (int s = tid; s < 64 * KQ4; s += 256) {
      int r = s / KQ4, c4 = (s % KQ4) * 4;
      int gr = rowBase + r;
      float4 v = make_float4(0.f, 0.f, 0.f, 0.f);
      if (gr < N) v = *reinterpret_cast<const float4*>(&Af[(size_t)gr * K + c4]);
      ushort4 hi, lo;
      hi.x = f2bf(v.x); lo.x = f2bf(v.x - bf2f(hi.x));
      hi.y = f2bf(v.y); lo.y = f2bf(v.y - bf2f(hi.y));
      hi.z = f2bf(v.z); lo.z = f2bf(v.z - bf2f(hi.z));
      hi.w = f2bf(v.w); lo.w = f2bf(v.w - bf2f(hi.w));
      int sw = c4 ^ ((r & 7) << 3);          // XOR hits bits 3-5 only; bit2 kept
      *reinterpret_cast<ushort4*>(&Ah[r * K + sw]) = hi;
      *reinterpret_cast<ushort4*>(&Al[r * K + sw]) = lo;
    }
  }
  __syncthreads();
  const int wv = tid >> 6, lane = tid & 63;
  const int wr = (wv >> 1) * 32, wc = (wv & 1) * 32;
  const int lrow = lane & 15, lkc = lane >> 4;
  f32x4 acc[2][2] = {};
#pragma unroll
  for (int ks = 0; ks < K; ks += 32) {
    bf16x8 ah[2], al[2], bh[2], bl[2];
#pragma unroll
    for (int fr = 0; fr < 2; ++fr) {
      int r = wr + fr * 16 + lrow;
      int sw = (ks + lkc * 8) ^ ((r & 7) << 3);
      ah[fr] = *reinterpret_cast<const bf16x8*>(&Ah[r * K + sw]);
      al[fr] = *reinterpret_cast<const bf16x8*>(&Al[r * K + sw]);
    }
#pragma unroll
    for (int fc = 0; fc < 2; ++fc) {
      int c = colBase + wc + fc * 16 + lrow;
      bh[fc] = *reinterpret_cast<const bf16x8*>(&BT_hi[(size_t)c * K + ks + lkc * 8]);
      bl[fc] = *reinterpret_cast<const bf16x8*>(&BT_lo[(size_t)c * K + ks + lkc * 8]);
    }
#pragma unroll
    for (int fr = 0; fr < 2; ++fr)
#pragma unroll
      for (int fc = 0; fc < 2; ++fc) {
        acc[fr][fc] = __builtin_amdgcn_mfma_f32_16x16x32_bf16(ah[fr], bh[fc], acc[fr][fc], 0, 0, 0);
        acc[fr][fc] = __builtin_amdgcn_mfma_f32_16x16x32_bf16(ah[fr], bl[fc], acc[fr][fc], 0, 0, 0);
        acc[fr][fc] = __builtin_amdgcn_mfma_f32_16x16x32_bf16(al[fr], bh[fc], acc[fr][fc], 0, 0, 0);
      }
  }
#pragma unroll
  for (int fr = 0; fr < 2; ++fr) {
#pragma unroll
    for (int i = 0; i < 4; ++i) {
      int row = rowBase + wr + fr * 16 + lkc * 4 + i;
      if (row < N) {
#pragma unroll
        for (int fc = 0; fc < 2; ++fc) {
          int col = colBase + wc + fc * 16 + lrow;
          Cbf[(size_t)row * M + col] = f2bf(acc[fr][fc][i]);
        }
      }
    }
  }
}

// ---- gemm1 (K=128, xt from f32 x) fused with CSR fill ----
constexpr int G1_BX = N_PAD / 64;          // 782
constexpr int G1_BLOCKS = G1_BX * (MBIG / 64);  // 3910
__global__ __launch_bounds__(256) void gemm1_fill(
    const float* __restrict__ x,
    const unsigned short* __restrict__ wbt_hi, const unsigned short* __restrict__ wbt_lo,
    unsigned short* __restrict__ xtbf,
    const int* __restrict__ src, const int* __restrict__ dst,
    const int* __restrict__ etype, const int* __restrict__ off,
    const int* __restrict__ rank, int* __restrict__ eprep) {
  if (blockIdx.x < G1_BLOCKS) {
    gemm_body<128, false>(blockIdx.x % G1_BX, blockIdx.x / G1_BX,
                          x, nullptr, wbt_hi, wbt_lo, xtbf, N_NODES, MBIG);
  } else {
    int e = (blockIdx.x - G1_BLOCKS) * 256 + threadIdx.x;
    if (e < N_EDGES) {
      int pos = off[dst[e]] + rank[e];
      eprep[pos] = src[e] | (etype[e] << 16);
    }
  }
}

// ---- gemm2 (K=64, g from pre-split h) ----
__global__ __launch_bounds__(256) void gemm2_k(
    const unsigned short* __restrict__ hhi, const unsigned short* __restrict__ hlo,
    const unsigned short* __restrict__ wgt_hi, const unsigned short* __restrict__ wgt_lo,
    unsigned short* __restrict__ gbf) {
  gemm_body<64, true>(blockIdx.x % G1_BX, blockIdx.x / G1_BX,
                      hhi, hlo, wgt_hi, wgt_lo, gbf, N_NODES, HOUT);
}

// ---- scan stage 1: per-block sums ----
__global__ __launch_bounds__(256) void k_s1(const int* __restrict__ deg,
                                            int* __restrict__ bsum) {
  __shared__ int ss[256];
  int t = threadIdx.x;
  int i = blockIdx.x * 256 + t;
  ss[t] = (i < N_NODES) ? deg[i] : 0;
  __syncthreads();
  for (int d = 128; d > 0; d >>= 1) {
    if (t < d) ss[t] += ss[t + d];
    __syncthreads();
  }
  if (t == 0) bsum[blockIdx.x] = ss[0];
}

// ---- scan stage 2: exclusive scan of block sums ----
__global__ __launch_bounds__(256) void k_s2(const int* __restrict__ bsum,
                                            int* __restrict__ bbase,
                                            int* __restrict__ off) {
  __shared__ int ss[256];
  int t = threadIdx.x;
  int v = (t < NBLK) ? bsum[t] : 0;
  ss[t] = v;
  __syncthreads();
  for (int d = 1; d < 256; d <<= 1) {
    int u = (t >= d) ? ss[t - d] : 0;
    __syncthreads();
    ss[t] += u;
    __syncthreads();
  }
  if (t < NBLK) bbase[t] = ss[t] - v;
  if (t == NBLK - 1) off[N_NODES] = ss[t];
}

// ---- scan stage 3: block-local scan + base ----
__global__ __launch_bounds__(256) void k_s3(const int* __restrict__ deg,
                                            const int* __restrict__ bbase,
                                            int* __restrict__ off) {
  __shared__ int ss[256];
  int t = threadIdx.x;
  int i = blockIdx.x * 256 + t;
  int v = (i < N_NODES) ? deg[i] : 0;
  ss[t] = v;
  __syncthreads();
  for (int d = 1; d < 256; d <<= 1) {
    int u = (t >= d) ? ss[t - d] : 0;
    __syncthreads();
    ss[t] += u;
    __syncthreads();
  }
  if (i < N_NODES) off[i] = bbase[blockIdx.x] + ss[t] - v;
}

// ---- RGCN: gather from bf16 xt; wave/node; emits h (bf16 hi/lo) AND
//      attention coefficients a_s/a_d = h @ (W_gat @ att) ----
__global__ __launch_bounds__(256) void rgcn_gather(const unsigned short* __restrict__ xtbf,
                                                   const int* __restrict__ off,
                                                   const int* __restrict__ eprep,
                                                   const float* __restrict__ b_rgcn,
                                                   const float* __restrict__ was,
                                                   const float* __restrict__ wad,
                                                   unsigned short* __restrict__ hhi,
                                                   unsigned short* __restrict__ hlo,
                                                   float* __restrict__ a_s,
                                                   float* __restrict__ a_d) {
  int wid = (blockIdx.x * 256 + threadIdx.x) >> 6;
  int lane = threadIdx.x & 63;
  int half = lane >> 5;
  int cp = lane & 31;
  int start = off[wid], end = off[wid + 1];
  float a0x=0.f,a0y=0.f,a1x=0.f,a1y=0.f,a2x=0.f,a2y=0.f,a3x=0.f,a3y=0.f;
  int c0=0,c1=0,c2=0,c3=0;
  int niter = (end - start + 1) >> 1;
  for (int t = 0; t < niter; t += 2) {
    int idx0 = start + 2 * t + half;
    int idx1 = idx0 + 2;
    int p0 = (idx0 < end) ? eprep[idx0] : 0x70000;
    int p1 = (idx1 < end) ? eprep[idx1] : 0x70000;
    int s0 = p0 & 0xFFFF, r0 = p0 >> 16;
    int s1 = p1 & 0xFFFF, r1 = p1 >> 16;
    unsigned u0 = *reinterpret_cast<const unsigned*>(
        &xtbf[(size_t)s0 * MBIG + H1 + (r0 << 6) + cp * 2]);
    unsigned u1 = *reinterpret_cast<const unsigned*>(
        &xtbf[(size_t)s1 * MBIG + H1 + (r1 << 6) + cp * 2]);
    float v0x = bflo(u0), v0y = bfhi(u0);
    float v1x = bflo(u1), v1y = bfhi(u1);
    a0x += (r0==0)?v0x:0.f; a0y += (r0==0)?v0y:0.f; c0 += (r0==0);
    a1x += (r0==1)?v0x:0.f; a1y += (r0==1)?v0y:0.f; c1 += (r0==1);
    a2x += (r0==2)?v0x:0.f; a2y += (r0==2)?v0y:0.f; c2 += (r0==2);
    a3x += (r0==3)?v0x:0.f; a3y += (r0==3)?v0y:0.f; c3 += (r0==3);
    a0x += (r1==0)?v1x:0.f; a0y += (r1==0)?v1y:0.f; c0 += (r1==0);
    a1x += (r1==1)?v1x:0.f; a1y += (r1==1)?v1y:0.f; c1 += (r1==1);
    a2x += (r1==2)?v1x:0.f; a2y += (r1==2)?v1y:0.f; c2 += (r1==2);
    a3x += (r1==3)?v1x:0.f; a3y += (r1==3)?v1y:0.f; c3 += (r1==3);
  }
  a0x += __shfl_xor(a0x, 32); a0y += __shfl_xor(a0y, 32);
  a1x += __shfl_xor(a1x, 32); a1y += __shfl_xor(a1y, 32);
  a2x += __shfl_xor(a2x, 32); a2y += __shfl_xor(a2y, 32);
  a3x += __shfl_xor(a3x, 32); a3y += __shfl_xor(a3y, 32);
  c0 += __shfl_xor(c0, 32); c1 += __shfl_xor(c1, 32);
  c2 += __shfl_xor(c2, 32); c3 += __shfl_xor(c3, 32);
  if (half == 0) {
    unsigned ur = *reinterpret_cast<const unsigned*>(&xtbf[(size_t)wid * MBIG + cp * 2]);
    float2 bb = *reinterpret_cast<const float2*>(&b_rgcn[cp * 2]);
    float i0 = 1.0f / (float)max(c0, 1);
    float i1 = 1.0f / (float)max(c1, 1);
    float i2 = 1.0f / (float)max(c2, 1);
    float i3 = 1.0f / (float)max(c3, 1);
    float vx = bflo(ur) + bb.x + a0x * i0 + a1x * i1 + a2x * i2 + a3x * i3;
    float vy = bfhi(ur) + bb.y + a0y * i0 + a1y * i1 + a2y * i2 + a3y * i3;
    vx = fmaxf(vx, 0.f);
    vy = fmaxf(vy, 0.f);
    unsigned short hx = f2bf(vx), hy = f2bf(vy);
    ushort2 hv = {hx, hy};
    ushort2 lv = {f2bf(vx - bf2f(hx)), f2bf(vy - bf2f(hy))};
    *reinterpret_cast<ushort2*>(&hhi[(size_t)wid * H1 + cp * 2]) = hv;
    *reinterpret_cast<ushort2*>(&hlo[(size_t)wid * H1 + cp * 2]) = lv;
    // ---- fused attention coefficients: a = h @ was / h @ wad ----
    float4 wsA = *reinterpret_cast<const float4*>(&was[cp * 8]);      // k=2cp
    float4 wsB = *reinterpret_cast<const float4*>(&was[cp * 8 + 4]);  // k=2cp+1
    float4 wdA = *reinterpret_cast<const float4*>(&wad[cp * 8]);
    float4 wdB = *reinterpret_cast<const float4*>(&wad[cp * 8 + 4]);
    float ps0 = vx * wsA.x + vy * wsB.x;
    float ps1 = vx * wsA.y + vy * wsB.y;
    float ps2 = vx * wsA.z + vy * wsB.z;
    float ps3 = vx * wsA.w + vy * wsB.w;
    float pd0 = vx * wdA.x + vy * wdB.x;
    float pd1 = vx * wdA.y + vy * wdB.y;
    float pd2 = vx * wdA.z + vy * wdB.z;
    float pd3 = vx * wdA.w + vy * wdB.w;
#pragma unroll
    for (int d = 1; d < 32; d <<= 1) {
      ps0 += __shfl_xor(ps0, d); ps1 += __shfl_xor(ps1, d);
      ps2 += __shfl_xor(ps2, d); ps3 += __shfl_xor(ps3, d);
      pd0 += __shfl_xor(pd0, d); pd1 += __shfl_xor(pd1, d);
      pd2 += __shfl_xor(pd2, d); pd3 += __shfl_xor(pd3, d);
    }
    if (cp == 0) {
      *reinterpret_cast<float4*>(&a_s[(size_t)wid * 4]) = make_float4(ps0, ps1, ps2, ps3);
      *reinterpret_cast<float4*>(&a_d[(size_t)wid * 4]) = make_float4(pd0, pd1, pd2, pd3);
    }
  }
}

// ---- GAT + head fused ----
constexpr int GAT_BLOCKS = 2048;
constexpr int GAT_WAVES = GAT_BLOCKS * 4;   // 8192
__global__ __launch_bounds__(256) void gat_fused(const unsigned short* __restrict__ gbf,
                                                 const float* __restrict__ a_s,
                                                 const float* __restrict__ a_d,
                                                 const int* __restrict__ off,
                                                 const int* __restrict__ eprep,
                                                 const float* __restrict__ b_gat,
                                                 const float* __restrict__ W1,
                                                 const float* __restrict__ b1,
                                                 const int* __restrict__ batch,
                                                 unsigned* __restrict__ p_mono) {
  __shared__ float w1s[HOUT * 16];        // W1[k][j]
  __shared__ float ob[4][HOUT];           // per-wave o row
  __shared__ unsigned sp[N_GRAPHS * 16];
  const int t = threadIdx.x;
  for (int i = t; i < HOUT * 16; i += 256) w1s[i] = W1[i];
  for (int i = t; i < N_GRAPHS * 16; i += 256) sp[i] = MONO_NEG_INF;
  __syncthreads();
  const int wv = t >> 6, lane = t & 63;
  const int hh = lane >> 4;
  const int jj = lane & 15, grp = lane >> 4;
  const int w = blockIdx.x * 4 + wv;
  const int q = N_NODES / GAT_WAVES;
  const int r = N_NODES % GAT_WAVES;
  const int nbeg = w * q + ((w < r) ? w : r);
  const int ncnt = q + ((w < r) ? 1 : 0);
  for (int wid = nbeg; wid < nbeg + ncnt; ++wid) {
    int start = off[wid], end = off[wid + 1];
    float4 ad4 = *reinterpret_cast<const float4*>(a_d + (size_t)wid * 4);
    float adh = (hh == 0) ? ad4.x : (hh == 1) ? ad4.y : (hh == 2) ? ad4.z : ad4.w;
    float ox = 0.f, oy = 0.f, den = 0.f;
    int i = start;
    for (; i + 4 <= end; i += 4) {
      int p0 = eprep[i], p1 = eprep[i + 1], p2 = eprep[i + 2], p3 = eprep[i + 3];
      int s0 = p0 & 0xFFFF, s1 = p1 & 0xFFFF, s2 = p2 & 0xFFFF, s3 = p3 & 0xFFFF;
      float as0 = a_s[(size_t)s0 * 4 + hh];
      float as1 = a_s[(size_t)s1 * 4 + hh];
      float as2 = a_s[(size_t)s2 * 4 + hh];
      float as3 = a_s[(size_t)s3 * 4 + hh];
      unsigned u0 = *reinterpret_cast<const unsigned*>(&gbf[(size_t)s0 * HOUT + lane * 2]);
      unsigned u1 = *reinterpret_cast<const unsigned*>(&gbf[(size_t)s1 * HOUT + lane * 2]);
      unsigned u2 = *reinterpret_cast<const unsigned*>(&gbf[(size_t)s2 * HOUT + lane * 2]);
      unsigned u3 = *reinterpret_cast<const unsigned*>(&gbf[(size_t)s3 * HOUT + lane * 2]);
      float e0 = as0 + adh; e0 = (e0 > 0.f) ? e0 : 0.2f * e0;
      float e1 = as1 + adh; e1 = (e1 > 0.f) ? e1 : 0.2f * e1;
      float e2 = as2 + adh; e2 = (e2 > 0.f) ? e2 : 0.2f * e2;
      float e3 = as3 + adh; e3 = (e3 > 0.f) ? e3 : 0.2f * e3;
      float x0 = __expf(e0), x1 = __expf(e1), x2 = __expf(e2), x3 = __expf(e3);
      den += x0 + x1 + x2 + x3;
      ox += x0 * bflo(u0) + x1 * bflo(u1) + x2 * bflo(u2) + x3 * bflo(u3);
      oy += x0 * bfhi(u0) + x1 * bfhi(u1) + x2 * bfhi(u2) + x3 * bfhi(u3);
    }
    for (; i < end; ++i) {
      int p = eprep[i];
      int s = p & 0xFFFF;
      float as = a_s[(size_t)s * 4 + hh];
      unsigned u = *reinterpret_cast<const unsigned*>(&gbf[(size_t)s * HOUT + lane * 2]);
      float e = as + adh; e = (e > 0.f) ? e : 0.2f * e;
      float ex = __expf(e);
      den += ex;
      ox += ex * bflo(u);
      oy += ex * bfhi(u);
    }
    float dinv = (den > 0.f) ? (1.0f / den) : 0.f;
    float2 bg = *reinterpret_cast<const float2*>(b_gat + lane * 2);
    float vx = ox * dinv + bg.x; vx = (vx > 0.f) ? vx : 0.01f * vx;
    float vy = oy * dinv + bg.y; vy = (vy > 0.f) ? vy : 0.01f * vy;
    *reinterpret_cast<float2*>(&ob[wv][lane * 2]) = make_float2(vx, vy);
    float acc = 0.f;
#pragma unroll 8
    for (int i2 = 0; i2 < 32; ++i2) {
      int c = grp + 4 * i2;
      acc += ob[wv][c] * w1s[c * 16 + jj];
    }
    acc += __shfl_xor(acc, 16);
    acc += __shfl_xor(acc, 32);
    float z = acc + b1[jj];
    z = (z > 0.f) ? z : 0.01f * z;
    int b = batch[wid];
    if (lane < 16) atomicMax(&sp[b * 16 + jj], f2mono(z));
  }
  __syncthreads();
  for (int i = t; i < N_GRAPHS * 16; i += 256) {
    unsigned v = sp[i];
    if (v != MONO_NEG_INF) atomicMax(p_mono + i, v);
  }
}

// ---- y = p @ W2 + b2 ----
__global__ void final_y(const unsigned* __restrict__ p_mono,
                        const float* __restrict__ W2,
                        const float* __restrict__ b2,
                        float* __restrict__ y) {
  int gr = threadIdx.x;
  if (gr >= N_GRAPHS) return;
  float acc = b2[0];
#pragma unroll
  for (int k = 0; k < 16; ++k) acc += mono2f(p_mono[gr * 16 + k]) * W2[k];
  y[gr] = acc;
}

extern "C" void kernel_launch(void* const* d_in, const int* in_sizes, int n_in,
                              void* d_out, int out_size, void* d_ws, size_t ws_size,
                              hipStream_t stream) {
  const float* x       = (const float*)d_in[0];
  const int*   eidx    = (const int*)d_in[1];
  const int*   etype   = (const int*)d_in[2];
  const int*   batch   = (const int*)d_in[3];
  const float* W_rel   = (const float*)d_in[4];
  const float* W_root  = (const float*)d_in[5];
  const float* b_rgcn  = (const float*)d_in[6];
  const float* W_gat   = (const float*)d_in[7];
  const float* att_src = (const float*)d_in[8];
  const float* att_dst = (const float*)d_in[9];
  const float* b_gat   = (const float*)d_in[10];
  const float* W1      = (const float*)d_in[11];
  const float* b1      = (const float*)d_in[12];
  const float* W2      = (const float*)d_in[13];
  const float* b2      = (const float*)d_in[14];
  float* y = (float*)d_out;

  const int* src = eidx;
  const int* dst = eidx + N_EDGES;

  float* ws = (float*)d_ws;
  // ---- workspace layout (float offsets); compacted (no xhi/xlo) ----
  const size_t OFF_XTBF= 0;           //  8,007,680 f: xt bf16 [N_PAD,320]
  const size_t OFF_GBF = 0;           //  g bf16 [N_PAD,128] (reuses xtbf)
  const size_t OFF_HHI = 8007680;     //  1,601,536 f: h hi bf16 [N_PAD,64]
  const size_t OFF_HLO = 9609216;     //  1,601,536 f: h lo
  const size_t OFF_AS  = 11210752;    //    200,000  a_src
  const size_t OFF_AD  = 11410752;    //    200,000  a_dst
  const size_t OFF_PM  = 11610752;    //      1,024 f = 1024 u32 pool max
  const size_t OFF_DEG = 11611776;    //     50,000  deg (int)
  const size_t OFF_OFFS= 11661776;    //     50,001  off (int)
  const size_t OFF_RANK= 11711780;    //    800,000  rank (int)
  const size_t OFF_EP  = 12511780;    //    800,000  eprep (int)
  const size_t OFF_BS  = 13311780;    //        196
  const size_t OFF_BB  = 13311976;    //        196
  const size_t OFF_WAS = 13312176;    //        256  was (16B aligned)
  const size_t OFF_WAD = 13312432;    //        256  wad
  const size_t OFF_WBH = 13312688;    //     20,480  WbigT_hi (16B aligned)
  const size_t OFF_WBL = 13333168;    //     20,480  WbigT_lo
  const size_t OFF_WGH = 13353648;    //      4,096  WgatT_hi
  const size_t OFF_WGL = 13357744;    //      4,096  WgatT_lo
  const size_t TOTAL_F = 13361840;
  if (ws_size < TOTAL_F * sizeof(float)) return;

  unsigned short* xtbf = (unsigned short*)(ws + OFF_XTBF);
  unsigned short* gbf  = (unsigned short*)(ws + OFF_GBF);
  unsigned short* hhi  = (unsigned short*)(ws + OFF_HHI);
  unsigned short* hlo  = (unsigned short*)(ws + OFF_HLO);
  float* a_s   = ws + OFF_AS;
  float* a_d   = ws + OFF_AD;
  unsigned* pm = (unsigned*)(ws + OFF_PM);
  int* deg     = (int*)(ws + OFF_DEG);
  int* offs    = (int*)(ws + OFF_OFFS);
  int* rank    = (int*)(ws + OFF_RANK);
  int* eprep   = (int*)(ws + OFF_EP);
  int* bsum    = (int*)(ws + OFF_BS);
  int* bbase   = (int*)(ws + OFF_BB);
  float* was   = ws + OFF_WAS;
  float* wad   = ws + OFF_WAD;
  unsigned short* wbt_hi = (unsigned short*)(ws + OFF_WBH);
  unsigned short* wbt_lo = (unsigned short*)(ws + OFF_WBL);
  unsigned short* wgt_hi = (unsigned short*)(ws + OFF_WGH);
  unsigned short* wgt_lo = (unsigned short*)(ws + OFF_WGL);

  // 1. deg = 0 (before fused hist)
  hipMemsetAsync(deg, 0, N_NODES * sizeof(int), stream);

  // 2. fused prep: hist(+rank) | build_wT | init_mono | watt
  pre_fused<<<HIST_BLOCKS + WT_BLOCKS + 2, 256, 0, stream>>>(
      W_root, W_rel, W_gat, att_src, att_dst, dst,
      wbt_hi, wbt_lo, wgt_hi, wgt_lo, deg, rank, pm, was, wad);

  // 3. scan (off from deg)
  k_s1<<<NBLK, 256, 0, stream>>>(deg, bsum);
  k_s2<<<1, 256, 0, stream>>>(bsum, bbase, offs);
  k_s3<<<NBLK, 256, 0, stream>>>(deg, bbase, offs);

  // 4. gemm1 (xt = x @ Wbig, conversion in staging) fused with CSR fill
  gemm1_fill<<<G1_BLOCKS + HIST_BLOCKS, 256, 0, stream>>>(
      x, wbt_hi, wbt_lo, xtbf, src, dst, etype, offs, rank, eprep);

  // 5. RGCN gather -> h (bf16 hi/lo) + fused a_s/a_d
  rgcn_gather<<<N_NODES / 4, 256, 0, stream>>>(xtbf, offs, eprep, b_rgcn,
                                               was, wad, hhi, hlo, a_s, a_d);

  // 6. g = h @ W_gat
  gemm2_k<<<G1_BX * (HOUT / 64), 256, 0, stream>>>(hhi, hlo, wgt_hi, wgt_lo, gbf);

  // 7. fused GAT aggregation + head + per-graph max pool
  gat_fused<<<GAT_BLOCKS, 256, 0, stream>>>(gbf, a_s, a_d, offs, eprep, b_gat,
                                            W1, b1, batch, pm);

  // 8. y = p @ W2 + b2
  final_y<<<1, 64, 0, stream>>>(pm, W2, b2, y);
}

// Round 16
// 208.854 us; speedup vs baseline: 1.2656x; 1.0250x over previous
//
#include <hip/hip_runtime.h>
#include <hip/hip_bf16.h>

constexpr int N_NODES = 50000;
constexpr int N_EDGES = 800000;
constexpr int F_IN = 128;
constexpr int H1 = 64;
constexpr int HEADS = 4;
constexpr int D_H = 32;
constexpr int HOUT = HEADS * D_H;       // 128
constexpr int N_REL = 4;
constexpr int N_GRAPHS = 64;
constexpr int MBIG = H1 * (1 + N_REL);  // 320
constexpr int NBLK = (N_NODES + 255) / 256;  // 196
constexpr int N_PAD = 50048;            // 64 * 782

typedef __attribute__((ext_vector_type(8))) short bf16x8;
typedef __attribute__((ext_vector_type(4))) float f32x4;

// ---- monotonic float<->uint for atomicMax on floats ----
__device__ __forceinline__ unsigned f2mono(float f) {
  unsigned u = __float_as_uint(f);
  return (u & 0x80000000u) ? ~u : (u | 0x80000000u);
}
__device__ __forceinline__ float mono2f(unsigned m) {
  unsigned u = (m & 0x80000000u) ? (m & 0x7FFFFFFFu) : ~m;
  return __uint_as_float(u);
}
constexpr unsigned MONO_NEG_INF = 0x007FFFFFu;

// ---- bf16 helpers ----
__device__ __forceinline__ unsigned short f2bf(float f) {
  unsigned u = __float_as_uint(f);
  unsigned r = (u + 0x7FFFu + ((u >> 16) & 1u)) >> 16;  // RNE
  return (unsigned short)r;
}
__device__ __forceinline__ float bf2f(unsigned short h) {
  return __uint_as_float((unsigned)h << 16);
}
__device__ __forceinline__ float bflo(unsigned u) { return __uint_as_float(u << 16); }
__device__ __forceinline__ float bfhi(unsigned u) { return __uint_as_float(u & 0xFFFF0000u); }

// ======= fused prep: hist | build_wT | init_mono | watt =======
constexpr int HIST_BLOCKS = (N_EDGES + 255) / 256;               // 3125
constexpr int WT_BLOCKS = (MBIG * F_IN + HOUT * H1 + 255) / 256; // 192

__global__ __launch_bounds__(256) void pre_fused(
    const float* __restrict__ W_root, const float* __restrict__ W_rel,
    const float* __restrict__ W_gat,
    const float* __restrict__ att_src, const float* __restrict__ att_dst,
    const int* __restrict__ dst,
    unsigned short* __restrict__ WbT_hi, unsigned short* __restrict__ WbT_lo,
    unsigned short* __restrict__ WgT_hi, unsigned short* __restrict__ WgT_lo,
    int* __restrict__ deg, int* __restrict__ rank,
    unsigned* __restrict__ pm,
    float* __restrict__ was, float* __restrict__ wad) {
  int b = blockIdx.x;
  if (b < HIST_BLOCKS) {
    int e = b * 256 + threadIdx.x;
    if (e < N_EDGES) rank[e] = atomicAdd(&deg[dst[e]], 1);
  } else if (b < HIST_BLOCKS + WT_BLOCKS) {
    int i = (b - HIST_BLOCKS) * 256 + threadIdx.x;
    if (i < MBIG * F_IN) {
      int c = i / F_IN, k = i % F_IN;
      float w = (c < H1) ? W_root[k * H1 + c]
                         : W_rel[((size_t)(((c - H1) >> 6) * F_IN + k)) * H1 + ((c - H1) & 63)];
      unsigned short hi = f2bf(w);
      WbT_hi[i] = hi;
      WbT_lo[i] = f2bf(w - bf2f(hi));
    } else {
      int j = i - MBIG * F_IN;
      if (j < HOUT * H1) {
        int c = j / H1, k = j % H1;
        float w = W_gat[k * HOUT + c];
        unsigned short hi = f2bf(w);
        WgT_hi[j] = hi;
        WgT_lo[j] = f2bf(w - bf2f(hi));
      }
    }
  } else if (b == HIST_BLOCKS + WT_BLOCKS) {
    for (int i = threadIdx.x; i < N_GRAPHS * 16; i += 256) pm[i] = MONO_NEG_INF;
  } else {
    // watt: was/wad[k*4+hh] = sum_d W_gat[k][hh*32+d] * att[hh][d]
    int t = threadIdx.x;          // t = k*4 + hh, 256 threads exactly
    int k = t >> 2, hh = t & 3;
    float s = 0.f, d2 = 0.f;
#pragma unroll 8
    for (int dd = 0; dd < D_H; ++dd) {
      float wg = W_gat[k * HOUT + hh * D_H + dd];
      s += wg * att_src[hh * D_H + dd];
      d2 += wg * att_dst[hh * D_H + dd];
    }
    was[t] = s;
    wad[t] = d2;
  }
}

// ================= LDS-staged split-bf16 MFMA GEMM, K-chunked =========
// Block = 64 rows x 64 cols, 4 waves (2x2), 2x2 frags/wave. A staged in
// 64-wide K-chunks (16 KB LDS -> 8+ blocks/CU). XOR-swizzled (bits 3-5).
// SPLIT=false: A f32, convert during staging. SPLIT=true: pre-split hi/lo.
template <int K, bool SPLIT>
__device__ __forceinline__ void gemm_body(int bx, int by,
    const void* __restrict__ A0,      // SPLIT ? Ahi : f32 A
    const void* __restrict__ A1,      // SPLIT ? Alo : unused
    const unsigned short* __restrict__ BT_hi,
    const unsigned short* __restrict__ BT_lo,
    unsigned short* __restrict__ Cbf, int N, int M) {
  constexpr int KC = 64;               // K-chunk width
  constexpr int NCH = K / KC;
  __shared__ unsigned short Ah[64 * KC];
  __shared__ unsigned short Al[64 * KC];
  const int tid = threadIdx.x;
  const int rowBase = bx * 64;
  const int colBase = by * 64;
  const int wv = tid >> 6, lane = tid & 63;
  const int wr = (wv >> 1) * 32, wc = (wv & 1) * 32;
  const int lrow = lane & 15, lkc = lane >> 4;
  f32x4 acc[2][2] = {};
#pragma unroll
  for (int ch = 0; ch < NCH; ++ch) {
    if (ch) __syncthreads();           // drain reads of previous chunk
    if (SPLIT) {
      const unsigned short* Ahi_ = (const unsigned short*)A0;
      const unsigned short* Alo_ = (const unsigned short*)A1;
      constexpr int KQ8 = KC / 8;      // uint4 slots per row (8)
      for (int s = tid; s < 64 * KQ8; s += 256) {
        int r = s / KQ8, c8 = (s % KQ8) * 8;
        size_t gi = (size_t)(rowBase + r) * K + ch * KC + c8;
        int sw = c8 ^ ((r & 7) << 3);
        *reinterpret_cast<uint4*>(&Ah[r * KC + sw]) =
            *reinterpret_cast<const uint4*>(&Ahi_[gi]);
        *reinterpret_cast<uint4*>(&Al[r * KC + sw]) =
            *reinterpret_cast<const uint4*>(&Alo_[gi]);
      }
    } else {
      const float* Af = (const float*)A0;
      constexpr int KQ4 = KC / 4;      // float4 slots per row (16)
      for (int s = tid; s < 64 * KQ4; s += 256) {
        int r = s / KQ4, c4 = (s % KQ4) * 4;
        int gr = rowBase + r;
        float4 v = make_float4(0.f, 0.f, 0.f, 0.f);
        if (gr < N) v = *reinterpret_cast<const float4*>(&Af[(size_t)gr * K + ch * KC + c4]);
        ushort4 hi, lo;
        hi.x = f2bf(v.x); lo.x = f2bf(v.x - bf2f(hi.x));
        hi.y = f2bf(v.y); lo.y = f2bf(v.y - bf2f(hi.y));
        hi.z = f2bf(v.z); lo.z = f2bf(v.z - bf2f(hi.z));
        hi.w = f2bf(v.w); lo.w = f2bf(v.w - bf2f(hi.w));
        int sw = c4 ^ ((r & 7) << 3);  // XOR bits 3-5; bit2 preserved
        *reinterpret_cast<ushort4*>(&Ah[r * KC + sw]) = hi;
        *reinterpret_cast<ushort4*>(&Al[r * KC + sw]) = lo;
      }
    }
    __syncthreads();
#pragma unroll
    for (int ks = 0; ks < KC; ks += 32) {
      bf16x8 ah[2], al[2], bh[2], bl[2];
#pragma unroll
      for (int fr = 0; fr < 2; ++fr) {
        int r = wr + fr * 16 + lrow;
        int sw = (ks + lkc * 8) ^ ((r & 7) << 3);
        ah[fr] = *reinterpret_cast<const bf16x8*>(&Ah[r * KC + sw]);
        al[fr] = *reinterpret_cast<const bf16x8*>(&Al[r * KC + sw]);
      }
#pragma unroll
      for (int fc = 0; fc < 2; ++fc) {
        int c = colBase + wc + fc * 16 + lrow;
        bh[fc] = *reinterpret_cast<const bf16x8*>(&BT_hi[(size_t)c * K + ch * KC + ks + lkc * 8]);
        bl[fc] = *reinterpret_cast<const bf16x8*>(&BT_lo[(size_t)c * K + ch * KC + ks + lkc * 8]);
      }
#pragma unroll
      for (int fr = 0; fr < 2; ++fr)
#pragma unroll
        for (int fc = 0; fc < 2; ++fc) {
          acc[fr][fc] = __builtin_amdgcn_mfma_f32_16x16x32_bf16(ah[fr], bh[fc], acc[fr][fc], 0, 0, 0);
          acc[fr][fc] = __builtin_amdgcn_mfma_f32_16x16x32_bf16(ah[fr], bl[fc], acc[fr][fc], 0, 0, 0);
          acc[fr][fc] = __builtin_amdgcn_mfma_f32_16x16x32_bf16(al[fr], bh[fc], acc[fr][fc], 0, 0, 0);
        }
    }
  }
#pragma unroll
  for (int fr = 0; fr < 2; ++fr) {
#pragma unroll
    for (int i = 0; i < 4; ++i) {
      int row = rowBase + wr + fr * 16 + lkc * 4 + i;
      if (row < N) {
#pragma unroll
        for (int fc = 0; fc < 2; ++fc) {
          int col = colBase + wc + fc * 16 + lrow;
          Cbf[(size_t)row * M + col] = f2bf(acc[fr][fc][i]);
        }
      }
    }
  }
}

// ---- gemm1 (K=128, xt from f32 x) fused with CSR fill ----
constexpr int G1_BX = N_PAD / 64;          // 782
constexpr int G1_BLOCKS = G1_BX * (MBIG / 64);  // 3910
__global__ __launch_bounds__(256) void gemm1_fill(
    const float* __restrict__ x,
    const unsigned short* __restrict__ wbt_hi, const unsigned short* __restrict__ wbt_lo,
    unsigned short* __restrict__ xtbf,
    const int* __restrict__ src, const int* __restrict__ dst,
    const int* __restrict__ etype, const int* __restrict__ off,
    const int* __restrict__ rank, int* __restrict__ eprep) {
  if (blockIdx.x < G1_BLOCKS) {
    gemm_body<128, false>(blockIdx.x % G1_BX, blockIdx.x / G1_BX,
                          x, nullptr, wbt_hi, wbt_lo, xtbf, N_NODES, MBIG);
  } else {
    int e = (blockIdx.x - G1_BLOCKS) * 256 + threadIdx.x;
    if (e < N_EDGES) {
      int pos = off[dst[e]] + rank[e];
      eprep[pos] = src[e] | (etype[e] << 16);
    }
  }
}

// ---- gemm2 (K=64, g from pre-split h) ----
__global__ __launch_bounds__(256) void gemm2_k(
    const unsigned short* __restrict__ hhi, const unsigned short* __restrict__ hlo,
    const unsigned short* __restrict__ wgt_hi, const unsigned short* __restrict__ wgt_lo,
    unsigned short* __restrict__ gbf) {
  gemm_body<64, true>(blockIdx.x % G1_BX, blockIdx.x / G1_BX,
                      hhi, hlo, wgt_hi, wgt_lo, gbf, N_NODES, HOUT);
}

// ---- scan stage 1: per-block sums ----
__global__ __launch_bounds__(256) void k_s1(const int* __restrict__ deg,
                                            int* __restrict__ bsum) {
  __shared__ int ss[256];
  int t = threadIdx.x;
  int i = blockIdx.x * 256 + t;
  ss[t] = (i < N_NODES) ? deg[i] : 0;
  __syncthreads();
  for (int d = 128; d > 0; d >>= 1) {
    if (t < d) ss[t] += ss[t + d];
    __syncthreads();
  }
  if (t == 0) bsum[blockIdx.x] = ss[0];
}

// ---- scan stage 2: exclusive scan of block sums ----
__global__ __launch_bounds__(256) void k_s2(const int* __restrict__ bsum,
                                            int* __restrict__ bbase,
                                            int* __restrict__ off) {
  __shared__ int ss[256];
  int t = threadIdx.x;
  int v = (t < NBLK) ? bsum[t] : 0;
  ss[t] = v;
  __syncthreads();
  for (int d = 1; d < 256; d <<= 1) {
    int u = (t >= d) ? ss[t - d] : 0;
    __syncthreads();
    ss[t] += u;
    __syncthreads();
  }
  if (t < NBLK) bbase[t] = ss[t] - v;
  if (t == NBLK - 1) off[N_NODES] = ss[t];
}

// ---- scan stage 3: block-local scan + base ----
__global__ __launch_bounds__(256) void k_s3(const int* __restrict__ deg,
                                            const int* __restrict__ bbase,
                                            int* __restrict__ off) {
  __shared__ int ss[256];
  int t = threadIdx.x;
  int i = blockIdx.x * 256 + t;
  int v = (i < N_NODES) ? deg[i] : 0;
  ss[t] = v;
  __syncthreads();
  for (int d = 1; d < 256; d <<= 1) {
    int u = (t >= d) ? ss[t - d] : 0;
    __syncthreads();
    ss[t] += u;
    __syncthreads();
  }
  if (i < N_NODES) off[i] = bbase[blockIdx.x] + ss[t] - v;
}

// ---- RGCN: gather from bf16 xt; wave/node; emits h (bf16 hi/lo) AND
//      attention coefficients a_s/a_d = h @ (W_gat @ att) ----
__global__ __launch_bounds__(256) void rgcn_gather(const unsigned short* __restrict__ xtbf,
                                                   const int* __restrict__ off,
                                                   const int* __restrict__ eprep,
                                                   const float* __restrict__ b_rgcn,
                                                   const float* __restrict__ was,
                                                   const float* __restrict__ wad,
                                                   unsigned short* __restrict__ hhi,
                                                   unsigned short* __restrict__ hlo,
                                                   float* __restrict__ a_s,
                                                   float* __restrict__ a_d) {
  int wid = (blockIdx.x * 256 + threadIdx.x) >> 6;
  int lane = threadIdx.x & 63;
  int half = lane >> 5;
  int cp = lane & 31;
  int start = off[wid], end = off[wid + 1];
  float a0x=0.f,a0y=0.f,a1x=0.f,a1y=0.f,a2x=0.f,a2y=0.f,a3x=0.f,a3y=0.f;
  int c0=0,c1=0,c2=0,c3=0;
  int niter = (end - start + 1) >> 1;
  for (int t = 0; t < niter; t += 2) {
    int idx0 = start + 2 * t + half;
    int idx1 = idx0 + 2;
    int p0 = (idx0 < end) ? eprep[idx0] : 0x70000;
    int p1 = (idx1 < end) ? eprep[idx1] : 0x70000;
    int s0 = p0 & 0xFFFF, r0 = p0 >> 16;
    int s1 = p1 & 0xFFFF, r1 = p1 >> 16;
    unsigned u0 = *reinterpret_cast<const unsigned*>(
        &xtbf[(size_t)s0 * MBIG + H1 + (r0 << 6) + cp * 2]);
    unsigned u1 = *reinterpret_cast<const unsigned*>(
        &xtbf[(size_t)s1 * MBIG + H1 + (r1 << 6) + cp * 2]);
    float v0x = bflo(u0), v0y = bfhi(u0);
    float v1x = bflo(u1), v1y = bfhi(u1);
    a0x += (r0==0)?v0x:0.f; a0y += (r0==0)?v0y:0.f; c0 += (r0==0);
    a1x += (r0==1)?v0x:0.f; a1y += (r0==1)?v0y:0.f; c1 += (r0==1);
    a2x += (r0==2)?v0x:0.f; a2y += (r0==2)?v0y:0.f; c2 += (r0==2);
    a3x += (r0==3)?v0x:0.f; a3y += (r0==3)?v0y:0.f; c3 += (r0==3);
    a0x += (r1==0)?v1x:0.f; a0y += (r1==0)?v1y:0.f; c0 += (r1==0);
    a1x += (r1==1)?v1x:0.f; a1y += (r1==1)?v1y:0.f; c1 += (r1==1);
    a2x += (r1==2)?v1x:0.f; a2y += (r1==2)?v1y:0.f; c2 += (r1==2);
    a3x += (r1==3)?v1x:0.f; a3y += (r1==3)?v1y:0.f; c3 += (r1==3);
  }
  a0x += __shfl_xor(a0x, 32); a0y += __shfl_xor(a0y, 32);
  a1x += __shfl_xor(a1x, 32); a1y += __shfl_xor(a1y, 32);
  a2x += __shfl_xor(a2x, 32); a2y += __shfl_xor(a2y, 32);
  a3x += __shfl_xor(a3x, 32); a3y += __shfl_xor(a3y, 32);
  c0 += __shfl_xor(c0, 32); c1 += __shfl_xor(c1, 32);
  c2 += __shfl_xor(c2, 32); c3 += __shfl_xor(c3, 32);
  if (half == 0) {
    unsigned ur = *reinterpret_cast<const unsigned*>(&xtbf[(size_t)wid * MBIG + cp * 2]);
    float2 bb = *reinterpret_cast<const float2*>(&b_rgcn[cp * 2]);
    float i0 = 1.0f / (float)max(c0, 1);
    float i1 = 1.0f / (float)max(c1, 1);
    float i2 = 1.0f / (float)max(c2, 1);
    float i3 = 1.0f / (float)max(c3, 1);
    float vx = bflo(ur) + bb.x + a0x * i0 + a1x * i1 + a2x * i2 + a3x * i3;
    float vy = bfhi(ur) + bb.y + a0y * i0 + a1y * i1 + a2y * i2 + a3y * i3;
    vx = fmaxf(vx, 0.f);
    vy = fmaxf(vy, 0.f);
    unsigned short hx = f2bf(vx), hy = f2bf(vy);
    ushort2 hv = {hx, hy};
    ushort2 lv = {f2bf(vx - bf2f(hx)), f2bf(vy - bf2f(hy))};
    *reinterpret_cast<ushort2*>(&hhi[(size_t)wid * H1 + cp * 2]) = hv;
    *reinterpret_cast<ushort2*>(&hlo[(size_t)wid * H1 + cp * 2]) = lv;
    // ---- fused attention coefficients: a = h @ was / h @ wad ----
    float4 wsA = *reinterpret_cast<const float4*>(&was[cp * 8]);      // k=2cp
    float4 wsB = *reinterpret_cast<const float4*>(&was[cp * 8 + 4]);  // k=2cp+1
    float4 wdA = *reinterpret_cast<const float4*>(&wad[cp * 8]);
    float4 wdB = *reinterpret_cast<const float4*>(&wad[cp * 8 + 4]);
    float ps0 = vx * wsA.x + vy * wsB.x;
    float ps1 = vx * wsA.y + vy * wsB.y;
    float ps2 = vx * wsA.z + vy * wsB.z;
    float ps3 = vx * wsA.w + vy * wsB.w;
    float pd0 = vx * wdA.x + vy * wdB.x;
    float pd1 = vx * wdA.y + vy * wdB.y;
    float pd2 = vx * wdA.z + vy * wdB.z;
    float pd3 = vx * wdA.w + vy * wdB.w;
#pragma unroll
    for (int d = 1; d < 32; d <<= 1) {
      ps0 += __shfl_xor(ps0, d); ps1 += __shfl_xor(ps1, d);
      ps2 += __shfl_xor(ps2, d); ps3 += __shfl_xor(ps3, d);
      pd0 += __shfl_xor(pd0, d); pd1 += __shfl_xor(pd1, d);
      pd2 += __shfl_xor(pd2, d); pd3 += __shfl_xor(pd3, d);
    }
    if (cp == 0) {
      *reinterpret_cast<float4*>(&a_s[(size_t)wid * 4]) = make_float4(ps0, ps1, ps2, ps3);
      *reinterpret_cast<float4*>(&a_d[(size_t)wid * 4]) = make_float4(pd0, pd1, pd2, pd3);
    }
  }
}

// ---- GAT + head fused ----
constexpr int GAT_BLOCKS = 2048;
constexpr int GAT_WAVES = GAT_BLOCKS * 4;   // 8192
__global__ __launch_bounds__(256) void gat_fused(const unsigned short* __restrict__ gbf,
                                                 const float* __restrict__ a_s,
                                                 const float* __restrict__ a_d,
                                                 const int* __restrict__ off,
                                                 const int* __restrict__ eprep,
                                                 const float* __restrict__ b_gat,
                                                 const float* __restrict__ W1,
                                                 const float* __restrict__ b1,
                                                 const int* __restrict__ batch,
                                                 unsigned* __restrict__ p_mono) {
  __shared__ float w1s[HOUT * 16];        // W1[k][j]
  __shared__ float ob[4][HOUT];           // per-wave o row
  __shared__ unsigned sp[N_GRAPHS * 16];
  const int t = threadIdx.x;
  for (int i = t; i < HOUT * 16; i += 256) w1s[i] = W1[i];
  for (int i = t; i < N_GRAPHS * 16; i += 256) sp[i] = MONO_NEG_INF;
  __syncthreads();
  const int wv = t >> 6, lane = t & 63;
  const int hh = lane >> 4;
  const int jj = lane & 15, grp = lane >> 4;
  const int w = blockIdx.x * 4 + wv;
  const int q = N_NODES / GAT_WAVES;
  const int r = N_NODES % GAT_WAVES;
  const int nbeg = w * q + ((w < r) ? w : r);
  const int ncnt = q + ((w < r) ? 1 : 0);
  for (int wid = nbeg; wid < nbeg + ncnt; ++wid) {
    int start = off[wid], end = off[wid + 1];
    float4 ad4 = *reinterpret_cast<const float4*>(a_d + (size_t)wid * 4);
    float adh = (hh == 0) ? ad4.x : (hh == 1) ? ad4.y : (hh == 2) ? ad4.z : ad4.w;
    float ox = 0.f, oy = 0.f, den = 0.f;
    int i = start;
    for (; i + 4 <= end; i += 4) {
      int p0 = eprep[i], p1 = eprep[i + 1], p2 = eprep[i + 2], p3 = eprep[i + 3];
      int s0 = p0 & 0xFFFF, s1 = p1 & 0xFFFF, s2 = p2 & 0xFFFF, s3 = p3 & 0xFFFF;
      float as0 = a_s[(size_t)s0 * 4 + hh];
      float as1 = a_s[(size_t)s1 * 4 + hh];
      float as2 = a_s[(size_t)s2 * 4 + hh];
      float as3 = a_s[(size_t)s3 * 4 + hh];
      unsigned u0 = *reinterpret_cast<const unsigned*>(&gbf[(size_t)s0 * HOUT + lane * 2]);
      unsigned u1 = *reinterpret_cast<const unsigned*>(&gbf[(size_t)s1 * HOUT + lane * 2]);
      unsigned u2 = *reinterpret_cast<const unsigned*>(&gbf[(size_t)s2 * HOUT + lane * 2]);
      unsigned u3 = *reinterpret_cast<const unsigned*>(&gbf[(size_t)s3 * HOUT + lane * 2]);
      float e0 = as0 + adh; e0 = (e0 > 0.f) ? e0 : 0.2f * e0;
      float e1 = as1 + adh; e1 = (e1 > 0.f) ? e1 : 0.2f * e1;
      float e2 = as2 + adh; e2 = (e2 > 0.f) ? e2 : 0.2f * e2;
      float e3 = as3 + adh; e3 = (e3 > 0.f) ? e3 : 0.2f * e3;
      float x0 = __expf(e0), x1 = __expf(e1), x2 = __expf(e2), x3 = __expf(e3);
      den += x0 + x1 + x2 + x3;
      ox += x0 * bflo(u0) + x1 * bflo(u1) + x2 * bflo(u2) + x3 * bflo(u3);
      oy += x0 * bfhi(u0) + x1 * bfhi(u1) + x2 * bfhi(u2) + x3 * bfhi(u3);
    }
    for (; i < end; ++i) {
      int p = eprep[i];
      int s = p & 0xFFFF;
      float as = a_s[(size_t)s * 4 + hh];
      unsigned u = *reinterpret_cast<const unsigned*>(&gbf[(size_t)s * HOUT + lane * 2]);
      float e = as + adh; e = (e > 0.f) ? e : 0.2f * e;
      float ex = __expf(e);
      den += ex;
      ox += ex * bflo(u);
      oy += ex * bfhi(u);
    }
    float dinv = (den > 0.f) ? (1.0f / den) : 0.f;
    float2 bg = *reinterpret_cast<const float2*>(b_gat + lane * 2);
    float vx = ox * dinv + bg.x; vx = (vx > 0.f) ? vx : 0.01f * vx;
    float vy = oy * dinv + bg.y; vy = (vy > 0.f) ? vy : 0.01f * vy;
    *reinterpret_cast<float2*>(&ob[wv][lane * 2]) = make_float2(vx, vy);
    float acc = 0.f;
#pragma unroll 8
    for (int i2 = 0; i2 < 32; ++i2) {
      int c = grp + 4 * i2;
      acc += ob[wv][c] * w1s[c * 16 + jj];
    }
    acc += __shfl_xor(acc, 16);
    acc += __shfl_xor(acc, 32);
    float z = acc + b1[jj];
    z = (z > 0.f) ? z : 0.01f * z;
    int b = batch[wid];
    if (lane < 16) atomicMax(&sp[b * 16 + jj], f2mono(z));
  }
  __syncthreads();
  for (int i = t; i < N_GRAPHS * 16; i += 256) {
    unsigned v = sp[i];
    if (v != MONO_NEG_INF) atomicMax(p_mono + i, v);
  }
}

// ---- y = p @ W2 + b2 ----
__global__ void final_y(const unsigned* __restrict__ p_mono,
                        const float* __restrict__ W2,
                        const float* __restrict__ b2,
                        float* __restrict__ y) {
  int gr = threadIdx.x;
  if (gr >= N_GRAPHS) return;
  float acc = b2[0];
#pragma unroll
  for (int k = 0; k < 16; ++k) acc += mono2f(p_mono[gr * 16 + k]) * W2[k];
  y[gr] = acc;
}

extern "C" void kernel_launch(void* const* d_in, const int* in_sizes, int n_in,
                              void* d_out, int out_size, void* d_ws, size_t ws_size,
                              hipStream_t stream) {
  const float* x       = (const float*)d_in[0];
  const int*   eidx    = (const int*)d_in[1];
  const int*   etype   = (const int*)d_in[2];
  const int*   batch   = (const int*)d_in[3];
  const float* W_rel   = (const float*)d_in[4];
  const float* W_root  = (const float*)d_in[5];
  const float* b_rgcn  = (const float*)d_in[6];
  const float* W_gat   = (const float*)d_in[7];
  const float* att_src = (const float*)d_in[8];
  const float* att_dst = (const float*)d_in[9];
  const float* b_gat   = (const float*)d_in[10];
  const float* W1      = (const float*)d_in[11];
  const float* b1      = (const float*)d_in[12];
  const float* W2      = (const float*)d_in[13];
  const float* b2      = (const float*)d_in[14];
  float* y = (float*)d_out;

  const int* src = eidx;
  const int* dst = eidx + N_EDGES;

  float* ws = (float*)d_ws;
  // ---- workspace layout (float offsets) ----
  const size_t OFF_XTBF= 0;           //  8,007,680 f: xt bf16 [N_PAD,320]
  const size_t OFF_GBF = 0;           //  g bf16 [N_PAD,128] (reuses xtbf)
  const size_t OFF_HHI = 8007680;     //  1,601,536 f: h hi bf16 [N_PAD,64]
  const size_t OFF_HLO = 9609216;     //  1,601,536 f: h lo
  const size_t OFF_AS  = 11210752;    //    200,000  a_src
  const size_t OFF_AD  = 11410752;    //    200,000  a_dst
  const size_t OFF_PM  = 11610752;    //      1,024 f = 1024 u32 pool max
  const size_t OFF_DEG = 11611776;    //     50,000  deg (int)
  const size_t OFF_OFFS= 11661776;    //     50,001  off (int)
  const size_t OFF_RANK= 11711780;    //    800,000  rank (int)
  const size_t OFF_EP  = 12511780;    //    800,000  eprep (int)
  const size_t OFF_BS  = 13311780;    //        196
  const size_t OFF_BB  = 13311976;    //        196
  const size_t OFF_WAS = 13312176;    //        256  was (16B aligned)
  const size_t OFF_WAD = 13312432;    //        256  wad
  const size_t OFF_WBH = 13312688;    //     20,480  WbigT_hi (16B aligned)
  const size_t OFF_WBL = 13333168;    //     20,480  WbigT_lo
  const size_t OFF_WGH = 13353648;    //      4,096  WgatT_hi
  const size_t OFF_WGL = 13357744;    //      4,096  WgatT_lo
  const size_t TOTAL_F = 13361840;
  if (ws_size < TOTAL_F * sizeof(float)) return;

  unsigned short* xtbf = (unsigned short*)(ws + OFF_XTBF);
  unsigned short* gbf  = (unsigned short*)(ws + OFF_GBF);
  unsigned short* hhi  = (unsigned short*)(ws + OFF_HHI);
  unsigned short* hlo  = (unsigned short*)(ws + OFF_HLO);
  float* a_s   = ws + OFF_AS;
  float* a_d   = ws + OFF_AD;
  unsigned* pm = (unsigned*)(ws + OFF_PM);
  int* deg     = (int*)(ws + OFF_DEG);
  int* offs    = (int*)(ws + OFF_OFFS);
  int* rank    = (int*)(ws + OFF_RANK);
  int* eprep   = (int*)(ws + OFF_EP);
  int* bsum    = (int*)(ws + OFF_BS);
  int* bbase   = (int*)(ws + OFF_BB);
  float* was   = ws + OFF_WAS;
  float* wad   = ws + OFF_WAD;
  unsigned short* wbt_hi = (unsigned short*)(ws + OFF_WBH);
  unsigned short* wbt_lo = (unsigned short*)(ws + OFF_WBL);
  unsigned short* wgt_hi = (unsigned short*)(ws + OFF_WGH);
  unsigned short* wgt_lo = (unsigned short*)(ws + OFF_WGL);

  // 1. deg = 0 (before fused hist)
  hipMemsetAsync(deg, 0, N_NODES * sizeof(int), stream);

  // 2. fused prep: hist(+rank) | build_wT | init_mono | watt
  pre_fused<<<HIST_BLOCKS + WT_BLOCKS + 2, 256, 0, stream>>>(
      W_root, W_rel, W_gat, att_src, att_dst, dst,
      wbt_hi, wbt_lo, wgt_hi, wgt_lo, deg, rank, pm, was, wad);

  // 3. scan (off from deg)
  k_s1<<<NBLK, 256, 0, stream>>>(deg, bsum);
  k_s2<<<1, 256, 0, stream>>>(bsum, bbase, offs);
  k_s3<<<NBLK, 256, 0, stream>>>(deg, bbase, offs);

  // 4. gemm1 (xt = x @ Wbig, K-chunked staging) fused with CSR fill
  gemm1_fill<<<G1_BLOCKS + HIST_BLOCKS, 256, 0, stream>>>(
      x, wbt_hi, wbt_lo, xtbf, src, dst, etype, offs, rank, eprep);

  // 5. RGCN gather -> h (bf16 hi/lo) + fused a_s/a_d
  rgcn_gather<<<N_NODES / 4, 256, 0, stream>>>(xtbf, offs, eprep, b_rgcn,
                                               was, wad, hhi, hlo, a_s, a_d);

  // 6. g = h @ W_gat
  gemm2_k<<<G1_BX * (HOUT / 64), 256, 0, stream>>>(hhi, hlo, wgt_hi, wgt_lo, gbf);

  // 7. fused GAT aggregation + head + per-graph max pool
  gat_fused<<<GAT_BLOCKS, 256, 0, stream>>>(gbf, a_s, a_d, offs, eprep, b_gat,
                                            W1, b1, batch, pm);

  // 8. y = p @ W2 + b2
  final_y<<<1, 64, 0, stream>>>(pm, W2, b2, y);
}

// Round 17
// 208.278 us; speedup vs baseline: 1.2691x; 1.0028x over previous
//
#include <hip/hip_runtime.h>
#include <hip/hip_bf16.h>

constexpr int N_NODES = 50000;
constexpr int N_EDGES = 800000;
constexpr int F_IN = 128;
constexpr int H1 = 64;
constexpr int HEADS = 4;
constexpr int D_H = 32;
constexpr int HOUT = HEADS * D_H;       // 128
constexpr int N_REL = 4;
constexpr int N_GRAPHS = 64;
constexpr int MBIG = H1 * (1 + N_REL);  // 320
constexpr int NBLK = (N_NODES + 255) / 256;  // 196
constexpr int N_PAD = 50048;            // 64 * 782

typedef __attribute__((ext_vector_type(8))) short bf16x8;
typedef __attribute__((ext_vector_type(4))) float f32x4;

// ---- monotonic float<->uint for atomicMax on floats ----
__device__ __forceinline__ unsigned f2mono(float f) {
  unsigned u = __float_as_uint(f);
  return (u & 0x80000000u) ? ~u : (u | 0x80000000u);
}
__device__ __forceinline__ float mono2f(unsigned m) {
  unsigned u = (m & 0x80000000u) ? (m & 0x7FFFFFFFu) : ~m;
  return __uint_as_float(u);
}
constexpr unsigned MONO_NEG_INF = 0x007FFFFFu;

// ---- bf16 helpers ----
__device__ __forceinline__ unsigned short f2bf(float f) {
  unsigned u = __float_as_uint(f);
  unsigned r = (u + 0x7FFFu + ((u >> 16) & 1u)) >> 16;  // RNE
  return (unsigned short)r;
}
__device__ __forceinline__ float bf2f(unsigned short h) {
  return __uint_as_float((unsigned)h << 16);
}
__device__ __forceinline__ float bflo(unsigned u) { return __uint_as_float(u << 16); }
__device__ __forceinline__ float bfhi(unsigned u) { return __uint_as_float(u & 0xFFFF0000u); }

// ======= fused prep: hist | build_wT | init_mono | watt =======
constexpr int HIST_BLOCKS = (N_EDGES + 255) / 256;               // 3125
constexpr int WT_BLOCKS = (MBIG * F_IN + HOUT * H1 + 255) / 256; // 192

__global__ __launch_bounds__(256) void pre_fused(
    const float* __restrict__ W_root, const float* __restrict__ W_rel,
    const float* __restrict__ W_gat,
    const float* __restrict__ att_src, const float* __restrict__ att_dst,
    const int* __restrict__ dst,
    unsigned short* __restrict__ WbT_hi, unsigned short* __restrict__ WbT_lo,
    unsigned short* __restrict__ WgT_hi, unsigned short* __restrict__ WgT_lo,
    int* __restrict__ deg, int* __restrict__ rank,
    unsigned* __restrict__ pm,
    float* __restrict__ was, float* __restrict__ wad) {
  int b = blockIdx.x;
  if (b < HIST_BLOCKS) {
    int e = b * 256 + threadIdx.x;
    if (e < N_EDGES) rank[e] = atomicAdd(&deg[dst[e]], 1);
  } else if (b < HIST_BLOCKS + WT_BLOCKS) {
    int i = (b - HIST_BLOCKS) * 256 + threadIdx.x;
    if (i < MBIG * F_IN) {
      int c = i / F_IN, k = i % F_IN;
      float w = (c < H1) ? W_root[k * H1 + c]
                         : W_rel[((size_t)(((c - H1) >> 6) * F_IN + k)) * H1 + ((c - H1) & 63)];
      unsigned short hi = f2bf(w);
      WbT_hi[i] = hi;
      WbT_lo[i] = f2bf(w - bf2f(hi));
    } else {
      int j = i - MBIG * F_IN;
      if (j < HOUT * H1) {
        int c = j / H1, k = j % H1;
        float w = W_gat[k * HOUT + c];
        unsigned short hi = f2bf(w);
        WgT_hi[j] = hi;
        WgT_lo[j] = f2bf(w - bf2f(hi));
      }
    }
  } else if (b == HIST_BLOCKS + WT_BLOCKS) {
    for (int i = threadIdx.x; i < N_GRAPHS * 16; i += 256) pm[i] = MONO_NEG_INF;
  } else {
    // watt: was/wad[k*4+hh] = sum_d W_gat[k][hh*32+d] * att[hh][d]
    int t = threadIdx.x;          // t = k*4 + hh, 256 threads exactly
    int k = t >> 2, hh = t & 3;
    float s = 0.f, d2 = 0.f;
#pragma unroll 8
    for (int dd = 0; dd < D_H; ++dd) {
      float wg = W_gat[k * HOUT + hh * D_H + dd];
      s += wg * att_src[hh * D_H + dd];
      d2 += wg * att_dst[hh * D_H + dd];
    }
    was[t] = s;
    wad[t] = d2;
  }
}

// ============ gemm1 body: K=128, f32 A, async double-buffered chunks ======
// Block = 64x64 tile, 4 waves 2x2, 2x2 frags/wave. A staged in 64-wide
// K-chunks (16 KB LDS); chunk-1 loads issued BEFORE chunk-0 MFMA (latency
// hides under compute). XOR-swizzled LDS (bits 3-5).
__device__ __forceinline__ void gemm_body128(int bx, int by,
    const float* __restrict__ Af,
    const unsigned short* __restrict__ BT_hi,
    const unsigned short* __restrict__ BT_lo,
    unsigned short* __restrict__ Cbf, int N, int M) {
  constexpr int K = 128, KC = 64;
  __shared__ unsigned short Ah[64 * KC];
  __shared__ unsigned short Al[64 * KC];
  const int tid = threadIdx.x;
  const int rowBase = bx * 64;
  const int colBase = by * 64;
  const int wv = tid >> 6, lane = tid & 63;
  const int wr = (wv >> 1) * 32, wc = (wv & 1) * 32;
  const int lrow = lane & 15, lkc = lane >> 4;
  // staging slots: 4 float4 per thread per chunk (64 rows x 16 slots)
  int r_[4], c4_[4];
#pragma unroll
  for (int it = 0; it < 4; ++it) {
    int s = it * 256 + tid;
    r_[it] = s >> 4;
    c4_[it] = (s & 15) * 4;
  }
  f32x4 acc[2][2] = {};
  // ---- load + stage chunk 0 ----
#pragma unroll
  for (int it = 0; it < 4; ++it) {
    int gr = rowBase + r_[it];
    float4 v = make_float4(0.f, 0.f, 0.f, 0.f);
    if (gr < N) v = *reinterpret_cast<const float4*>(&Af[(size_t)gr * K + c4_[it]]);
    ushort4 hi, lo;
    hi.x = f2bf(v.x); lo.x = f2bf(v.x - bf2f(hi.x));
    hi.y = f2bf(v.y); lo.y = f2bf(v.y - bf2f(hi.y));
    hi.z = f2bf(v.z); lo.z = f2bf(v.z - bf2f(hi.z));
    hi.w = f2bf(v.w); lo.w = f2bf(v.w - bf2f(hi.w));
    int sw = c4_[it] ^ ((r_[it] & 7) << 3);
    *reinterpret_cast<ushort4*>(&Ah[r_[it] * KC + sw]) = hi;
    *reinterpret_cast<ushort4*>(&Al[r_[it] * KC + sw]) = lo;
  }
  __syncthreads();
  // ---- issue chunk-1 loads (in flight across chunk-0 MFMA) ----
  float4 v1[4];
#pragma unroll
  for (int it = 0; it < 4; ++it) {
    int gr = rowBase + r_[it];
    v1[it] = make_float4(0.f, 0.f, 0.f, 0.f);
    if (gr < N) v1[it] = *reinterpret_cast<const float4*>(&Af[(size_t)gr * K + KC + c4_[it]]);
  }
  // ---- MFMA over chunks ----
#pragma unroll
  for (int ch = 0; ch < 2; ++ch) {
    if (ch == 1) {
      __syncthreads();                 // drain chunk-0 reads
#pragma unroll
      for (int it = 0; it < 4; ++it) {
        float4 v = v1[it];
        ushort4 hi, lo;
        hi.x = f2bf(v.x); lo.x = f2bf(v.x - bf2f(hi.x));
        hi.y = f2bf(v.y); lo.y = f2bf(v.y - bf2f(hi.y));
        hi.z = f2bf(v.z); lo.z = f2bf(v.z - bf2f(hi.z));
        hi.w = f2bf(v.w); lo.w = f2bf(v.w - bf2f(hi.w));
        int sw = c4_[it] ^ ((r_[it] & 7) << 3);
        *reinterpret_cast<ushort4*>(&Ah[r_[it] * KC + sw]) = hi;
        *reinterpret_cast<ushort4*>(&Al[r_[it] * KC + sw]) = lo;
      }
      __syncthreads();
    }
#pragma unroll
    for (int ks = 0; ks < KC; ks += 32) {
      bf16x8 ah[2], al[2], bh[2], bl[2];
#pragma unroll
      for (int fr = 0; fr < 2; ++fr) {
        int r = wr + fr * 16 + lrow;
        int sw = (ks + lkc * 8) ^ ((r & 7) << 3);
        ah[fr] = *reinterpret_cast<const bf16x8*>(&Ah[r * KC + sw]);
        al[fr] = *reinterpret_cast<const bf16x8*>(&Al[r * KC + sw]);
      }
#pragma unroll
      for (int fc = 0; fc < 2; ++fc) {
        int c = colBase + wc + fc * 16 + lrow;
        bh[fc] = *reinterpret_cast<const bf16x8*>(&BT_hi[(size_t)c * K + ch * KC + ks + lkc * 8]);
        bl[fc] = *reinterpret_cast<const bf16x8*>(&BT_lo[(size_t)c * K + ch * KC + ks + lkc * 8]);
      }
#pragma unroll
      for (int fr = 0; fr < 2; ++fr)
#pragma unroll
        for (int fc = 0; fc < 2; ++fc) {
          acc[fr][fc] = __builtin_amdgcn_mfma_f32_16x16x32_bf16(ah[fr], bh[fc], acc[fr][fc], 0, 0, 0);
          acc[fr][fc] = __builtin_amdgcn_mfma_f32_16x16x32_bf16(ah[fr], bl[fc], acc[fr][fc], 0, 0, 0);
          acc[fr][fc] = __builtin_amdgcn_mfma_f32_16x16x32_bf16(al[fr], bh[fc], acc[fr][fc], 0, 0, 0);
        }
    }
  }
#pragma unroll
  for (int fr = 0; fr < 2; ++fr) {
#pragma unroll
    for (int i = 0; i < 4; ++i) {
      int row = rowBase + wr + fr * 16 + lkc * 4 + i;
      if (row < N) {
#pragma unroll
        for (int fc = 0; fc < 2; ++fc) {
          int col = colBase + wc + fc * 16 + lrow;
          Cbf[(size_t)row * M + col] = f2bf(acc[fr][fc][i]);
        }
      }
    }
  }
}

// ============ gemm2 body: K=64, pre-split hi/lo A, single chunk ==========
__device__ __forceinline__ void gemm_body64(int bx, int by,
    const unsigned short* __restrict__ Ahi_,
    const unsigned short* __restrict__ Alo_,
    const unsigned short* __restrict__ BT_hi,
    const unsigned short* __restrict__ BT_lo,
    unsigned short* __restrict__ Cbf, int N, int M) {
  constexpr int K = 64;
  __shared__ unsigned short Ah[64 * K];
  __shared__ unsigned short Al[64 * K];
  const int tid = threadIdx.x;
  const int rowBase = bx * 64;
  const int colBase = by * 64;
  constexpr int KQ8 = K / 8;
  for (int s = tid; s < 64 * KQ8; s += 256) {
    int r = s / KQ8, c8 = (s % KQ8) * 8;
    size_t gi = (size_t)(rowBase + r) * K + c8;
    int sw = c8 ^ ((r & 7) << 3);
    *reinterpret_cast<uint4*>(&Ah[r * K + sw]) =
        *reinterpret_cast<const uint4*>(&Ahi_[gi]);
    *reinterpret_cast<uint4*>(&Al[r * K + sw]) =
        *reinterpret_cast<const uint4*>(&Alo_[gi]);
  }
  __syncthreads();
  const int wv = tid >> 6, lane = tid & 63;
  const int wr = (wv >> 1) * 32, wc = (wv & 1) * 32;
  const int lrow = lane & 15, lkc = lane >> 4;
  f32x4 acc[2][2] = {};
#pragma unroll
  for (int ks = 0; ks < K; ks += 32) {
    bf16x8 ah[2], al[2], bh[2], bl[2];
#pragma unroll
    for (int fr = 0; fr < 2; ++fr) {
      int r = wr + fr * 16 + lrow;
      int sw = (ks + lkc * 8) ^ ((r & 7) << 3);
      ah[fr] = *reinterpret_cast<const bf16x8*>(&Ah[r * K + sw]);
      al[fr] = *reinterpret_cast<const bf16x8*>(&Al[r * K + sw]);
    }
#pragma unroll
    for (int fc = 0; fc < 2; ++fc) {
      int c = colBase + wc + fc * 16 + lrow;
      bh[fc] = *reinterpret_cast<const bf16x8*>(&BT_hi[(size_t)c * K + ks + lkc * 8]);
      bl[fc] = *reinterpret_cast<const bf16x8*>(&BT_lo[(size_t)c * K + ks + lkc * 8]);
    }
#pragma unroll
    for (int fr = 0; fr < 2; ++fr)
#pragma unroll
      for (int fc = 0; fc < 2; ++fc) {
        acc[fr][fc] = __builtin_amdgcn_mfma_f32_16x16x32_bf16(ah[fr], bh[fc], acc[fr][fc], 0, 0, 0);
        acc[fr][fc] = __builtin_amdgcn_mfma_f32_16x16x32_bf16(ah[fr], bl[fc], acc[fr][fc], 0, 0, 0);
        acc[fr][fc] = __builtin_amdgcn_mfma_f32_16x16x32_bf16(al[fr], bh[fc], acc[fr][fc], 0, 0, 0);
      }
  }
#pragma unroll
  for (int fr = 0; fr < 2; ++fr) {
#pragma unroll
    for (int i = 0; i < 4; ++i) {
      int row = rowBase + wr + fr * 16 + lkc * 4 + i;
      if (row < N) {
#pragma unroll
        for (int fc = 0; fc < 2; ++fc) {
          int col = colBase + wc + fc * 16 + lrow;
          Cbf[(size_t)row * M + col] = f2bf(acc[fr][fc][i]);
        }
      }
    }
  }
}

// ---- gemm1 (xt from f32 x) fused with CSR fill; XCD-group swizzle ----
constexpr int G1_BX = N_PAD / 64;          // 782
constexpr int G1_GRID = 3920;              // 8 * 5 * 98 (>= 782*5, padded)
__global__ __launch_bounds__(256) void gemm1_fill(
    const float* __restrict__ x,
    const unsigned short* __restrict__ wbt_hi, const unsigned short* __restrict__ wbt_lo,
    unsigned short* __restrict__ xtbf,
    const int* __restrict__ src, const int* __restrict__ dst,
    const int* __restrict__ etype, const int* __restrict__ off,
    const int* __restrict__ rank, int* __restrict__ eprep) {
  if (blockIdx.x < G1_GRID) {
    // XCD-group swizzle: the 5 col-tiles of one row-tile sit 8 apart
    // in blockIdx -> same XCD under round-robin -> A-tile L2 reuse.
    int b = blockIdx.x;
    int r8 = b & 7, s = b >> 3;
    int by = s % 5, q = s / 5;
    int bx = q * 8 + r8;
    if (bx < G1_BX)
      gemm_body128(bx, by, x, wbt_hi, wbt_lo, xtbf, N_NODES, MBIG);
  } else {
    int e = (blockIdx.x - G1_GRID) * 256 + threadIdx.x;
    if (e < N_EDGES) {
      int pos = off[dst[e]] + rank[e];
      eprep[pos] = src[e] | (etype[e] << 16);
    }
  }
}

// ---- gemm2 (K=64, g from pre-split h) ----
__global__ __launch_bounds__(256) void gemm2_k(
    const unsigned short* __restrict__ hhi, const unsigned short* __restrict__ hlo,
    const unsigned short* __restrict__ wgt_hi, const unsigned short* __restrict__ wgt_lo,
    unsigned short* __restrict__ gbf) {
  gemm_body64(blockIdx.x % G1_BX, blockIdx.x / G1_BX,
              hhi, hlo, wgt_hi, wgt_lo, gbf, N_NODES, HOUT);
}

// ---- scan stage 1: per-block sums ----
__global__ __launch_bounds__(256) void k_s1(const int* __restrict__ deg,
                                            int* __restrict__ bsum) {
  __shared__ int ss[256];
  int t = threadIdx.x;
  int i = blockIdx.x * 256 + t;
  ss[t] = (i < N_NODES) ? deg[i] : 0;
  __syncthreads();
  for (int d = 128; d > 0; d >>= 1) {
    if (t < d) ss[t] += ss[t + d];
    __syncthreads();
  }
  if (t == 0) bsum[blockIdx.x] = ss[0];
}

// ---- scan stage 2: exclusive scan of block sums ----
__global__ __launch_bounds__(256) void k_s2(const int* __restrict__ bsum,
                                            int* __restrict__ bbase,
                                            int* __restrict__ off) {
  __shared__ int ss[256];
  int t = threadIdx.x;
  int v = (t < NBLK) ? bsum[t] : 0;
  ss[t] = v;
  __syncthreads();
  for (int d = 1; d < 256; d <<= 1) {
    int u = (t >= d) ? ss[t - d] : 0;
    __syncthreads();
    ss[t] += u;
    __syncthreads();
  }
  if (t < NBLK) bbase[t] = ss[t] - v;
  if (t == NBLK - 1) off[N_NODES] = ss[t];
}

// ---- scan stage 3: block-local scan + base ----
__global__ __launch_bounds__(256) void k_s3(const int* __restrict__ deg,
                                            const int* __restrict__ bbase,
                                            int* __restrict__ off) {
  __shared__ int ss[256];
  int t = threadIdx.x;
  int i = blockIdx.x * 256 + t;
  int v = (i < N_NODES) ? deg[i] : 0;
  ss[t] = v;
  __syncthreads();
  for (int d = 1; d < 256; d <<= 1) {
    int u = (t >= d) ? ss[t - d] : 0;
    __syncthreads();
    ss[t] += u;
    __syncthreads();
  }
  if (i < N_NODES) off[i] = bbase[blockIdx.x] + ss[t] - v;
}

// ---- RGCN: gather from bf16 xt; wave/node; emits h (bf16 hi/lo) AND
//      attention coefficients a_s/a_d = h @ (W_gat @ att) ----
__global__ __launch_bounds__(256) void rgcn_gather(const unsigned short* __restrict__ xtbf,
                                                   const int* __restrict__ off,
                                                   const int* __restrict__ eprep,
                                                   const float* __restrict__ b_rgcn,
                                                   const float* __restrict__ was,
                                                   const float* __restrict__ wad,
                                                   unsigned short* __restrict__ hhi,
                                                   unsigned short* __restrict__ hlo,
                                                   float* __restrict__ a_s,
                                                   float* __restrict__ a_d) {
  int wid = (blockIdx.x * 256 + threadIdx.x) >> 6;
  int lane = threadIdx.x & 63;
  int half = lane >> 5;
  int cp = lane & 31;
  int start = off[wid], end = off[wid + 1];
  float a0x=0.f,a0y=0.f,a1x=0.f,a1y=0.f,a2x=0.f,a2y=0.f,a3x=0.f,a3y=0.f;
  int c0=0,c1=0,c2=0,c3=0;
  int niter = (end - start + 1) >> 1;
  for (int t = 0; t < niter; t += 2) {
    int idx0 = start + 2 * t + half;
    int idx1 = idx0 + 2;
    int p0 = (idx0 < end) ? eprep[idx0] : 0x70000;
    int p1 = (idx1 < end) ? eprep[idx1] : 0x70000;
    int s0 = p0 & 0xFFFF, r0 = p0 >> 16;
    int s1 = p1 & 0xFFFF, r1 = p1 >> 16;
    unsigned u0 = *reinterpret_cast<const unsigned*>(
        &xtbf[(size_t)s0 * MBIG + H1 + (r0 << 6) + cp * 2]);
    unsigned u1 = *reinterpret_cast<const unsigned*>(
        &xtbf[(size_t)s1 * MBIG + H1 + (r1 << 6) + cp * 2]);
    float v0x = bflo(u0), v0y = bfhi(u0);
    float v1x = bflo(u1), v1y = bfhi(u1);
    a0x += (r0==0)?v0x:0.f; a0y += (r0==0)?v0y:0.f; c0 += (r0==0);
    a1x += (r0==1)?v0x:0.f; a1y += (r0==1)?v0y:0.f; c1 += (r0==1);
    a2x += (r0==2)?v0x:0.f; a2y += (r0==2)?v0y:0.f; c2 += (r0==2);
    a3x += (r0==3)?v0x:0.f; a3y += (r0==3)?v0y:0.f; c3 += (r0==3);
    a0x += (r1==0)?v1x:0.f; a0y += (r1==0)?v1y:0.f; c0 += (r1==0);
    a1x += (r1==1)?v1x:0.f; a1y += (r1==1)?v1y:0.f; c1 += (r1==1);
    a2x += (r1==2)?v1x:0.f; a2y += (r1==2)?v1y:0.f; c2 += (r1==2);
    a3x += (r1==3)?v1x:0.f; a3y += (r1==3)?v1y:0.f; c3 += (r1==3);
  }
  a0x += __shfl_xor(a0x, 32); a0y += __shfl_xor(a0y, 32);
  a1x += __shfl_xor(a1x, 32); a1y += __shfl_xor(a1y, 32);
  a2x += __shfl_xor(a2x, 32); a2y += __shfl_xor(a2y, 32);
  a3x += __shfl_xor(a3x, 32); a3y += __shfl_xor(a3y, 32);
  c0 += __shfl_xor(c0, 32); c1 += __shfl_xor(c1, 32);
  c2 += __shfl_xor(c2, 32); c3 += __shfl_xor(c3, 32);
  if (half == 0) {
    unsigned ur = *reinterpret_cast<const unsigned*>(&xtbf[(size_t)wid * MBIG + cp * 2]);
    float2 bb = *reinterpret_cast<const float2*>(&b_rgcn[cp * 2]);
    float i0 = 1.0f / (float)max(c0, 1);
    float i1 = 1.0f / (float)max(c1, 1);
    float i2 = 1.0f / (float)max(c2, 1);
    float i3 = 1.0f / (float)max(c3, 1);
    float vx = bflo(ur) + bb.x + a0x * i0 + a1x * i1 + a2x * i2 + a3x * i3;
    float vy = bfhi(ur) + bb.y + a0y * i0 + a1y * i1 + a2y * i2 + a3y * i3;
    vx = fmaxf(vx, 0.f);
    vy = fmaxf(vy, 0.f);
    unsigned short hx = f2bf(vx), hy = f2bf(vy);
    ushort2 hv = {hx, hy};
    ushort2 lv = {f2bf(vx - bf2f(hx)), f2bf(vy - bf2f(hy))};
    *reinterpret_cast<ushort2*>(&hhi[(size_t)wid * H1 + cp * 2]) = hv;
    *reinterpret_cast<ushort2*>(&hlo[(size_t)wid * H1 + cp * 2]) = lv;
    // ---- fused attention coefficients: a = h @ was / h @ wad ----
    float4 wsA = *reinterpret_cast<const float4*>(&was[cp * 8]);      // k=2cp
    float4 wsB = *reinterpret_cast<const float4*>(&was[cp * 8 + 4]);  // k=2cp+1
    float4 wdA = *reinterpret_cast<const float4*>(&wad[cp * 8]);
    float4 wdB = *reinterpret_cast<const float4*>(&wad[cp * 8 + 4]);
    float ps0 = vx * wsA.x + vy * wsB.x;
    float ps1 = vx * wsA.y + vy * wsB.y;
    float ps2 = vx * wsA.z + vy * wsB.z;
    float ps3 = vx * wsA.w + vy * wsB.w;
    float pd0 = vx * wdA.x + vy * wdB.x;
    float pd1 = vx * wdA.y + vy * wdB.y;
    float pd2 = vx * wdA.z + vy * wdB.z;
    float pd3 = vx * wdA.w + vy * wdB.w;
#pragma unroll
    for (int d = 1; d < 32; d <<= 1) {
      ps0 += __shfl_xor(ps0, d); ps1 += __shfl_xor(ps1, d);
      ps2 += __shfl_xor(ps2, d); ps3 += __shfl_xor(ps3, d);
      pd0 += __shfl_xor(pd0, d); pd1 += __shfl_xor(pd1, d);
      pd2 += __shfl_xor(pd2, d); pd3 += __shfl_xor(pd3, d);
    }
    if (cp == 0) {
      *reinterpret_cast<float4*>(&a_s[(size_t)wid * 4]) = make_float4(ps0, ps1, ps2, ps3);
      *reinterpret_cast<float4*>(&a_d[(size_t)wid * 4]) = make_float4(pd0, pd1, pd2, pd3);
    }
  }
}

// ---- GAT + head fused ----
constexpr int GAT_BLOCKS = 2048;
constexpr int GAT_WAVES = GAT_BLOCKS * 4;   // 8192
__global__ __launch_bounds__(256) void gat_fused(const unsigned short* __restrict__ gbf,
                                                 const float* __restrict__ a_s,
                                                 const float* __restrict__ a_d,
                                                 const int* __restrict__ off,
                                                 const int* __restrict__ eprep,
                                                 const float* __restrict__ b_gat,
                                                 const float* __restrict__ W1,
                                                 const float* __restrict__ b1,
                                                 const int* __restrict__ batch,
                                                 unsigned* __restrict__ p_mono) {
  __shared__ float w1s[HOUT * 16];        // W1[k][j]
  __shared__ float ob[4][HOUT];           // per-wave o row
  __shared__ unsigned sp[N_GRAPHS * 16];
  const int t = threadIdx.x;
  for (int i = t; i < HOUT * 16; i += 256) w1s[i] = W1[i];
  for (int i = t; i < N_GRAPHS * 16; i += 256) sp[i] = MONO_NEG_INF;
  __syncthreads();
  const int wv = t >> 6, lane = t & 63;
  const int hh = lane >> 4;
  const int jj = lane & 15, grp = lane >> 4;
  const int w = blockIdx.x * 4 + wv;
  const int q = N_NODES / GAT_WAVES;
  const int r = N_NODES % GAT_WAVES;
  const int nbeg = w * q + ((w < r) ? w : r);
  const int ncnt = q + ((w < r) ? 1 : 0);
  for (int wid = nbeg; wid < nbeg + ncnt; ++wid) {
    int start = off[wid], end = off[wid + 1];
    float4 ad4 = *reinterpret_cast<const float4*>(a_d + (size_t)wid * 4);
    float adh = (hh == 0) ? ad4.x : (hh == 1) ? ad4.y : (hh == 2) ? ad4.z : ad4.w;
    float ox = 0.f, oy = 0.f, den = 0.f;
    int i = start;
    for (; i + 4 <= end; i += 4) {
      int p0 = eprep[i], p1 = eprep[i + 1], p2 = eprep[i + 2], p3 = eprep[i + 3];
      int s0 = p0 & 0xFFFF, s1 = p1 & 0xFFFF, s2 = p2 & 0xFFFF, s3 = p3 & 0xFFFF;
      float as0 = a_s[(size_t)s0 * 4 + hh];
      float as1 = a_s[(size_t)s1 * 4 + hh];
      float as2 = a_s[(size_t)s2 * 4 + hh];
      float as3 = a_s[(size_t)s3 * 4 + hh];
      unsigned u0 = *reinterpret_cast<const unsigned*>(&gbf[(size_t)s0 * HOUT + lane * 2]);
      unsigned u1 = *reinterpret_cast<const unsigned*>(&gbf[(size_t)s1 * HOUT + lane * 2]);
      unsigned u2 = *reinterpret_cast<const unsigned*>(&gbf[(size_t)s2 * HOUT + lane * 2]);
      unsigned u3 = *reinterpret_cast<const unsigned*>(&gbf[(size_t)s3 * HOUT + lane * 2]);
      float e0 = as0 + adh; e0 = (e0 > 0.f) ? e0 : 0.2f * e0;
      float e1 = as1 + adh; e1 = (e1 > 0.f) ? e1 : 0.2f * e1;
      float e2 = as2 + adh; e2 = (e2 > 0.f) ? e2 : 0.2f * e2;
      float e3 = as3 + adh; e3 = (e3 > 0.f) ? e3 : 0.2f * e3;
      float x0 = __expf(e0), x1 = __expf(e1), x2 = __expf(e2), x3 = __expf(e3);
      den += x0 + x1 + x2 + x3;
      ox += x0 * bflo(u0) + x1 * bflo(u1) + x2 * bflo(u2) + x3 * bflo(u3);
      oy += x0 * bfhi(u0) + x1 * bfhi(u1) + x2 * bfhi(u2) + x3 * bfhi(u3);
    }
    for (; i < end; ++i) {
      int p = eprep[i];
      int s = p & 0xFFFF;
      float as = a_s[(size_t)s * 4 + hh];
      unsigned u = *reinterpret_cast<const unsigned*>(&gbf[(size_t)s * HOUT + lane * 2]);
      float e = as + adh; e = (e > 0.f) ? e : 0.2f * e;
      float ex = __expf(e);
      den += ex;
      ox += ex * bflo(u);
      oy += ex * bfhi(u);
    }
    float dinv = (den > 0.f) ? (1.0f / den) : 0.f;
    float2 bg = *reinterpret_cast<const float2*>(b_gat + lane * 2);
    float vx = ox * dinv + bg.x; vx = (vx > 0.f) ? vx : 0.01f * vx;
    float vy = oy * dinv + bg.y; vy = (vy > 0.f) ? vy : 0.01f * vy;
    *reinterpret_cast<float2*>(&ob[wv][lane * 2]) = make_float2(vx, vy);
    float acc = 0.f;
#pragma unroll 8
    for (int i2 = 0; i2 < 32; ++i2) {
      int c = grp + 4 * i2;
      acc += ob[wv][c] * w1s[c * 16 + jj];
    }
    acc += __shfl_xor(acc, 16);
    acc += __shfl_xor(acc, 32);
    float z = acc + b1[jj];
    z = (z > 0.f) ? z : 0.01f * z;
    int b = batch[wid];
    if (lane < 16) atomicMax(&sp[b * 16 + jj], f2mono(z));
  }
  __syncthreads();
  for (int i = t; i < N_GRAPHS * 16; i += 256) {
    unsigned v = sp[i];
    if (v != MONO_NEG_INF) atomicMax(p_mono + i, v);
  }
}

// ---- y = p @ W2 + b2 ----
__global__ void final_y(const unsigned* __restrict__ p_mono,
                        const float* __restrict__ W2,
                        const float* __restrict__ b2,
                        float* __restrict__ y) {
  int gr = threadIdx.x;
  if (gr >= N_GRAPHS) return;
  float acc = b2[0];
#pragma unroll
  for (int k = 0; k < 16; ++k) acc += mono2f(p_mono[gr * 16 + k]) * W2[k];
  y[gr] = acc;
}

extern "C" void kernel_launch(void* const* d_in, const int* in_sizes, int n_in,
                              void* d_out, int out_size, void* d_ws, size_t ws_size,
                              hipStream_t stream) {
  const float* x       = (const float*)d_in[0];
  const int*   eidx    = (const int*)d_in[1];
  const int*   etype   = (const int*)d_in[2];
  const int*   batch   = (const int*)d_in[3];
  const float* W_rel   = (const float*)d_in[4];
  const float* W_root  = (const float*)d_in[5];
  const float* b_rgcn  = (const float*)d_in[6];
  const float* W_gat   = (const float*)d_in[7];
  const float* att_src = (const float*)d_in[8];
  const float* att_dst = (const float*)d_in[9];
  const float* b_gat   = (const float*)d_in[10];
  const float* W1      = (const float*)d_in[11];
  const float* b1      = (const float*)d_in[12];
  const float* W2      = (const float*)d_in[13];
  const float* b2      = (const float*)d_in[14];
  float* y = (float*)d_out;

  const int* src = eidx;
  const int* dst = eidx + N_EDGES;

  float* ws = (float*)d_ws;
  // ---- workspace layout (float offsets) ----
  const size_t OFF_XTBF= 0;           //  8,007,680 f: xt bf16 [N_PAD,320]
  const size_t OFF_GBF = 0;           //  g bf16 [N_PAD,128] (reuses xtbf)
  const size_t OFF_HHI = 8007680;     //  1,601,536 f: h hi bf16 [N_PAD,64]
  const size_t OFF_HLO = 9609216;     //  1,601,536 f: h lo
  const size_t OFF_AS  = 11210752;    //    200,000  a_src
  const size_t OFF_AD  = 11410752;    //    200,000  a_dst
  const size_t OFF_PM  = 11610752;    //      1,024 f = 1024 u32 pool max
  const size_t OFF_DEG = 11611776;    //     50,000  deg (int)
  const size_t OFF_OFFS= 11661776;    //     50,001  off (int)
  const size_t OFF_RANK= 11711780;    //    800,000  rank (int)
  const size_t OFF_EP  = 12511780;    //    800,000  eprep (int)
  const size_t OFF_BS  = 13311780;    //        196
  const size_t OFF_BB  = 13311976;    //        196
  const size_t OFF_WAS = 13312176;    //        256  was (16B aligned)
  const size_t OFF_WAD = 13312432;    //        256  wad
  const size_t OFF_WBH = 13312688;    //     20,480  WbigT_hi (16B aligned)
  const size_t OFF_WBL = 13333168;    //     20,480  WbigT_lo
  const size_t OFF_WGH = 13353648;    //      4,096  WgatT_hi
  const size_t OFF_WGL = 13357744;    //      4,096  WgatT_lo
  const size_t TOTAL_F = 13361840;
  if (ws_size < TOTAL_F * sizeof(float)) return;

  unsigned short* xtbf = (unsigned short*)(ws + OFF_XTBF);
  unsigned short* gbf  = (unsigned short*)(ws + OFF_GBF);
  unsigned short* hhi  = (unsigned short*)(ws + OFF_HHI);
  unsigned short* hlo  = (unsigned short*)(ws + OFF_HLO);
  float* a_s   = ws + OFF_AS;
  float* a_d   = ws + OFF_AD;
  unsigned* pm = (unsigned*)(ws + OFF_PM);
  int* deg     = (int*)(ws + OFF_DEG);
  int* offs    = (int*)(ws + OFF_OFFS);
  int* rank    = (int*)(ws + OFF_RANK);
  int* eprep   = (int*)(ws + OFF_EP);
  int* bsum    = (int*)(ws + OFF_BS);
  int* bbase   = (int*)(ws + OFF_BB);
  float* was   = ws + OFF_WAS;
  float* wad   = ws + OFF_WAD;
  unsigned short* wbt_hi = (unsigned short*)(ws + OFF_WBH);
  unsigned short* wbt_lo = (unsigned short*)(ws + OFF_WBL);
  unsigned short* wgt_hi = (unsigned short*)(ws + OFF_WGH);
  unsigned short* wgt_lo = (unsigned short*)(ws + OFF_WGL);

  // 1. deg = 0 (before fused hist)
  hipMemsetAsync(deg, 0, N_NODES * sizeof(int), stream);

  // 2. fused prep: hist(+rank) | build_wT | init_mono | watt
  pre_fused<<<HIST_BLOCKS + WT_BLOCKS + 2, 256, 0, stream>>>(
      W_root, W_rel, W_gat, att_src, att_dst, dst,
      wbt_hi, wbt_lo, wgt_hi, wgt_lo, deg, rank, pm, was, wad);

  // 3. scan (off from deg)
  k_s1<<<NBLK, 256, 0, stream>>>(deg, bsum);
  k_s2<<<1, 256, 0, stream>>>(bsum, bbase, offs);
  k_s3<<<NBLK, 256, 0, stream>>>(deg, bbase, offs);

  // 4. gemm1 (XCD-swizzled, async dbuf chunks) fused with CSR fill
  gemm1_fill<<<G1_GRID + HIST_BLOCKS, 256, 0, stream>>>(
      x, wbt_hi, wbt_lo, xtbf, src, dst, etype, offs, rank, eprep);

  // 5. RGCN gather -> h (bf16 hi/lo) + fused a_s/a_d
  rgcn_gather<<<N_NODES / 4, 256, 0, stream>>>(xtbf, offs, eprep, b_rgcn,
                                               was, wad, hhi, hlo, a_s, a_d);

  // 6. g = h @ W_gat
  gemm2_k<<<G1_BX * (HOUT / 64), 256, 0, stream>>>(hhi, hlo, wgt_hi, wgt_lo, gbf);

  // 7. fused GAT aggregation + head + per-graph max pool
  gat_fused<<<GAT_BLOCKS, 256, 0, stream>>>(gbf, a_s, a_d, offs, eprep, b_gat,
                                            W1, b1, batch, pm);

  // 8. y = p @ W2 + b2
  final_y<<<1, 64, 0, stream>>>(pm, W2, b2, y);
}